// Round 3
// baseline (6090.902 us; speedup 1.0000x reference)
//
#include <hip/hip_runtime.h>
#include <hip/hip_bf16.h>
#include <math.h>

#define T_DIM 64
#define B_DIM 32
#define N_ENT 16
#define M_SLOTS 33
#define S_TOT 16384
#define BA 256
#define SB 64

#define ACT_OFF 0
#define LP_OFF 32768
#define ENT_OFF 49152

typedef __attribute__((ext_vector_type(8))) short short8;
typedef __attribute__((ext_vector_type(4))) float f32x4;
typedef unsigned int uint32;

__device__ __forceinline__ float sigf(float x) { return 1.0f / (1.0f + expf(-x)); }
__device__ __forceinline__ float bf2f(unsigned short u) {
    union { unsigned int i; float f; } a; a.i = ((unsigned int)u) << 16; return a.f;
}
__device__ __forceinline__ uint32 pkbf(float a, float b) {
    __hip_bfloat16 ha = __float2bfloat16(a), hb = __float2bfloat16(b);
    return (uint32)(*(unsigned short*)&ha) | ((uint32)(*(unsigned short*)&hb) << 16);
}

// ---------------------------------------------------------------------------
// Kernel A: sample-batched front end (unchanged from round 2).
// ---------------------------------------------------------------------------
__global__ __launch_bounds__(256, 1) void k_frontA(
    const float* __restrict__ xag, const float* __restrict__ xlid,
    const float* __restrict__ xsz, const float* __restrict__ xe0,
    const float* __restrict__ xe1,
    const float* __restrict__ conv_w, const float* __restrict__ conv_b,
    const float* __restrict__ self_w, const float* __restrict__ self_b,
    const float* __restrict__ ent0_w, const float* __restrict__ ent0_b,
    const float* __restrict__ ent1_w, const float* __restrict__ ent1_b,
    const float* __restrict__ pool_w,
    __hip_bfloat16* __restrict__ z_ent, float* __restrict__ zin_x)
{
    extern __shared__ float lds[];
    float* xs   = lds;              // [290][64]
    float* ebuf = xs + 290 * 64;    // [192][66]
    float* xp   = ebuf + 192 * 66;  // [64][65]
    float* zbuf = xp + 64 * 65;     // [64][65]

    const int tid = threadIdx.x;
    const int lane = tid & 63;
    const int wv = __builtin_amdgcn_readfirstlane(tid >> 6);
    const int s0 = blockIdx.x * SB;
    float* lid = ebuf;

    for (int i = tid; i < SB * 32; i += 256) {
        int d = i & 31, sl = i >> 5;
        lid[d * 66 + sl] = xlid[(size_t)s0 * 32 + i];
    }
    for (int i = tid; i < SB * 16; i += 256) {
        int d = i & 15, sl = i >> 4;
        xs[d * 64 + sl] = xag[(size_t)s0 * 16 + i];
    }
    for (int i = tid; i < SB * 4; i += 256) {
        int d = i & 3, sl = i >> 2;
        xs[(286 + d) * 64 + sl] = xsz[(size_t)s0 * 4 + i];
    }
    __syncthreads();
    for (int cp = wv; cp < 270; cp += 4) {
        int c = cp / 30, p = cp - c * 30;
        float w0 = conv_w[c * 3], w1 = conv_w[c * 3 + 1], w2 = conv_w[c * 3 + 2];
        float v = conv_b[c] + w0 * lid[p * 66 + lane] + w1 * lid[(p + 1) * 66 + lane]
                + w2 * lid[(p + 2) * 66 + lane];
        xs[(16 + cp) * 64 + lane] = fmaxf(v, 0.0f);
    }
    __syncthreads();

    for (int j = 0; j < 16; ++j) {
        int e = wv * 16 + j;
        const float* w = self_w + (size_t)e * 580;
        float acc = self_b[e];
        for (int d = 0; d < 290; ++d)
            acc = fmaf(w[d] + w[290 + d], xs[d * 64 + lane], acc);
        zbuf[e * 65 + lane] = fmaxf(acc, 0.0f);
    }
    __syncthreads();
    for (int i = tid; i < SB * 64; i += 256) {
        int e = i & 63, sl = i >> 6;
        z_ent[(size_t)(s0 + sl) * 2112 + e] = __float2bfloat16(zbuf[e * 65 + sl]);
    }
    __syncthreads();

    for (int h = 0; h < 2; ++h) {
        for (int j = 0; j < 16; ++j) {
            int r = h * 64 + wv * 16 + j;
            const float* w = pool_w + (size_t)r * 354;
            float acc = 0.0f;
            for (int d = 0; d < 290; ++d) acc = fmaf(w[d], xs[d * 64 + lane], acc);
            zbuf[(r & 63) * 65 + lane] = acc;
        }
        __syncthreads();
        for (int i = tid; i < SB * 64; i += 256) {
            int e = i & 63, sl = i >> 6;
            zin_x[(size_t)(s0 + sl) * 128 + h * 64 + e] = zbuf[e * 65 + sl];
        }
        __syncthreads();
    }

    for (int i = tid; i < SB * 192; i += 256) {
        int sl = i / 192, d = i - sl * 192;
        ebuf[d * 66 + sl] = xe0[(size_t)s0 * 192 + i];
    }
    for (int j = 0; j < 16; ++j) {
        int e = wv * 16 + j;
        const float* w = ent0_w + (size_t)e * 302;
        float acc = ent0_b[e];
        for (int d = 0; d < 290; ++d) acc = fmaf(w[12 + d], xs[d * 64 + lane], acc);
        xp[e * 65 + lane] = acc;
    }
    __syncthreads();
    for (int n = 0; n < 16; ++n) {
        for (int j = 0; j < 16; ++j) {
            int e = wv * 16 + j;
            const float* w = ent0_w + (size_t)e * 302;
            float acc = xp[e * 65 + lane];
            #pragma unroll
            for (int dd = 0; dd < 12; ++dd)
                acc = fmaf(w[dd], ebuf[(n * 12 + dd) * 66 + lane], acc);
            zbuf[e * 65 + lane] = fmaxf(acc, 0.0f);
        }
        __syncthreads();
        for (int i = tid; i < SB * 64; i += 256) {
            int e = i & 63, sl = i >> 6;
            z_ent[(size_t)(s0 + sl) * 2112 + (1 + n) * 64 + e] = __float2bfloat16(zbuf[e * 65 + sl]);
        }
        __syncthreads();
    }

    for (int i = tid; i < SB * 128; i += 256) {
        int sl = i >> 7, d = i & 127;
        ebuf[d * 66 + sl] = xe1[(size_t)s0 * 128 + i];
    }
    for (int j = 0; j < 16; ++j) {
        int e = wv * 16 + j;
        const float* w = ent1_w + (size_t)e * 298;
        float acc = ent1_b[e];
        for (int d = 0; d < 290; ++d) acc = fmaf(w[8 + d], xs[d * 64 + lane], acc);
        xp[e * 65 + lane] = acc;
    }
    __syncthreads();
    for (int n = 0; n < 16; ++n) {
        for (int j = 0; j < 16; ++j) {
            int e = wv * 16 + j;
            const float* w = ent1_w + (size_t)e * 298;
            float acc = xp[e * 65 + lane];
            #pragma unroll
            for (int dd = 0; dd < 8; ++dd)
                acc = fmaf(w[dd], ebuf[(n * 8 + dd) * 66 + lane], acc);
            zbuf[e * 65 + lane] = fmaxf(acc, 0.0f);
        }
        __syncthreads();
        for (int i = tid; i < SB * 64; i += 256) {
            int e = i & 63, sl = i >> 6;
            z_ent[(size_t)(s0 + sl) * 2112 + (17 + n) * 64 + e] = __float2bfloat16(zbuf[e * 65 + sl]);
        }
        __syncthreads();
    }
}

// ---------------------------------------------------------------------------
// k_cvt: one-time f32 -> bf16 weight conversion into ws
// ---------------------------------------------------------------------------
__global__ __launch_bounds__(256) void k_cvt(
    const float* __restrict__ inp_w, const float* __restrict__ outp_w,
    const float* __restrict__ sa_w, short* __restrict__ wq,
    short* __restrict__ wo, short* __restrict__ ws)
{
    int i = blockIdx.x * 256 + threadIdx.x;
    if (i < 12288) { __hip_bfloat16 h = __float2bfloat16(inp_w[i]); wq[i] = *(short*)&h; }
    if (i < 4096) {
        __hip_bfloat16 h = __float2bfloat16(outp_w[i]); wo[i] = *(short*)&h;
        __hip_bfloat16 h2 = __float2bfloat16(sa_w[i]);  ws[i] = *(short*)&h2;
    }
}

// ---------------------------------------------------------------------------
// Kernel C: MFMA attention block. 8192 blocks x 256 thr, 2 samples/block.
// LDS (66.4 KB -> 2 blocks/CU):
//   zeb  bf16 [80][64] swizzled       10240 B
//   Qf   f32  [66][68]                17952 B   (aliased as res later)
//   kvb  bf16 [66][128]               16896 B
//   ob   bf16 [80][64] swizzled       10240 B
//   o2b  bf16 [80][64] swizzled       10240 B
//   msk  f32  [2][36]                   288 B
//   pooled f32 [2][64]                  512 B
// ---------------------------------------------------------------------------
#define LDS_ZEB   0
#define LDS_QF    10240
#define LDS_KV    28192
#define LDS_OB    45088
#define LDS_O2B   55328
#define LDS_MSK   65568
#define LDS_POOL  65856
#define LDS_TOTAL 66368

__global__ __launch_bounds__(256, 2) void k_attnC(
    const __hip_bfloat16* __restrict__ z_ent, const float* __restrict__ zin_x_ws,
    const int* __restrict__ mask0, const int* __restrict__ mask1,
    const short* __restrict__ wqkvb, const float* __restrict__ inp_b,
    const short* __restrict__ wob_g, const float* __restrict__ outp_b,
    const short* __restrict__ wsb_g, const float* __restrict__ sa_b,
    const float* __restrict__ pool_w, const float* __restrict__ pool_b,
    float* __restrict__ zin)
{
    extern __shared__ char smem[];
    char*  zeb = smem + LDS_ZEB;
    float* Qf  = (float*)(smem + LDS_QF);
    char*  kvb = smem + LDS_KV;
    char*  ob  = smem + LDS_OB;
    char*  o2b = smem + LDS_O2B;
    float* msk = (float*)(smem + LDS_MSK);
    float* pooled = (float*)(smem + LDS_POOL);
    float* res = Qf;  // alias: Qf dead after attention phase

    const int tid = threadIdx.x;
    const int gs0 = blockIdx.x * 2;

    // ---- stage: zero pad rows (66..79) of bf16 tiles; load ze swizzled; mask ----
    for (int i = tid; i < 448; i += 256) {
        ((uint32*)(zeb + 66 * 128))[i] = 0;
        ((uint32*)(ob  + 66 * 128))[i] = 0;
        ((uint32*)(o2b + 66 * 128))[i] = 0;
    }
    {
        const uint32* zsrc = (const uint32*)(z_ent + (size_t)gs0 * 2112);
        for (int i = tid; i < 2112; i += 256) {
            int s = (i >= 1056) ? 1 : 0;
            int idx = i - s * 1056;
            int row = s * 33 + (idx >> 5);
            int c2 = idx & 31;
            int byteo = (row * 128 + c2 * 4) ^ ((row & 7) << 4);
            *(uint32*)(zeb + byteo) = zsrc[i];
        }
    }
    if (tid < 32) { int s = tid >> 4, i2 = tid & 15; msk[s * 36 + 1 + i2] = (float)mask0[(size_t)(gs0 + s) * 16 + i2]; }
    else if (tid < 64) { int u = tid - 32; int s = u >> 4, i2 = u & 15; msk[s * 36 + 17 + i2] = (float)mask1[(size_t)(gs0 + s) * 16 + i2]; }
    else if (tid < 66) msk[(tid - 64) * 36] = 1.0f;
    __syncthreads();

    const int wv = tid >> 6;
    const int l  = tid & 63;
    const int lr = l & 15;    // frag row/col index
    const int lg = l >> 4;    // k-group

    // ---- in_proj GEMM: qkv = ze @ inp_w^T + b ----
    {
        short8 bw[3][2]; float bias[3];
        #pragma unroll
        for (int c = 0; c < 3; ++c) {
            int col = (wv * 3 + c) * 16 + lr;
            bw[c][0] = *(const short8*)(wqkvb + col * 64 + lg * 8);
            bw[c][1] = *(const short8*)(wqkvb + col * 64 + 32 + lg * 8);
            bias[c] = inp_b[col];
        }
        for (int rt = 0; rt < 5; ++rt) {
            int arow = rt * 16 + lr;
            int sw = (arow & 7) << 4;
            short8 a0 = *(const short8*)(zeb + ((arow * 128 + lg * 16) ^ sw));
            short8 a1 = *(const short8*)(zeb + ((arow * 128 + 64 + lg * 16) ^ sw));
            #pragma unroll
            for (int c = 0; c < 3; ++c) {
                f32x4 acc = {0.f, 0.f, 0.f, 0.f};
                acc = __builtin_amdgcn_mfma_f32_16x16x32_bf16(a0, bw[c][0], acc, 0, 0, 0);
                acc = __builtin_amdgcn_mfma_f32_16x16x32_bf16(a1, bw[c][1], acc, 0, 0, 0);
                int ct = wv * 3 + c;
                int col = ct * 16 + lr;
                int rb = rt * 16 + lg * 4;
                if (ct < 4) {
                    #pragma unroll
                    for (int r = 0; r < 4; ++r) {
                        int row = rb + r;
                        if (row < 66) Qf[row * 68 + col] = acc[r] + bias[c];
                    }
                } else {
                    int kc = col - 64;
                    #pragma unroll
                    for (int r = 0; r < 4; ++r) {
                        int row = rb + r;
                        if (row < 66)
                            *(__hip_bfloat16*)(kvb + row * 256 + kc * 2) = __float2bfloat16(acc[r] + bias[c]);
                    }
                }
            }
        }
    }
    __syncthreads();

    // ---- attention core: thread = (s,h, q-pair) ----
    if (tid < 136) {
        int sh, q0; bool two;
        if (tid < 128) { sh = tid >> 4; q0 = (tid & 15) * 2; two = true; }
        else { sh = tid - 128; q0 = 32; two = false; }
        int s = sh >> 2, h = sh & 3;
        float qr0[16], qr1[16];
        {
            const float4* p0 = (const float4*)(Qf + (s * 33 + q0) * 68 + h * 16);
            int q1 = two ? q0 + 1 : q0;
            const float4* p1 = (const float4*)(Qf + (s * 33 + q1) * 68 + h * 16);
            #pragma unroll
            for (int j = 0; j < 4; ++j) {
                float4 v0 = p0[j], v1 = p1[j];
                qr0[4 * j] = v0.x; qr0[4 * j + 1] = v0.y; qr0[4 * j + 2] = v0.z; qr0[4 * j + 3] = v0.w;
                qr1[4 * j] = v1.x; qr1[4 * j + 1] = v1.y; qr1[4 * j + 2] = v1.z; qr1[4 * j + 3] = v1.w;
            }
        }
        float sc0[33], sc1[33];
        float mx0 = -3e38f, mx1 = -3e38f;
        #pragma unroll
        for (int k = 0; k < 33; ++k) {
            const short8* kp = (const short8*)(kvb + (s * 33 + k) * 256 + h * 32);
            short8 k0 = kp[0], k1 = kp[1];
            float d0 = 0.f, d1 = 0.f;
            #pragma unroll
            for (int j = 0; j < 8; ++j) {
                float kv0 = bf2f((unsigned short)k0[j]);
                d0 = fmaf(qr0[j], kv0, d0);
                d1 = fmaf(qr1[j], kv0, d1);
            }
            #pragma unroll
            for (int j = 0; j < 8; ++j) {
                float kv1 = bf2f((unsigned short)k1[j]);
                d0 = fmaf(qr0[8 + j], kv1, d0);
                d1 = fmaf(qr1[8 + j], kv1, d1);
            }
            bool mk = msk[s * 36 + k] > 0.f;
            float v0 = mk ? d0 * 0.25f : -1e9f;
            float v1 = mk ? d1 * 0.25f : -1e9f;
            sc0[k] = v0; sc1[k] = v1;
            mx0 = fmaxf(mx0, v0); mx1 = fmaxf(mx1, v1);
        }
        float sum0 = 0.f, sum1 = 0.f;
        #pragma unroll
        for (int k = 0; k < 33; ++k) {
            float e0 = __expf(sc0[k] - mx0), e1 = __expf(sc1[k] - mx1);
            sc0[k] = e0; sc1[k] = e1; sum0 += e0; sum1 += e1;
        }
        float inv0 = 1.f / sum0, inv1 = 1.f / sum1;
        float o0[16], o1[16];
        #pragma unroll
        for (int j = 0; j < 16; ++j) { o0[j] = 0.f; o1[j] = 0.f; }
        #pragma unroll
        for (int k = 0; k < 33; ++k) {
            const short8* vp = (const short8*)(kvb + (s * 33 + k) * 256 + 128 + h * 32);
            short8 v0 = vp[0], v1 = vp[1];
            float p0 = sc0[k], p1 = sc1[k];
            #pragma unroll
            for (int j = 0; j < 8; ++j) {
                float vv = bf2f((unsigned short)v0[j]);
                o0[j] = fmaf(p0, vv, o0[j]); o1[j] = fmaf(p1, vv, o1[j]);
            }
            #pragma unroll
            for (int j = 0; j < 8; ++j) {
                float vv = bf2f((unsigned short)v1[j]);
                o0[8 + j] = fmaf(p0, vv, o0[8 + j]); o1[8 + j] = fmaf(p1, vv, o1[8 + j]);
            }
        }
        int row0 = s * 33 + q0;
        int base0 = row0 * 128 + h * 32;
        int sw0 = (row0 & 7) << 4;
        #pragma unroll
        for (int j = 0; j < 8; ++j)
            *(uint32*)(ob + ((base0 + j * 4) ^ sw0)) = pkbf(o0[2 * j] * inv0, o0[2 * j + 1] * inv0);
        if (two) {
            int row1 = row0 + 1;
            int base1 = row1 * 128 + h * 32;
            int sw1 = (row1 & 7) << 4;
            #pragma unroll
            for (int j = 0; j < 8; ++j)
                *(uint32*)(ob + ((base1 + j * 4) ^ sw1)) = pkbf(o1[2 * j] * inv1, o1[2 * j + 1] * inv1);
        }
    }
    __syncthreads();

    // ---- out_proj GEMM: o2 = o @ outp_w^T + b -> o2b (bf16) ----
    {
        int col = wv * 16 + lr;
        short8 b0 = *(const short8*)(wob_g + col * 64 + lg * 8);
        short8 b1 = *(const short8*)(wob_g + col * 64 + 32 + lg * 8);
        float bias = outp_b[col];
        for (int rt = 0; rt < 5; ++rt) {
            int arow = rt * 16 + lr;
            int sw = (arow & 7) << 4;
            short8 a0 = *(const short8*)(ob + ((arow * 128 + lg * 16) ^ sw));
            short8 a1 = *(const short8*)(ob + ((arow * 128 + 64 + lg * 16) ^ sw));
            f32x4 acc = {0.f, 0.f, 0.f, 0.f};
            acc = __builtin_amdgcn_mfma_f32_16x16x32_bf16(a0, b0, acc, 0, 0, 0);
            acc = __builtin_amdgcn_mfma_f32_16x16x32_bf16(a1, b1, acc, 0, 0, 0);
            int rb = rt * 16 + lg * 4;
            #pragma unroll
            for (int r = 0; r < 4; ++r) {
                int row = rb + r;
                if (row < 66)
                    *(__hip_bfloat16*)(o2b + ((row * 128 + col * 2) ^ ((row & 7) << 4))) = __float2bfloat16(acc[r] + bias);
            }
        }
    }
    __syncthreads();

    // ---- sa GEMM + residual + mask -> res (f32, aliases Qf) ----
    {
        int col = wv * 16 + lr;
        short8 b0 = *(const short8*)(wsb_g + col * 64 + lg * 8);
        short8 b1 = *(const short8*)(wsb_g + col * 64 + 32 + lg * 8);
        float bias = sa_b[col];
        for (int rt = 0; rt < 5; ++rt) {
            int arow = rt * 16 + lr;
            int sw = (arow & 7) << 4;
            short8 a0 = *(const short8*)(o2b + ((arow * 128 + lg * 16) ^ sw));
            short8 a1 = *(const short8*)(o2b + ((arow * 128 + 64 + lg * 16) ^ sw));
            f32x4 acc = {0.f, 0.f, 0.f, 0.f};
            acc = __builtin_amdgcn_mfma_f32_16x16x32_bf16(a0, b0, acc, 0, 0, 0);
            acc = __builtin_amdgcn_mfma_f32_16x16x32_bf16(a1, b1, acc, 0, 0, 0);
            int rb = rt * 16 + lg * 4;
            #pragma unroll
            for (int r = 0; r < 4; ++r) {
                int row = rb + r;
                if (row < 66) {
                    int ss = (row >= 33) ? 1 : 0;
                    int m = row - ss * 33;
                    float zev = bf2f(*(const unsigned short*)(zeb + ((row * 128 + col * 2) ^ ((row & 7) << 4))));
                    res[row * 68 + col] = msk[ss * 36 + m] * (zev + fmaxf(acc[r] + bias, 0.f));
                }
            }
        }
    }
    __syncthreads();

    // ---- pool ----
    if (tid < 128) {
        int s = tid >> 6, e = tid & 63;
        float acc = 0.f;
        #pragma unroll
        for (int m = 0; m < 33; ++m) acc += res[(s * 33 + m) * 68 + e];
        pooled[s * 64 + e] = acc * (1.0f / 33.0f);
    }
    __syncthreads();

    // ---- zin = relu(zin_x + pool_w[:,290:] @ pooled + b) ----
    {
        int s = tid >> 7, r = tid & 127;
        float acc = pool_b[r] + zin_x_ws[(size_t)(gs0 + s) * 128 + r];
        const float* wrow = pool_w + (size_t)r * 354 + 290;
        const float* pl = pooled + s * 64;
        #pragma unroll 8
        for (int e = 0; e < 64; ++e) acc = fmaf(wrow[e], pl[e], acc);
        zin[(size_t)(gs0 + s) * 128 + r] = fmaxf(acc, 0.f);
    }
}

// ---------------------------------------------------------------------------
// Kernel: LSTM scan (unchanged)
// ---------------------------------------------------------------------------
__global__ __launch_bounds__(512) void k_lstm(
    const float* __restrict__ zin, const float* __restrict__ w_ih,
    const float* __restrict__ w_hh, const float* __restrict__ b_ih,
    const float* __restrict__ b_hh, const int* __restrict__ done,
    float* __restrict__ h_all)
{
    extern __shared__ float lds[];
    float* xp = lds;
    float* zl = xp + 64 * 512;
    float* hl = zl + 128;
    float* gl = hl + 128;
    const int s = blockIdx.x;
    const int r = threadIdx.x;
    const int b = s >> 3;

    float4 w[32];
    {
        const float4* wsrc = (const float4*)(w_ih + (size_t)r * 128);
        #pragma unroll
        for (int j = 0; j < 32; ++j) w[j] = wsrc[j];
    }
    const float bias = b_ih[r] + b_hh[r];

    for (int t = 0; t < T_DIM; ++t) {
        __syncthreads();
        if (r < 128) zl[r] = zin[((size_t)t * BA + s) * 128 + r];
        __syncthreads();
        const float4* x4 = (const float4*)zl;
        float a0 = 0.f, a1 = 0.f, a2 = 0.f, a3 = 0.f;
        #pragma unroll
        for (int j = 0; j < 32; ++j) {
            float4 wa = w[j], xa = x4[j];
            a0 = fmaf(wa.x, xa.x, a0);
            a1 = fmaf(wa.y, xa.y, a1);
            a2 = fmaf(wa.z, xa.z, a2);
            a3 = fmaf(wa.w, xa.w, a3);
        }
        xp[t * 512 + r] = bias + ((a0 + a1) + (a2 + a3));
    }

    {
        const float4* wsrc = (const float4*)(w_hh + (size_t)r * 128);
        #pragma unroll
        for (int j = 0; j < 32; ++j) w[j] = wsrc[j];
    }
    if (r < 128) hl[r] = 0.0f;
    float c = 0.0f;
    __syncthreads();

    for (int t = 0; t < T_DIM; ++t) {
        const float4* h4 = (const float4*)hl;
        float a0 = 0.f, a1 = 0.f, a2 = 0.f, a3 = 0.f;
        #pragma unroll
        for (int j = 0; j < 32; ++j) {
            float4 wa = w[j], xa = h4[j];
            a0 = fmaf(wa.x, xa.x, a0);
            a1 = fmaf(wa.y, xa.y, a1);
            a2 = fmaf(wa.z, xa.z, a2);
            a3 = fmaf(wa.w, xa.w, a3);
        }
        gl[r] = xp[t * 512 + r] + ((a0 + a1) + (a2 + a3));
        __syncthreads();
        if (r < 128) {
            float keep = done[t * B_DIM + b] ? 0.0f : 1.0f;
            float gi = gl[r], gf = gl[r + 128], gg = gl[r + 256], go = gl[r + 384];
            c *= keep;
            c = sigf(gf) * c + sigf(gi) * tanhf(gg);
            float hn = sigf(go) * tanhf(c);
            float keepn = (t < T_DIM - 1) ? (done[(t + 1) * B_DIM + b] ? 0.0f : 1.0f) : 1.0f;
            hl[r] = hn * keepn;
            h_all[((size_t)t * BA + s) * 128 + r] = hn;
        }
        __syncthreads();
    }
}

// ---------------------------------------------------------------------------
// Kernel: categorical heads (unchanged)
// ---------------------------------------------------------------------------
__global__ __launch_bounds__(256) void k_heads(
    const float* __restrict__ h_all, const int* __restrict__ actions,
    const float* __restrict__ h0w, const float* __restrict__ h0b,
    const float* __restrict__ h1w, const float* __restrict__ h1b,
    float* __restrict__ out)
{
    __shared__ float w0[640], w1[640], b0[8], b1[8];
    const int tid = threadIdx.x;
    for (int i = tid; i < 640; i += 256) { w0[i] = h0w[i]; w1[i] = h1w[i]; }
    if (tid < 5) { b0[tid] = h0b[tid]; b1[tid] = h1b[tid]; }
    __syncthreads();
    const int g = blockIdx.x * 256 + tid;
    const float* h = h_all + (size_t)g * 128;
    float l0[5], l1[5];
    #pragma unroll
    for (int cc = 0; cc < 5; ++cc) { l0[cc] = b0[cc]; l1[cc] = b1[cc]; }
    for (int j = 0; j < 128; ++j) {
        float hv = h[j];
        #pragma unroll
        for (int cc = 0; cc < 5; ++cc) {
            l0[cc] = fmaf(w0[cc * 128 + j], hv, l0[cc]);
            l1[cc] = fmaf(w1[cc * 128 + j], hv, l1[cc]);
        }
    }
    int a0 = actions[(size_t)g * 2], a1 = actions[(size_t)g * 2 + 1];
    float m0 = l0[0], m1 = l1[0];
    #pragma unroll
    for (int cc = 1; cc < 5; ++cc) { m0 = fmaxf(m0, l0[cc]); m1 = fmaxf(m1, l1[cc]); }
    float s0 = 0.f, s1 = 0.f;
    #pragma unroll
    for (int cc = 0; cc < 5; ++cc) { s0 += expf(l0[cc] - m0); s1 += expf(l1[cc] - m1); }
    float lse0 = m0 + logf(s0), lse1 = m1 + logf(s1);
    float ent0 = 0.f, ent1 = 0.f, lp0 = 0.f, lp1 = 0.f;
    #pragma unroll
    for (int cc = 0; cc < 5; ++cc) {
        float p0 = l0[cc] - lse0, p1 = l1[cc] - lse1;
        ent0 -= expf(p0) * p0;
        ent1 -= expf(p1) * p1;
        if (cc == a0) lp0 = p0;
        if (cc == a1) lp1 = p1;
    }
    out[ACT_OFF + (size_t)g * 2]     = (float)a0;
    out[ACT_OFF + (size_t)g * 2 + 1] = (float)a1;
    out[LP_OFF + g]                  = lp0 * lp1;
    out[ENT_OFF + (size_t)g * 2]     = ent0;
    out[ENT_OFF + (size_t)g * 2 + 1] = ent1;
}

extern "C" void kernel_launch(void* const* d_in, const int* in_sizes, int n_in,
                              void* d_out, int out_size, void* d_ws, size_t ws_size,
                              hipStream_t stream)
{
    const float* x_agent = (const float*)d_in[0];
    const float* x_lidar = (const float*)d_in[1];
    const float* x_safe  = (const float*)d_in[2];
    const float* x_ent0  = (const float*)d_in[3];
    const float* x_ent1  = (const float*)d_in[4];
    const int*   mask0   = (const int*)d_in[5];
    const int*   mask1   = (const int*)d_in[6];
    const int*   done    = (const int*)d_in[7];
    const int*   actions = (const int*)d_in[8];
    const float* conv_w  = (const float*)d_in[9];
    const float* conv_b  = (const float*)d_in[10];
    const float* self_w  = (const float*)d_in[11];
    const float* self_b  = (const float*)d_in[12];
    const float* ent0_w  = (const float*)d_in[13];
    const float* ent0_b  = (const float*)d_in[14];
    const float* ent1_w  = (const float*)d_in[15];
    const float* ent1_b  = (const float*)d_in[16];
    const float* inp_w   = (const float*)d_in[17];
    const float* inp_b   = (const float*)d_in[18];
    const float* outp_w  = (const float*)d_in[19];
    const float* outp_b  = (const float*)d_in[20];
    const float* sa_w    = (const float*)d_in[21];
    const float* sa_b    = (const float*)d_in[22];
    const float* pool_w  = (const float*)d_in[23];
    const float* pool_b  = (const float*)d_in[24];
    const float* w_ih    = (const float*)d_in[25];
    const float* w_hh    = (const float*)d_in[26];
    const float* b_ih    = (const float*)d_in[27];
    const float* b_hh    = (const float*)d_in[28];
    const float* h0w     = (const float*)d_in[29];
    const float* h0b     = (const float*)d_in[30];
    const float* h1w     = (const float*)d_in[31];
    const float* h1b     = (const float*)d_in[32];

    // ws: z_ent bf16 [16384][2112] | zin_x f32 | zin f32 | h_all f32 | bf16 weights
    __hip_bfloat16* z_ent = (__hip_bfloat16*)d_ws;
    float* zin_x = (float*)((char*)d_ws + (size_t)S_TOT * 2112 * 2);
    float* zin   = zin_x + (size_t)S_TOT * 128;
    float* h_all = zin + (size_t)S_TOT * 128;
    short* wqkvb = (short*)(h_all + (size_t)S_TOT * 128);
    short* wob   = wqkvb + 12288;
    short* wsb   = wob + 4096;

    size_t ldsA = (size_t)(290 * 64 + 192 * 66 + 64 * 65 + 64 * 65) * sizeof(float);
    k_frontA<<<S_TOT / SB, 256, ldsA, stream>>>(
        x_agent, x_lidar, x_safe, x_ent0, x_ent1,
        conv_w, conv_b, self_w, self_b, ent0_w, ent0_b, ent1_w, ent1_b,
        pool_w, z_ent, zin_x);

    k_cvt<<<48, 256, 0, stream>>>(inp_w, outp_w, sa_w, wqkvb, wob, wsb);

    k_attnC<<<S_TOT / 2, 256, LDS_TOTAL, stream>>>(
        z_ent, zin_x, mask0, mask1, wqkvb, inp_b, wob, outp_b,
        wsb, sa_b, pool_w, pool_b, zin);

    size_t lstm_lds = (size_t)(64 * 512 + 128 + 128 + 512) * sizeof(float);
    k_lstm<<<BA, 512, lstm_lds, stream>>>(zin, w_ih, w_hh, b_ih, b_hh, done, h_all);

    k_heads<<<S_TOT / 256, 256, 0, stream>>>(h_all, actions, h0w, h0b, h1w, h1b, (float*)d_out);
}

// Round 4
// 1189.733 us; speedup vs baseline: 5.1196x; 5.1196x over previous
//
#include <hip/hip_runtime.h>
#include <hip/hip_bf16.h>
#include <math.h>

#define T_DIM 64
#define B_DIM 32
#define N_ENT 16
#define M_SLOTS 33
#define S_TOT 16384
#define BA 256
#define SB 64

#define ACT_OFF 0
#define LP_OFF 32768
#define ENT_OFF 49152

typedef __attribute__((ext_vector_type(8))) short short8;
typedef __attribute__((ext_vector_type(4))) float f32x4;
typedef unsigned int uint32;

__device__ __forceinline__ float sigf(float x) { return 1.0f / (1.0f + expf(-x)); }
__device__ __forceinline__ float bf2f(unsigned short u) {
    union { unsigned int i; float f; } a; a.i = ((unsigned int)u) << 16; return a.f;
}
__device__ __forceinline__ uint32 pkbf(float a, float b) {
    __hip_bfloat16 ha = __float2bfloat16(a), hb = __float2bfloat16(b);
    return (uint32)(*(unsigned short*)&ha) | ((uint32)(*(unsigned short*)&hb) << 16);
}

// ---------------------------------------------------------------------------
// Kernel A: sample-batched front end (unchanged).
// ---------------------------------------------------------------------------
__global__ __launch_bounds__(256, 1) void k_frontA(
    const float* __restrict__ xag, const float* __restrict__ xlid,
    const float* __restrict__ xsz, const float* __restrict__ xe0,
    const float* __restrict__ xe1,
    const float* __restrict__ conv_w, const float* __restrict__ conv_b,
    const float* __restrict__ self_w, const float* __restrict__ self_b,
    const float* __restrict__ ent0_w, const float* __restrict__ ent0_b,
    const float* __restrict__ ent1_w, const float* __restrict__ ent1_b,
    const float* __restrict__ pool_w,
    __hip_bfloat16* __restrict__ z_ent, float* __restrict__ zin_x)
{
    extern __shared__ float lds[];
    float* xs   = lds;              // [290][64]
    float* ebuf = xs + 290 * 64;    // [192][66]
    float* xp   = ebuf + 192 * 66;  // [64][65]
    float* zbuf = xp + 64 * 65;     // [64][65]

    const int tid = threadIdx.x;
    const int lane = tid & 63;
    const int wv = __builtin_amdgcn_readfirstlane(tid >> 6);
    const int s0 = blockIdx.x * SB;
    float* lid = ebuf;

    for (int i = tid; i < SB * 32; i += 256) {
        int d = i & 31, sl = i >> 5;
        lid[d * 66 + sl] = xlid[(size_t)s0 * 32 + i];
    }
    for (int i = tid; i < SB * 16; i += 256) {
        int d = i & 15, sl = i >> 4;
        xs[d * 64 + sl] = xag[(size_t)s0 * 16 + i];
    }
    for (int i = tid; i < SB * 4; i += 256) {
        int d = i & 3, sl = i >> 2;
        xs[(286 + d) * 64 + sl] = xsz[(size_t)s0 * 4 + i];
    }
    __syncthreads();
    for (int cp = wv; cp < 270; cp += 4) {
        int c = cp / 30, p = cp - c * 30;
        float w0 = conv_w[c * 3], w1 = conv_w[c * 3 + 1], w2 = conv_w[c * 3 + 2];
        float v = conv_b[c] + w0 * lid[p * 66 + lane] + w1 * lid[(p + 1) * 66 + lane]
                + w2 * lid[(p + 2) * 66 + lane];
        xs[(16 + cp) * 64 + lane] = fmaxf(v, 0.0f);
    }
    __syncthreads();

    for (int j = 0; j < 16; ++j) {
        int e = wv * 16 + j;
        const float* w = self_w + (size_t)e * 580;
        float acc = self_b[e];
        for (int d = 0; d < 290; ++d)
            acc = fmaf(w[d] + w[290 + d], xs[d * 64 + lane], acc);
        zbuf[e * 65 + lane] = fmaxf(acc, 0.0f);
    }
    __syncthreads();
    for (int i = tid; i < SB * 64; i += 256) {
        int e = i & 63, sl = i >> 6;
        z_ent[(size_t)(s0 + sl) * 2112 + e] = __float2bfloat16(zbuf[e * 65 + sl]);
    }
    __syncthreads();

    for (int h = 0; h < 2; ++h) {
        for (int j = 0; j < 16; ++j) {
            int r = h * 64 + wv * 16 + j;
            const float* w = pool_w + (size_t)r * 354;
            float acc = 0.0f;
            for (int d = 0; d < 290; ++d) acc = fmaf(w[d], xs[d * 64 + lane], acc);
            zbuf[(r & 63) * 65 + lane] = acc;
        }
        __syncthreads();
        for (int i = tid; i < SB * 64; i += 256) {
            int e = i & 63, sl = i >> 6;
            zin_x[(size_t)(s0 + sl) * 128 + h * 64 + e] = zbuf[e * 65 + sl];
        }
        __syncthreads();
    }

    for (int i = tid; i < SB * 192; i += 256) {
        int sl = i / 192, d = i - sl * 192;
        ebuf[d * 66 + sl] = xe0[(size_t)s0 * 192 + i];
    }
    for (int j = 0; j < 16; ++j) {
        int e = wv * 16 + j;
        const float* w = ent0_w + (size_t)e * 302;
        float acc = ent0_b[e];
        for (int d = 0; d < 290; ++d) acc = fmaf(w[12 + d], xs[d * 64 + lane], acc);
        xp[e * 65 + lane] = acc;
    }
    __syncthreads();
    for (int n = 0; n < 16; ++n) {
        for (int j = 0; j < 16; ++j) {
            int e = wv * 16 + j;
            const float* w = ent0_w + (size_t)e * 302;
            float acc = xp[e * 65 + lane];
            #pragma unroll
            for (int dd = 0; dd < 12; ++dd)
                acc = fmaf(w[dd], ebuf[(n * 12 + dd) * 66 + lane], acc);
            zbuf[e * 65 + lane] = fmaxf(acc, 0.0f);
        }
        __syncthreads();
        for (int i = tid; i < SB * 64; i += 256) {
            int e = i & 63, sl = i >> 6;
            z_ent[(size_t)(s0 + sl) * 2112 + (1 + n) * 64 + e] = __float2bfloat16(zbuf[e * 65 + sl]);
        }
        __syncthreads();
    }

    for (int i = tid; i < SB * 128; i += 256) {
        int sl = i >> 7, d = i & 127;
        ebuf[d * 66 + sl] = xe1[(size_t)s0 * 128 + i];
    }
    for (int j = 0; j < 16; ++j) {
        int e = wv * 16 + j;
        const float* w = ent1_w + (size_t)e * 298;
        float acc = ent1_b[e];
        for (int d = 0; d < 290; ++d) acc = fmaf(w[8 + d], xs[d * 64 + lane], acc);
        xp[e * 65 + lane] = acc;
    }
    __syncthreads();
    for (int n = 0; n < 16; ++n) {
        for (int j = 0; j < 16; ++j) {
            int e = wv * 16 + j;
            const float* w = ent1_w + (size_t)e * 298;
            float acc = xp[e * 65 + lane];
            #pragma unroll
            for (int dd = 0; dd < 8; ++dd)
                acc = fmaf(w[dd], ebuf[(n * 8 + dd) * 66 + lane], acc);
            zbuf[e * 65 + lane] = fmaxf(acc, 0.0f);
        }
        __syncthreads();
        for (int i = tid; i < SB * 64; i += 256) {
            int e = i & 63, sl = i >> 6;
            z_ent[(size_t)(s0 + sl) * 2112 + (17 + n) * 64 + e] = __float2bfloat16(zbuf[e * 65 + sl]);
        }
        __syncthreads();
    }
}

// ---------------------------------------------------------------------------
// k_cvt: one-time f32 -> bf16 weight conversion into ws
// ---------------------------------------------------------------------------
__global__ __launch_bounds__(256) void k_cvt(
    const float* __restrict__ inp_w, const float* __restrict__ outp_w,
    const float* __restrict__ sa_w, short* __restrict__ wq,
    short* __restrict__ wo, short* __restrict__ ws)
{
    int i = blockIdx.x * 256 + threadIdx.x;
    if (i < 12288) { __hip_bfloat16 h = __float2bfloat16(inp_w[i]); wq[i] = *(short*)&h; }
    if (i < 4096) {
        __hip_bfloat16 h = __float2bfloat16(outp_w[i]); wo[i] = *(short*)&h;
        __hip_bfloat16 h2 = __float2bfloat16(sa_w[i]);  ws[i] = *(short*)&h2;
    }
}

// ---------------------------------------------------------------------------
// Kernel C: MFMA attention block. 8192 blocks x 256 thr, 2 samples/block.
// Attention core restructured: ONE (s,h,q) triple per thread (264 triples,
// 8 threads loop twice) -> per-thread live set ~49 floats, no spill.
// ---------------------------------------------------------------------------
#define LDS_ZEB   0
#define LDS_QF    10240
#define LDS_KV    28192
#define LDS_OB    45088
#define LDS_O2B   55328
#define LDS_MSK   65568
#define LDS_POOL  65856
#define LDS_TOTAL 66368

__global__ __launch_bounds__(256, 2) void k_attnC(
    const __hip_bfloat16* __restrict__ z_ent, const float* __restrict__ zin_x_ws,
    const int* __restrict__ mask0, const int* __restrict__ mask1,
    const short* __restrict__ wqkvb, const float* __restrict__ inp_b,
    const short* __restrict__ wob_g, const float* __restrict__ outp_b,
    const short* __restrict__ wsb_g, const float* __restrict__ sa_b,
    const float* __restrict__ pool_w, const float* __restrict__ pool_b,
    float* __restrict__ zin)
{
    extern __shared__ char smem[];
    char*  zeb = smem + LDS_ZEB;
    float* Qf  = (float*)(smem + LDS_QF);
    char*  kvb = smem + LDS_KV;
    char*  ob  = smem + LDS_OB;
    char*  o2b = smem + LDS_O2B;
    float* msk = (float*)(smem + LDS_MSK);
    float* pooled = (float*)(smem + LDS_POOL);
    float* res = Qf;  // alias: Qf dead after attention phase

    const int tid = threadIdx.x;
    const int gs0 = blockIdx.x * 2;

    // ---- stage: zero pad rows; load ze swizzled; mask ----
    for (int i = tid; i < 448; i += 256) {
        ((uint32*)(zeb + 66 * 128))[i] = 0;
        ((uint32*)(ob  + 66 * 128))[i] = 0;
        ((uint32*)(o2b + 66 * 128))[i] = 0;
    }
    {
        const uint32* zsrc = (const uint32*)(z_ent + (size_t)gs0 * 2112);
        for (int i = tid; i < 2112; i += 256) {
            int s = (i >= 1056) ? 1 : 0;
            int idx = i - s * 1056;
            int row = s * 33 + (idx >> 5);
            int c2 = idx & 31;
            int byteo = (row * 128 + c2 * 4) ^ ((row & 7) << 4);
            *(uint32*)(zeb + byteo) = zsrc[i];
        }
    }
    if (tid < 32) { int s = tid >> 4, i2 = tid & 15; msk[s * 36 + 1 + i2] = (float)mask0[(size_t)(gs0 + s) * 16 + i2]; }
    else if (tid < 64) { int u = tid - 32; int s = u >> 4, i2 = u & 15; msk[s * 36 + 17 + i2] = (float)mask1[(size_t)(gs0 + s) * 16 + i2]; }
    else if (tid < 66) msk[(tid - 64) * 36] = 1.0f;
    __syncthreads();

    const int wv = tid >> 6;
    const int l  = tid & 63;
    const int lr = l & 15;    // frag row/col index
    const int lg = l >> 4;    // k-group

    // ---- in_proj GEMM: qkv = ze @ inp_w^T + b ----
    {
        short8 bw[3][2]; float bias[3];
        #pragma unroll
        for (int c = 0; c < 3; ++c) {
            int col = (wv * 3 + c) * 16 + lr;
            bw[c][0] = *(const short8*)(wqkvb + col * 64 + lg * 8);
            bw[c][1] = *(const short8*)(wqkvb + col * 64 + 32 + lg * 8);
            bias[c] = inp_b[col];
        }
        for (int rt = 0; rt < 5; ++rt) {
            int arow = rt * 16 + lr;
            int sw = (arow & 7) << 4;
            short8 a0 = *(const short8*)(zeb + ((arow * 128 + lg * 16) ^ sw));
            short8 a1 = *(const short8*)(zeb + ((arow * 128 + 64 + lg * 16) ^ sw));
            #pragma unroll
            for (int c = 0; c < 3; ++c) {
                f32x4 acc = {0.f, 0.f, 0.f, 0.f};
                acc = __builtin_amdgcn_mfma_f32_16x16x32_bf16(a0, bw[c][0], acc, 0, 0, 0);
                acc = __builtin_amdgcn_mfma_f32_16x16x32_bf16(a1, bw[c][1], acc, 0, 0, 0);
                int ct = wv * 3 + c;
                int col = ct * 16 + lr;
                int rb = rt * 16 + lg * 4;
                if (ct < 4) {
                    #pragma unroll
                    for (int r = 0; r < 4; ++r) {
                        int row = rb + r;
                        if (row < 66) Qf[row * 68 + col] = acc[r] + bias[c];
                    }
                } else {
                    int kc = col - 64;
                    #pragma unroll
                    for (int r = 0; r < 4; ++r) {
                        int row = rb + r;
                        if (row < 66)
                            *(__hip_bfloat16*)(kvb + row * 256 + kc * 2) = __float2bfloat16(acc[r] + bias[c]);
                    }
                }
            }
        }
    }
    __syncthreads();

    // ---- attention core: one (s,h,q) per thread; 264 triples over 256 thr ----
    for (int u = tid; u < 264; u += 256) {
        int s = (u >= 132) ? 1 : 0;
        int v = u - s * 132;
        int q = v >> 2, h = v & 3;
        float qr[16];
        {
            const float4* p = (const float4*)(Qf + (s * 33 + q) * 68 + h * 16);
            #pragma unroll
            for (int j = 0; j < 4; ++j) {
                float4 t = p[j];
                qr[4 * j] = t.x; qr[4 * j + 1] = t.y; qr[4 * j + 2] = t.z; qr[4 * j + 3] = t.w;
            }
        }
        float sc[33]; float mx = -3e38f;
        #pragma unroll
        for (int k = 0; k < 33; ++k) {
            const short8* kp = (const short8*)(kvb + (s * 33 + k) * 256 + h * 32);
            short8 k0 = kp[0], k1 = kp[1];
            float d0 = 0.f;
            #pragma unroll
            for (int j = 0; j < 8; ++j) d0 = fmaf(qr[j], bf2f((unsigned short)k0[j]), d0);
            #pragma unroll
            for (int j = 0; j < 8; ++j) d0 = fmaf(qr[8 + j], bf2f((unsigned short)k1[j]), d0);
            float vv = (msk[s * 36 + k] > 0.f) ? d0 * 0.25f : -1e9f;
            sc[k] = vv; mx = fmaxf(mx, vv);
        }
        float sum = 0.f;
        #pragma unroll
        for (int k = 0; k < 33; ++k) { float e = __expf(sc[k] - mx); sc[k] = e; sum += e; }
        float inv = 1.f / sum;
        float o[16];
        #pragma unroll
        for (int j = 0; j < 16; ++j) o[j] = 0.f;
        #pragma unroll
        for (int k = 0; k < 33; ++k) {
            const short8* vp = (const short8*)(kvb + (s * 33 + k) * 256 + 128 + h * 32);
            short8 v0 = vp[0], v1 = vp[1];
            float p = sc[k];
            #pragma unroll
            for (int j = 0; j < 8; ++j) o[j] = fmaf(p, bf2f((unsigned short)v0[j]), o[j]);
            #pragma unroll
            for (int j = 0; j < 8; ++j) o[8 + j] = fmaf(p, bf2f((unsigned short)v1[j]), o[8 + j]);
        }
        int row = s * 33 + q;
        int base = row * 128 + h * 32;
        int sw = (row & 7) << 4;
        #pragma unroll
        for (int j = 0; j < 8; ++j)
            *(uint32*)(ob + ((base + j * 4) ^ sw)) = pkbf(o[2 * j] * inv, o[2 * j + 1] * inv);
    }
    __syncthreads();

    // ---- out_proj GEMM: o2 = o @ outp_w^T + b -> o2b (bf16) ----
    {
        int col = wv * 16 + lr;
        short8 b0 = *(const short8*)(wob_g + col * 64 + lg * 8);
        short8 b1 = *(const short8*)(wob_g + col * 64 + 32 + lg * 8);
        float bias = outp_b[col];
        for (int rt = 0; rt < 5; ++rt) {
            int arow = rt * 16 + lr;
            int sw = (arow & 7) << 4;
            short8 a0 = *(const short8*)(ob + ((arow * 128 + lg * 16) ^ sw));
            short8 a1 = *(const short8*)(ob + ((arow * 128 + 64 + lg * 16) ^ sw));
            f32x4 acc = {0.f, 0.f, 0.f, 0.f};
            acc = __builtin_amdgcn_mfma_f32_16x16x32_bf16(a0, b0, acc, 0, 0, 0);
            acc = __builtin_amdgcn_mfma_f32_16x16x32_bf16(a1, b1, acc, 0, 0, 0);
            int rb = rt * 16 + lg * 4;
            #pragma unroll
            for (int r = 0; r < 4; ++r) {
                int row = rb + r;
                if (row < 66)
                    *(__hip_bfloat16*)(o2b + ((row * 128 + col * 2) ^ ((row & 7) << 4))) = __float2bfloat16(acc[r] + bias);
            }
        }
    }
    __syncthreads();

    // ---- sa GEMM + residual + mask -> res (f32, aliases Qf) ----
    {
        int col = wv * 16 + lr;
        short8 b0 = *(const short8*)(wsb_g + col * 64 + lg * 8);
        short8 b1 = *(const short8*)(wsb_g + col * 64 + 32 + lg * 8);
        float bias = sa_b[col];
        for (int rt = 0; rt < 5; ++rt) {
            int arow = rt * 16 + lr;
            int sw = (arow & 7) << 4;
            short8 a0 = *(const short8*)(o2b + ((arow * 128 + lg * 16) ^ sw));
            short8 a1 = *(const short8*)(o2b + ((arow * 128 + 64 + lg * 16) ^ sw));
            f32x4 acc = {0.f, 0.f, 0.f, 0.f};
            acc = __builtin_amdgcn_mfma_f32_16x16x32_bf16(a0, b0, acc, 0, 0, 0);
            acc = __builtin_amdgcn_mfma_f32_16x16x32_bf16(a1, b1, acc, 0, 0, 0);
            int rb = rt * 16 + lg * 4;
            #pragma unroll
            for (int r = 0; r < 4; ++r) {
                int row = rb + r;
                if (row < 66) {
                    int ss = (row >= 33) ? 1 : 0;
                    int m = row - ss * 33;
                    float zev = bf2f(*(const unsigned short*)(zeb + ((row * 128 + col * 2) ^ ((row & 7) << 4))));
                    res[row * 68 + col] = msk[ss * 36 + m] * (zev + fmaxf(acc[r] + bias, 0.f));
                }
            }
        }
    }
    __syncthreads();

    // ---- pool ----
    if (tid < 128) {
        int s = tid >> 6, e = tid & 63;
        float acc = 0.f;
        #pragma unroll
        for (int m = 0; m < 33; ++m) acc += res[(s * 33 + m) * 68 + e];
        pooled[s * 64 + e] = acc * (1.0f / 33.0f);
    }
    __syncthreads();

    // ---- zin = relu(zin_x + pool_w[:,290:] @ pooled + b) ----
    {
        int s = tid >> 7, r = tid & 127;
        float acc = pool_b[r] + zin_x_ws[(size_t)(gs0 + s) * 128 + r];
        const float* wrow = pool_w + (size_t)r * 354 + 290;
        const float* pl = pooled + s * 64;
        #pragma unroll 8
        for (int e = 0; e < 64; ++e) acc = fmaf(wrow[e], pl[e], acc);
        zin[(size_t)(gs0 + s) * 128 + r] = fmaxf(acc, 0.f);
    }
}

// ---------------------------------------------------------------------------
// Kernel: LSTM scan (unchanged)
// ---------------------------------------------------------------------------
__global__ __launch_bounds__(512) void k_lstm(
    const float* __restrict__ zin, const float* __restrict__ w_ih,
    const float* __restrict__ w_hh, const float* __restrict__ b_ih,
    const float* __restrict__ b_hh, const int* __restrict__ done,
    float* __restrict__ h_all)
{
    extern __shared__ float lds[];
    float* xp = lds;
    float* zl = xp + 64 * 512;
    float* hl = zl + 128;
    float* gl = hl + 128;
    const int s = blockIdx.x;
    const int r = threadIdx.x;
    const int b = s >> 3;

    float4 w[32];
    {
        const float4* wsrc = (const float4*)(w_ih + (size_t)r * 128);
        #pragma unroll
        for (int j = 0; j < 32; ++j) w[j] = wsrc[j];
    }
    const float bias = b_ih[r] + b_hh[r];

    for (int t = 0; t < T_DIM; ++t) {
        __syncthreads();
        if (r < 128) zl[r] = zin[((size_t)t * BA + s) * 128 + r];
        __syncthreads();
        const float4* x4 = (const float4*)zl;
        float a0 = 0.f, a1 = 0.f, a2 = 0.f, a3 = 0.f;
        #pragma unroll
        for (int j = 0; j < 32; ++j) {
            float4 wa = w[j], xa = x4[j];
            a0 = fmaf(wa.x, xa.x, a0);
            a1 = fmaf(wa.y, xa.y, a1);
            a2 = fmaf(wa.z, xa.z, a2);
            a3 = fmaf(wa.w, xa.w, a3);
        }
        xp[t * 512 + r] = bias + ((a0 + a1) + (a2 + a3));
    }

    {
        const float4* wsrc = (const float4*)(w_hh + (size_t)r * 128);
        #pragma unroll
        for (int j = 0; j < 32; ++j) w[j] = wsrc[j];
    }
    if (r < 128) hl[r] = 0.0f;
    float c = 0.0f;
    __syncthreads();

    for (int t = 0; t < T_DIM; ++t) {
        const float4* h4 = (const float4*)hl;
        float a0 = 0.f, a1 = 0.f, a2 = 0.f, a3 = 0.f;
        #pragma unroll
        for (int j = 0; j < 32; ++j) {
            float4 wa = w[j], xa = h4[j];
            a0 = fmaf(wa.x, xa.x, a0);
            a1 = fmaf(wa.y, xa.y, a1);
            a2 = fmaf(wa.z, xa.z, a2);
            a3 = fmaf(wa.w, xa.w, a3);
        }
        gl[r] = xp[t * 512 + r] + ((a0 + a1) + (a2 + a3));
        __syncthreads();
        if (r < 128) {
            float keep = done[t * B_DIM + b] ? 0.0f : 1.0f;
            float gi = gl[r], gf = gl[r + 128], gg = gl[r + 256], go = gl[r + 384];
            c *= keep;
            c = sigf(gf) * c + sigf(gi) * tanhf(gg);
            float hn = sigf(go) * tanhf(c);
            float keepn = (t < T_DIM - 1) ? (done[(t + 1) * B_DIM + b] ? 0.0f : 1.0f) : 1.0f;
            hl[r] = hn * keepn;
            h_all[((size_t)t * BA + s) * 128 + r] = hn;
        }
        __syncthreads();
    }
}

// ---------------------------------------------------------------------------
// Kernel: categorical heads (unchanged)
// ---------------------------------------------------------------------------
__global__ __launch_bounds__(256) void k_heads(
    const float* __restrict__ h_all, const int* __restrict__ actions,
    const float* __restrict__ h0w, const float* __restrict__ h0b,
    const float* __restrict__ h1w, const float* __restrict__ h1b,
    float* __restrict__ out)
{
    __shared__ float w0[640], w1[640], b0[8], b1[8];
    const int tid = threadIdx.x;
    for (int i = tid; i < 640; i += 256) { w0[i] = h0w[i]; w1[i] = h1w[i]; }
    if (tid < 5) { b0[tid] = h0b[tid]; b1[tid] = h1b[tid]; }
    __syncthreads();
    const int g = blockIdx.x * 256 + tid;
    const float* h = h_all + (size_t)g * 128;
    float l0[5], l1[5];
    #pragma unroll
    for (int cc = 0; cc < 5; ++cc) { l0[cc] = b0[cc]; l1[cc] = b1[cc]; }
    for (int j = 0; j < 128; ++j) {
        float hv = h[j];
        #pragma unroll
        for (int cc = 0; cc < 5; ++cc) {
            l0[cc] = fmaf(w0[cc * 128 + j], hv, l0[cc]);
            l1[cc] = fmaf(w1[cc * 128 + j], hv, l1[cc]);
        }
    }
    int a0 = actions[(size_t)g * 2], a1 = actions[(size_t)g * 2 + 1];
    float m0 = l0[0], m1 = l1[0];
    #pragma unroll
    for (int cc = 1; cc < 5; ++cc) { m0 = fmaxf(m0, l0[cc]); m1 = fmaxf(m1, l1[cc]); }
    float s0 = 0.f, s1 = 0.f;
    #pragma unroll
    for (int cc = 0; cc < 5; ++cc) { s0 += expf(l0[cc] - m0); s1 += expf(l1[cc] - m1); }
    float lse0 = m0 + logf(s0), lse1 = m1 + logf(s1);
    float ent0 = 0.f, ent1 = 0.f, lp0 = 0.f, lp1 = 0.f;
    #pragma unroll
    for (int cc = 0; cc < 5; ++cc) {
        float p0 = l0[cc] - lse0, p1 = l1[cc] - lse1;
        ent0 -= expf(p0) * p0;
        ent1 -= expf(p1) * p1;
        if (cc == a0) lp0 = p0;
        if (cc == a1) lp1 = p1;
    }
    out[ACT_OFF + (size_t)g * 2]     = (float)a0;
    out[ACT_OFF + (size_t)g * 2 + 1] = (float)a1;
    out[LP_OFF + g]                  = lp0 * lp1;
    out[ENT_OFF + (size_t)g * 2]     = ent0;
    out[ENT_OFF + (size_t)g * 2 + 1] = ent1;
}

extern "C" void kernel_launch(void* const* d_in, const int* in_sizes, int n_in,
                              void* d_out, int out_size, void* d_ws, size_t ws_size,
                              hipStream_t stream)
{
    const float* x_agent = (const float*)d_in[0];
    const float* x_lidar = (const float*)d_in[1];
    const float* x_safe  = (const float*)d_in[2];
    const float* x_ent0  = (const float*)d_in[3];
    const float* x_ent1  = (const float*)d_in[4];
    const int*   mask0   = (const int*)d_in[5];
    const int*   mask1   = (const int*)d_in[6];
    const int*   done    = (const int*)d_in[7];
    const int*   actions = (const int*)d_in[8];
    const float* conv_w  = (const float*)d_in[9];
    const float* conv_b  = (const float*)d_in[10];
    const float* self_w  = (const float*)d_in[11];
    const float* self_b  = (const float*)d_in[12];
    const float* ent0_w  = (const float*)d_in[13];
    const float* ent0_b  = (const float*)d_in[14];
    const float* ent1_w  = (const float*)d_in[15];
    const float* ent1_b  = (const float*)d_in[16];
    const float* inp_w   = (const float*)d_in[17];
    const float* inp_b   = (const float*)d_in[18];
    const float* outp_w  = (const float*)d_in[19];
    const float* outp_b  = (const float*)d_in[20];
    const float* sa_w    = (const float*)d_in[21];
    const float* sa_b    = (const float*)d_in[22];
    const float* pool_w  = (const float*)d_in[23];
    const float* pool_b  = (const float*)d_in[24];
    const float* w_ih    = (const float*)d_in[25];
    const float* w_hh    = (const float*)d_in[26];
    const float* b_ih    = (const float*)d_in[27];
    const float* b_hh    = (const float*)d_in[28];
    const float* h0w     = (const float*)d_in[29];
    const float* h0b     = (const float*)d_in[30];
    const float* h1w     = (const float*)d_in[31];
    const float* h1b     = (const float*)d_in[32];

    __hip_bfloat16* z_ent = (__hip_bfloat16*)d_ws;
    float* zin_x = (float*)((char*)d_ws + (size_t)S_TOT * 2112 * 2);
    float* zin   = zin_x + (size_t)S_TOT * 128;
    float* h_all = zin + (size_t)S_TOT * 128;
    short* wqkvb = (short*)(h_all + (size_t)S_TOT * 128);
    short* wob   = wqkvb + 12288;
    short* wsb   = wob + 4096;

    size_t ldsA = (size_t)(290 * 64 + 192 * 66 + 64 * 65 + 64 * 65) * sizeof(float);
    k_frontA<<<S_TOT / SB, 256, ldsA, stream>>>(
        x_agent, x_lidar, x_safe, x_ent0, x_ent1,
        conv_w, conv_b, self_w, self_b, ent0_w, ent0_b, ent1_w, ent1_b,
        pool_w, z_ent, zin_x);

    k_cvt<<<48, 256, 0, stream>>>(inp_w, outp_w, sa_w, wqkvb, wob, wsb);

    k_attnC<<<S_TOT / 2, 256, LDS_TOTAL, stream>>>(
        z_ent, zin_x, mask0, mask1, wqkvb, inp_b, wob, outp_b,
        wsb, sa_b, pool_w, pool_b, zin);

    size_t lstm_lds = (size_t)(64 * 512 + 128 + 128 + 512) * sizeof(float);
    k_lstm<<<BA, 512, lstm_lds, stream>>>(zin, w_ih, w_hh, b_ih, b_hh, done, h_all);

    k_heads<<<S_TOT / 256, 256, 0, stream>>>(h_all, actions, h0w, h0b, h1w, h1b, (float*)d_out);
}

// Round 5
// 670.432 us; speedup vs baseline: 9.0850x; 1.7746x over previous
//
#include <hip/hip_runtime.h>
#include <hip/hip_bf16.h>
#include <math.h>

#define T_DIM 64
#define B_DIM 32
#define N_ENT 16
#define M_SLOTS 33
#define S_TOT 16384
#define BA 256
#define SB 64

#define ACT_OFF 0
#define LP_OFF 32768
#define ENT_OFF 49152

typedef __attribute__((ext_vector_type(8))) short short8;
typedef __attribute__((ext_vector_type(4))) float f32x4;
typedef unsigned int uint32;

__device__ __forceinline__ float sigf(float x) { return 1.0f / (1.0f + expf(-x)); }
__device__ __forceinline__ float bf2f(unsigned short u) {
    union { unsigned int i; float f; } a; a.i = ((unsigned int)u) << 16; return a.f;
}
__device__ __forceinline__ uint32 pkbf(float a, float b) {
    __hip_bfloat16 ha = __float2bfloat16(a), hb = __float2bfloat16(b);
    return (uint32)(*(unsigned short*)&ha) | ((uint32)(*(unsigned short*)&hb) << 16);
}
__device__ __forceinline__ short f2bs(float v) {
    __hip_bfloat16 h = __float2bfloat16(v); return *(short*)&h;
}

// ---------------------------------------------------------------------------
// k_cvt2: pack all MFMA weights to bf16 in ws.
// Wf [320 cols][320 K]: 0-63 self-fold | 64-191 pool[:, :290] | 192-255 ent0
// xs-part | 256-319 ent1 xs-part. K 290-319 zero.
// We0/We1 [64][16]: entity-feature parts, K-padded with zeros.
// ---------------------------------------------------------------------------
__global__ __launch_bounds__(256) void k_cvt2(
    const float* __restrict__ inp_w, const float* __restrict__ outp_w,
    const float* __restrict__ sa_w, const float* __restrict__ self_w,
    const float* __restrict__ pool_w, const float* __restrict__ ent0_w,
    const float* __restrict__ ent1_w,
    short* __restrict__ wq, short* __restrict__ wo, short* __restrict__ ws,
    short* __restrict__ Wf, short* __restrict__ We0, short* __restrict__ We1)
{
    int i = blockIdx.x * 256 + threadIdx.x;
    if (i < 12288) wq[i] = f2bs(inp_w[i]);
    if (i < 4096) { wo[i] = f2bs(outp_w[i]); ws[i] = f2bs(sa_w[i]); }
    if (i < 1024) {
        int e = i >> 4, k = i & 15;
        We0[i] = f2bs(k < 12 ? ent0_w[e * 302 + k] : 0.f);
        We1[i] = f2bs(k < 8 ? ent1_w[e * 298 + k] : 0.f);
    }
    if (i < 102400) {
        int c = i / 320, k = i - c * 320;
        float v = 0.f;
        if (k < 290) {
            if (c < 64) v = self_w[c * 580 + k] + self_w[c * 580 + 290 + k];
            else if (c < 192) v = pool_w[(size_t)(c - 64) * 354 + k];
            else if (c < 256) v = ent0_w[(c - 192) * 302 + 12 + k];
            else v = ent1_w[(c - 256) * 298 + 8 + k];
        }
        Wf[i] = f2bs(v);
    }
}

// ---------------------------------------------------------------------------
// k_frontM: MFMA front end. 256 blocks x 256 thr, 64 samples/block, 1 blk/CU.
// Phase 1: [64 x 320] @ Wf^T [320 x 320] -> z_self / zin_x / xp0 / xp1
// Phase 2: entity MLPs as [1024 x 32] @ We^T [32 x 64] MFMA.
// LDS: xsb bf16 [64][320] swz (40960) | xp0 f32 [64][68] (17408) |
//      xp1 (17408) | ae bf16 [1024][32] swz (65536, aliases lid f32[32][66])
// ---------------------------------------------------------------------------
#define FM_XSB 0
#define FM_XP0 40960
#define FM_XP1 58368
#define FM_AE  75776
#define FM_TOTAL 141312

__global__ __launch_bounds__(256, 1) void k_frontM(
    const float* __restrict__ xag, const float* __restrict__ xlid,
    const float* __restrict__ xsz, const float* __restrict__ xe0,
    const float* __restrict__ xe1,
    const float* __restrict__ conv_w, const float* __restrict__ conv_b,
    const float* __restrict__ self_b, const float* __restrict__ ent0_b,
    const float* __restrict__ ent1_b,
    const short* __restrict__ Wf, const short* __restrict__ We0,
    const short* __restrict__ We1,
    __hip_bfloat16* __restrict__ z_ent, float* __restrict__ zin_x)
{
    extern __shared__ char smem[];
    char* xsb = smem + FM_XSB;
    float* xp0f = (float*)(smem + FM_XP0);
    float* xp1f = (float*)(smem + FM_XP1);
    char* ae = smem + FM_AE;
    float* lidf = (float*)(smem + FM_AE);   // alias, dead after conv

    const int tid = threadIdx.x;
    const int s0 = blockIdx.x * SB;
    const int wv = __builtin_amdgcn_readfirstlane(tid >> 6);
    const int l = tid & 63;
    const int lr = l & 15;
    const int lg = l >> 4;

    // ---- stage inputs ----
    for (int i = tid; i < SB * 32; i += 256) {           // lidar -> f32 [32][66]
        int d = i & 31, sl = i >> 5;
        lidf[d * 66 + sl] = xlid[(size_t)s0 * 32 + i];
    }
    for (int i = tid; i < SB * 16; i += 256) {           // x_agent -> xsb[sl][0..15]
        int sl = i >> 4, d = i & 15;
        *(short*)(xsb + ((sl * 640 + d * 2) ^ ((sl & 7) << 4))) = f2bs(xag[(size_t)s0 * 16 + i]);
    }
    for (int i = tid; i < SB * 4; i += 256) {            // safe -> xsb[sl][286..289]
        int sl = i >> 2, d = i & 3;
        *(short*)(xsb + ((sl * 640 + (286 + d) * 2) ^ ((sl & 7) << 4))) = f2bs(xsz[(size_t)s0 * 4 + i]);
    }
    for (int i = tid; i < SB * 30; i += 256) {           // K pad 290..319 = 0
        int sl = i / 30, d = 290 + (i - (i / 30) * 30);
        *(short*)(xsb + ((sl * 640 + d * 2) ^ ((sl & 7) << 4))) = 0;
    }
    __syncthreads();
    // ---- conv -> xsb[sl][16+cp] ----
    for (int i = tid; i < 270 * 64; i += 256) {
        int cp = i >> 6, sl = i & 63;
        int c = cp / 30, p = cp - c * 30;
        float v = conv_b[c] + conv_w[c * 3] * lidf[p * 66 + sl]
                + conv_w[c * 3 + 1] * lidf[(p + 1) * 66 + sl]
                + conv_w[c * 3 + 2] * lidf[(p + 2) * 66 + sl];
        *(short*)(xsb + ((sl * 640 + (16 + cp) * 2) ^ ((sl & 7) << 4))) = f2bs(fmaxf(v, 0.f));
    }
    __syncthreads();

    // ---- Phase 1 GEMM: acc[rt 0..3][c 0..4], wave wv owns col-tiles wv*5+c ----
    f32x4 acc[4][5];
    #pragma unroll
    for (int rt = 0; rt < 4; ++rt)
        #pragma unroll
        for (int c = 0; c < 5; ++c) acc[rt][c] = (f32x4){0.f, 0.f, 0.f, 0.f};

    for (int kk = 0; kk < 10; ++kk) {
        short8 af[4];
        #pragma unroll
        for (int rt = 0; rt < 4; ++rt) {
            int row = rt * 16 + lr;
            af[rt] = *(const short8*)(xsb + ((row * 640 + kk * 64 + lg * 16) ^ ((row & 7) << 4)));
        }
        short8 bf[5];
        #pragma unroll
        for (int c = 0; c < 5; ++c) {
            int col = (wv * 5 + c) * 16 + lr;
            bf[c] = *(const short8*)(Wf + (size_t)col * 320 + kk * 32 + lg * 8);
        }
        #pragma unroll
        for (int rt = 0; rt < 4; ++rt)
            #pragma unroll
            for (int c = 0; c < 5; ++c)
                acc[rt][c] = __builtin_amdgcn_mfma_f32_16x16x32_bf16(af[rt], bf[c], acc[rt][c], 0, 0, 0);
    }

    // zero ae (entity A-tile) while accs settle; lid is dead now
    for (int i = tid; i < 16384; i += 256) ((uint32*)ae)[i] = 0;

    // ---- Phase 1 epilogue ----
    #pragma unroll
    for (int rt = 0; rt < 4; ++rt) {
        #pragma unroll
        for (int c = 0; c < 5; ++c) {
            int ct = wv * 5 + c;
            int gc = ct * 16 + lr;
            int rowb = rt * 16 + lg * 4;
            f32x4 a = acc[rt][c];
            if (ct * 16 < 64) {                    // z_self -> z_ent slot 0
                float bias = self_b[gc];
                #pragma unroll
                for (int r = 0; r < 4; ++r)
                    z_ent[(size_t)(s0 + rowb + r) * 2112 + gc] = __float2bfloat16(fmaxf(a[r] + bias, 0.f));
            } else if (ct * 16 < 192) {            // pool xs-part (raw)
                int r2 = gc - 64;
                #pragma unroll
                for (int r = 0; r < 4; ++r)
                    zin_x[(size_t)(s0 + rowb + r) * 128 + r2] = a[r];
            } else if (ct * 16 < 256) {            // ent0 xs-part + bias
                float bias = ent0_b[gc - 192];
                #pragma unroll
                for (int r = 0; r < 4; ++r)
                    xp0f[(rowb + r) * 68 + (gc - 192)] = a[r] + bias;
            } else {                               // ent1 xs-part + bias
                float bias = ent1_b[gc - 256];
                #pragma unroll
                for (int r = 0; r < 4; ++r)
                    xp1f[(rowb + r) * 68 + (gc - 256)] = a[r] + bias;
            }
        }
    }
    __syncthreads();

    // ---- stage ent0 features: ae[sl*16+n][k<12] (rest zero) ----
    for (int i = tid; i < SB * 192; i += 256) {
        int sl = i / 192, r = i - sl * 192;
        int n = r / 12, d = r - n * 12;
        int row = sl * 16 + n;
        *(short*)(ae + ((row * 64 + d * 2) ^ ((row & 3) << 4))) = f2bs(xe0[(size_t)s0 * 192 + i]);
    }
    __syncthreads();

    // ---- ent0 MFMA: wave wv -> row-tiles wv*16..wv*16+15 ----
    {
        short8 bz = {0, 0, 0, 0, 0, 0, 0, 0};
        short8 be[4];
        #pragma unroll
        for (int ct = 0; ct < 4; ++ct) {
            int col = ct * 16 + lr;
            short8 bv = *(const short8*)(We0 + col * 16 + (lg & 1) * 8);
            be[ct] = (lg < 2) ? bv : bz;
        }
        for (int rt8 = 0; rt8 < 16; ++rt8) {
            int rt = wv * 16 + rt8;             // rt == sample
            int row = rt * 16 + lr;
            short8 af = *(const short8*)(ae + ((row * 64 + lg * 16) ^ ((row & 3) << 4)));
            #pragma unroll
            for (int ct = 0; ct < 4; ++ct) {
                f32x4 a2 = {0.f, 0.f, 0.f, 0.f};
                a2 = __builtin_amdgcn_mfma_f32_16x16x32_bf16(af, be[ct], a2, 0, 0, 0);
                int e = ct * 16 + lr;
                float xpv = xp0f[rt * 68 + e];
                #pragma unroll
                for (int r = 0; r < 4; ++r) {
                    int n = lg * 4 + r;
                    z_ent[(size_t)(s0 + rt) * 2112 + (1 + n) * 64 + e] =
                        __float2bfloat16(fmaxf(a2[r] + xpv, 0.f));
                }
            }
        }
    }
    __syncthreads();

    // ---- stage ent1 features: cols 0-7 data, 8-11 zero (12-31 still zero) ----
    for (int i = tid; i < SB * 128; i += 256) {
        int sl = i >> 7, r = i & 127;
        int n = r >> 3, d = r & 7;
        int row = sl * 16 + n;
        *(short*)(ae + ((row * 64 + d * 2) ^ ((row & 3) << 4))) = f2bs(xe1[(size_t)s0 * 128 + i]);
    }
    for (int i = tid; i < SB * 16 * 4; i += 256) {
        int row = i >> 2, d = 8 + (i & 3);
        *(short*)(ae + ((row * 64 + d * 2) ^ ((row & 3) << 4))) = 0;
    }
    __syncthreads();

    // ---- ent1 MFMA ----
    {
        short8 bz = {0, 0, 0, 0, 0, 0, 0, 0};
        short8 be[4];
        #pragma unroll
        for (int ct = 0; ct < 4; ++ct) {
            int col = ct * 16 + lr;
            short8 bv = *(const short8*)(We1 + col * 16 + (lg & 1) * 8);
            be[ct] = (lg < 2) ? bv : bz;
        }
        for (int rt8 = 0; rt8 < 16; ++rt8) {
            int rt = wv * 16 + rt8;
            int row = rt * 16 + lr;
            short8 af = *(const short8*)(ae + ((row * 64 + lg * 16) ^ ((row & 3) << 4)));
            #pragma unroll
            for (int ct = 0; ct < 4; ++ct) {
                f32x4 a2 = {0.f, 0.f, 0.f, 0.f};
                a2 = __builtin_amdgcn_mfma_f32_16x16x32_bf16(af, be[ct], a2, 0, 0, 0);
                int e = ct * 16 + lr;
                float xpv = xp1f[rt * 68 + e];
                #pragma unroll
                for (int r = 0; r < 4; ++r) {
                    int n = lg * 4 + r;
                    z_ent[(size_t)(s0 + rt) * 2112 + (17 + n) * 64 + e] =
                        __float2bfloat16(fmaxf(a2[r] + xpv, 0.f));
                }
            }
        }
    }
}

// ---------------------------------------------------------------------------
// Kernel C: MFMA attention block (unchanged from round 4).
// ---------------------------------------------------------------------------
#define LDS_ZEB   0
#define LDS_QF    10240
#define LDS_KV    28192
#define LDS_OB    45088
#define LDS_O2B   55328
#define LDS_MSK   65568
#define LDS_POOL  65856
#define LDS_TOTAL 66368

__global__ __launch_bounds__(256, 2) void k_attnC(
    const __hip_bfloat16* __restrict__ z_ent, const float* __restrict__ zin_x_ws,
    const int* __restrict__ mask0, const int* __restrict__ mask1,
    const short* __restrict__ wqkvb, const float* __restrict__ inp_b,
    const short* __restrict__ wob_g, const float* __restrict__ outp_b,
    const short* __restrict__ wsb_g, const float* __restrict__ sa_b,
    const float* __restrict__ pool_w, const float* __restrict__ pool_b,
    float* __restrict__ zin)
{
    extern __shared__ char smem[];
    char*  zeb = smem + LDS_ZEB;
    float* Qf  = (float*)(smem + LDS_QF);
    char*  kvb = smem + LDS_KV;
    char*  ob  = smem + LDS_OB;
    char*  o2b = smem + LDS_O2B;
    float* msk = (float*)(smem + LDS_MSK);
    float* pooled = (float*)(smem + LDS_POOL);
    float* res = Qf;

    const int tid = threadIdx.x;
    const int gs0 = blockIdx.x * 2;

    for (int i = tid; i < 448; i += 256) {
        ((uint32*)(zeb + 66 * 128))[i] = 0;
        ((uint32*)(ob  + 66 * 128))[i] = 0;
        ((uint32*)(o2b + 66 * 128))[i] = 0;
    }
    {
        const uint32* zsrc = (const uint32*)(z_ent + (size_t)gs0 * 2112);
        for (int i = tid; i < 2112; i += 256) {
            int s = (i >= 1056) ? 1 : 0;
            int idx = i - s * 1056;
            int row = s * 33 + (idx >> 5);
            int c2 = idx & 31;
            int byteo = (row * 128 + c2 * 4) ^ ((row & 7) << 4);
            *(uint32*)(zeb + byteo) = zsrc[i];
        }
    }
    if (tid < 32) { int s = tid >> 4, i2 = tid & 15; msk[s * 36 + 1 + i2] = (float)mask0[(size_t)(gs0 + s) * 16 + i2]; }
    else if (tid < 64) { int u = tid - 32; int s = u >> 4, i2 = u & 15; msk[s * 36 + 17 + i2] = (float)mask1[(size_t)(gs0 + s) * 16 + i2]; }
    else if (tid < 66) msk[(tid - 64) * 36] = 1.0f;
    __syncthreads();

    const int wv = tid >> 6;
    const int l  = tid & 63;
    const int lr = l & 15;
    const int lg = l >> 4;

    {
        short8 bw[3][2]; float bias[3];
        #pragma unroll
        for (int c = 0; c < 3; ++c) {
            int col = (wv * 3 + c) * 16 + lr;
            bw[c][0] = *(const short8*)(wqkvb + col * 64 + lg * 8);
            bw[c][1] = *(const short8*)(wqkvb + col * 64 + 32 + lg * 8);
            bias[c] = inp_b[col];
        }
        for (int rt = 0; rt < 5; ++rt) {
            int arow = rt * 16 + lr;
            int sw = (arow & 7) << 4;
            short8 a0 = *(const short8*)(zeb + ((arow * 128 + lg * 16) ^ sw));
            short8 a1 = *(const short8*)(zeb + ((arow * 128 + 64 + lg * 16) ^ sw));
            #pragma unroll
            for (int c = 0; c < 3; ++c) {
                f32x4 acc = {0.f, 0.f, 0.f, 0.f};
                acc = __builtin_amdgcn_mfma_f32_16x16x32_bf16(a0, bw[c][0], acc, 0, 0, 0);
                acc = __builtin_amdgcn_mfma_f32_16x16x32_bf16(a1, bw[c][1], acc, 0, 0, 0);
                int ct = wv * 3 + c;
                int col = ct * 16 + lr;
                int rb = rt * 16 + lg * 4;
                if (ct < 4) {
                    #pragma unroll
                    for (int r = 0; r < 4; ++r) {
                        int row = rb + r;
                        if (row < 66) Qf[row * 68 + col] = acc[r] + bias[c];
                    }
                } else {
                    int kc = col - 64;
                    #pragma unroll
                    for (int r = 0; r < 4; ++r) {
                        int row = rb + r;
                        if (row < 66)
                            *(__hip_bfloat16*)(kvb + row * 256 + kc * 2) = __float2bfloat16(acc[r] + bias[c]);
                    }
                }
            }
        }
    }
    __syncthreads();

    for (int u = tid; u < 264; u += 256) {
        int s = (u >= 132) ? 1 : 0;
        int v = u - s * 132;
        int q = v >> 2, h = v & 3;
        float qr[16];
        {
            const float4* p = (const float4*)(Qf + (s * 33 + q) * 68 + h * 16);
            #pragma unroll
            for (int j = 0; j < 4; ++j) {
                float4 t = p[j];
                qr[4 * j] = t.x; qr[4 * j + 1] = t.y; qr[4 * j + 2] = t.z; qr[4 * j + 3] = t.w;
            }
        }
        float sc[33]; float mx = -3e38f;
        #pragma unroll
        for (int k = 0; k < 33; ++k) {
            const short8* kp = (const short8*)(kvb + (s * 33 + k) * 256 + h * 32);
            short8 k0 = kp[0], k1 = kp[1];
            float d0 = 0.f;
            #pragma unroll
            for (int j = 0; j < 8; ++j) d0 = fmaf(qr[j], bf2f((unsigned short)k0[j]), d0);
            #pragma unroll
            for (int j = 0; j < 8; ++j) d0 = fmaf(qr[8 + j], bf2f((unsigned short)k1[j]), d0);
            float vv = (msk[s * 36 + k] > 0.f) ? d0 * 0.25f : -1e9f;
            sc[k] = vv; mx = fmaxf(mx, vv);
        }
        float sum = 0.f;
        #pragma unroll
        for (int k = 0; k < 33; ++k) { float e = __expf(sc[k] - mx); sc[k] = e; sum += e; }
        float inv = 1.f / sum;
        float o[16];
        #pragma unroll
        for (int j = 0; j < 16; ++j) o[j] = 0.f;
        #pragma unroll
        for (int k = 0; k < 33; ++k) {
            const short8* vp = (const short8*)(kvb + (s * 33 + k) * 256 + 128 + h * 32);
            short8 v0 = vp[0], v1 = vp[1];
            float p = sc[k];
            #pragma unroll
            for (int j = 0; j < 8; ++j) o[j] = fmaf(p, bf2f((unsigned short)v0[j]), o[j]);
            #pragma unroll
            for (int j = 0; j < 8; ++j) o[8 + j] = fmaf(p, bf2f((unsigned short)v1[j]), o[8 + j]);
        }
        int row = s * 33 + q;
        int base = row * 128 + h * 32;
        int sw = (row & 7) << 4;
        #pragma unroll
        for (int j = 0; j < 8; ++j)
            *(uint32*)(ob + ((base + j * 4) ^ sw)) = pkbf(o[2 * j] * inv, o[2 * j + 1] * inv);
    }
    __syncthreads();

    {
        int col = wv * 16 + lr;
        short8 b0 = *(const short8*)(wob_g + col * 64 + lg * 8);
        short8 b1 = *(const short8*)(wob_g + col * 64 + 32 + lg * 8);
        float bias = outp_b[col];
        for (int rt = 0; rt < 5; ++rt) {
            int arow = rt * 16 + lr;
            int sw = (arow & 7) << 4;
            short8 a0 = *(const short8*)(ob + ((arow * 128 + lg * 16) ^ sw));
            short8 a1 = *(const short8*)(ob + ((arow * 128 + 64 + lg * 16) ^ sw));
            f32x4 acc = {0.f, 0.f, 0.f, 0.f};
            acc = __builtin_amdgcn_mfma_f32_16x16x32_bf16(a0, b0, acc, 0, 0, 0);
            acc = __builtin_amdgcn_mfma_f32_16x16x32_bf16(a1, b1, acc, 0, 0, 0);
            int rb = rt * 16 + lg * 4;
            #pragma unroll
            for (int r = 0; r < 4; ++r) {
                int row = rb + r;
                if (row < 66)
                    *(__hip_bfloat16*)(o2b + ((row * 128 + col * 2) ^ ((row & 7) << 4))) = __float2bfloat16(acc[r] + bias);
            }
        }
    }
    __syncthreads();

    {
        int col = wv * 16 + lr;
        short8 b0 = *(const short8*)(wsb_g + col * 64 + lg * 8);
        short8 b1 = *(const short8*)(wsb_g + col * 64 + 32 + lg * 8);
        float bias = sa_b[col];
        for (int rt = 0; rt < 5; ++rt) {
            int arow = rt * 16 + lr;
            int sw = (arow & 7) << 4;
            short8 a0 = *(const short8*)(o2b + ((arow * 128 + lg * 16) ^ sw));
            short8 a1 = *(const short8*)(o2b + ((arow * 128 + 64 + lg * 16) ^ sw));
            f32x4 acc = {0.f, 0.f, 0.f, 0.f};
            acc = __builtin_amdgcn_mfma_f32_16x16x32_bf16(a0, b0, acc, 0, 0, 0);
            acc = __builtin_amdgcn_mfma_f32_16x16x32_bf16(a1, b1, acc, 0, 0, 0);
            int rb = rt * 16 + lg * 4;
            #pragma unroll
            for (int r = 0; r < 4; ++r) {
                int row = rb + r;
                if (row < 66) {
                    int ss = (row >= 33) ? 1 : 0;
                    int m = row - ss * 33;
                    float zev = bf2f(*(const unsigned short*)(zeb + ((row * 128 + col * 2) ^ ((row & 7) << 4))));
                    res[row * 68 + col] = msk[ss * 36 + m] * (zev + fmaxf(acc[r] + bias, 0.f));
                }
            }
        }
    }
    __syncthreads();

    if (tid < 128) {
        int s = tid >> 6, e = tid & 63;
        float acc = 0.f;
        #pragma unroll
        for (int m = 0; m < 33; ++m) acc += res[(s * 33 + m) * 68 + e];
        pooled[s * 64 + e] = acc * (1.0f / 33.0f);
    }
    __syncthreads();

    {
        int s = tid >> 7, r = tid & 127;
        float acc = pool_b[r] + zin_x_ws[(size_t)(gs0 + s) * 128 + r];
        const float* wrow = pool_w + (size_t)r * 354 + 290;
        const float* pl = pooled + s * 64;
        #pragma unroll 8
        for (int e = 0; e < 64; ++e) acc = fmaf(wrow[e], pl[e], acc);
        zin[(size_t)(gs0 + s) * 128 + r] = fmaxf(acc, 0.f);
    }
}

// ---------------------------------------------------------------------------
// Kernel: LSTM scan (unchanged)
// ---------------------------------------------------------------------------
__global__ __launch_bounds__(512) void k_lstm(
    const float* __restrict__ zin, const float* __restrict__ w_ih,
    const float* __restrict__ w_hh, const float* __restrict__ b_ih,
    const float* __restrict__ b_hh, const int* __restrict__ done,
    float* __restrict__ h_all)
{
    extern __shared__ float lds[];
    float* xp = lds;
    float* zl = xp + 64 * 512;
    float* hl = zl + 128;
    float* gl = hl + 128;
    const int s = blockIdx.x;
    const int r = threadIdx.x;
    const int b = s >> 3;

    float4 w[32];
    {
        const float4* wsrc = (const float4*)(w_ih + (size_t)r * 128);
        #pragma unroll
        for (int j = 0; j < 32; ++j) w[j] = wsrc[j];
    }
    const float bias = b_ih[r] + b_hh[r];

    for (int t = 0; t < T_DIM; ++t) {
        __syncthreads();
        if (r < 128) zl[r] = zin[((size_t)t * BA + s) * 128 + r];
        __syncthreads();
        const float4* x4 = (const float4*)zl;
        float a0 = 0.f, a1 = 0.f, a2 = 0.f, a3 = 0.f;
        #pragma unroll
        for (int j = 0; j < 32; ++j) {
            float4 wa = w[j], xa = x4[j];
            a0 = fmaf(wa.x, xa.x, a0);
            a1 = fmaf(wa.y, xa.y, a1);
            a2 = fmaf(wa.z, xa.z, a2);
            a3 = fmaf(wa.w, xa.w, a3);
        }
        xp[t * 512 + r] = bias + ((a0 + a1) + (a2 + a3));
    }

    {
        const float4* wsrc = (const float4*)(w_hh + (size_t)r * 128);
        #pragma unroll
        for (int j = 0; j < 32; ++j) w[j] = wsrc[j];
    }
    if (r < 128) hl[r] = 0.0f;
    float c = 0.0f;
    __syncthreads();

    for (int t = 0; t < T_DIM; ++t) {
        const float4* h4 = (const float4*)hl;
        float a0 = 0.f, a1 = 0.f, a2 = 0.f, a3 = 0.f;
        #pragma unroll
        for (int j = 0; j < 32; ++j) {
            float4 wa = w[j], xa = h4[j];
            a0 = fmaf(wa.x, xa.x, a0);
            a1 = fmaf(wa.y, xa.y, a1);
            a2 = fmaf(wa.z, xa.z, a2);
            a3 = fmaf(wa.w, xa.w, a3);
        }
        gl[r] = xp[t * 512 + r] + ((a0 + a1) + (a2 + a3));
        __syncthreads();
        if (r < 128) {
            float keep = done[t * B_DIM + b] ? 0.0f : 1.0f;
            float gi = gl[r], gf = gl[r + 128], gg = gl[r + 256], go = gl[r + 384];
            c *= keep;
            c = sigf(gf) * c + sigf(gi) * tanhf(gg);
            float hn = sigf(go) * tanhf(c);
            float keepn = (t < T_DIM - 1) ? (done[(t + 1) * B_DIM + b] ? 0.0f : 1.0f) : 1.0f;
            hl[r] = hn * keepn;
            h_all[((size_t)t * BA + s) * 128 + r] = hn;
        }
        __syncthreads();
    }
}

// ---------------------------------------------------------------------------
// Kernel: categorical heads (unchanged)
// ---------------------------------------------------------------------------
__global__ __launch_bounds__(256) void k_heads(
    const float* __restrict__ h_all, const int* __restrict__ actions,
    const float* __restrict__ h0w, const float* __restrict__ h0b,
    const float* __restrict__ h1w, const float* __restrict__ h1b,
    float* __restrict__ out)
{
    __shared__ float w0[640], w1[640], b0[8], b1[8];
    const int tid = threadIdx.x;
    for (int i = tid; i < 640; i += 256) { w0[i] = h0w[i]; w1[i] = h1w[i]; }
    if (tid < 5) { b0[tid] = h0b[tid]; b1[tid] = h1b[tid]; }
    __syncthreads();
    const int g = blockIdx.x * 256 + tid;
    const float* h = h_all + (size_t)g * 128;
    float l0[5], l1[5];
    #pragma unroll
    for (int cc = 0; cc < 5; ++cc) { l0[cc] = b0[cc]; l1[cc] = b1[cc]; }
    for (int j = 0; j < 128; ++j) {
        float hv = h[j];
        #pragma unroll
        for (int cc = 0; cc < 5; ++cc) {
            l0[cc] = fmaf(w0[cc * 128 + j], hv, l0[cc]);
            l1[cc] = fmaf(w1[cc * 128 + j], hv, l1[cc]);
        }
    }
    int a0 = actions[(size_t)g * 2], a1 = actions[(size_t)g * 2 + 1];
    float m0 = l0[0], m1 = l1[0];
    #pragma unroll
    for (int cc = 1; cc < 5; ++cc) { m0 = fmaxf(m0, l0[cc]); m1 = fmaxf(m1, l1[cc]); }
    float s0 = 0.f, s1 = 0.f;
    #pragma unroll
    for (int cc = 0; cc < 5; ++cc) { s0 += expf(l0[cc] - m0); s1 += expf(l1[cc] - m1); }
    float lse0 = m0 + logf(s0), lse1 = m1 + logf(s1);
    float ent0 = 0.f, ent1 = 0.f, lp0 = 0.f, lp1 = 0.f;
    #pragma unroll
    for (int cc = 0; cc < 5; ++cc) {
        float p0 = l0[cc] - lse0, p1 = l1[cc] - lse1;
        ent0 -= expf(p0) * p0;
        ent1 -= expf(p1) * p1;
        if (cc == a0) lp0 = p0;
        if (cc == a1) lp1 = p1;
    }
    out[ACT_OFF + (size_t)g * 2]     = (float)a0;
    out[ACT_OFF + (size_t)g * 2 + 1] = (float)a1;
    out[LP_OFF + g]                  = lp0 * lp1;
    out[ENT_OFF + (size_t)g * 2]     = ent0;
    out[ENT_OFF + (size_t)g * 2 + 1] = ent1;
}

extern "C" void kernel_launch(void* const* d_in, const int* in_sizes, int n_in,
                              void* d_out, int out_size, void* d_ws, size_t ws_size,
                              hipStream_t stream)
{
    const float* x_agent = (const float*)d_in[0];
    const float* x_lidar = (const float*)d_in[1];
    const float* x_safe  = (const float*)d_in[2];
    const float* x_ent0  = (const float*)d_in[3];
    const float* x_ent1  = (const float*)d_in[4];
    const int*   mask0   = (const int*)d_in[5];
    const int*   mask1   = (const int*)d_in[6];
    const int*   done    = (const int*)d_in[7];
    const int*   actions = (const int*)d_in[8];
    const float* conv_w  = (const float*)d_in[9];
    const float* conv_b  = (const float*)d_in[10];
    const float* self_w  = (const float*)d_in[11];
    const float* self_b  = (const float*)d_in[12];
    const float* ent0_w  = (const float*)d_in[13];
    const float* ent0_b  = (const float*)d_in[14];
    const float* ent1_w  = (const float*)d_in[15];
    const float* ent1_b  = (const float*)d_in[16];
    const float* inp_w   = (const float*)d_in[17];
    const float* inp_b   = (const float*)d_in[18];
    const float* outp_w  = (const float*)d_in[19];
    const float* outp_b  = (const float*)d_in[20];
    const float* sa_w    = (const float*)d_in[21];
    const float* sa_b    = (const float*)d_in[22];
    const float* pool_w  = (const float*)d_in[23];
    const float* pool_b  = (const float*)d_in[24];
    const float* w_ih    = (const float*)d_in[25];
    const float* w_hh    = (const float*)d_in[26];
    const float* b_ih    = (const float*)d_in[27];
    const float* b_hh    = (const float*)d_in[28];
    const float* h0w     = (const float*)d_in[29];
    const float* h0b     = (const float*)d_in[30];
    const float* h1w     = (const float*)d_in[31];
    const float* h1b     = (const float*)d_in[32];

    // ws: z_ent bf16 | zin_x | zin | h_all (f32) | bf16 weights
    __hip_bfloat16* z_ent = (__hip_bfloat16*)d_ws;
    float* zin_x = (float*)((char*)d_ws + (size_t)S_TOT * 2112 * 2);
    float* zin   = zin_x + (size_t)S_TOT * 128;
    float* h_all = zin + (size_t)S_TOT * 128;
    short* wqkvb = (short*)(h_all + (size_t)S_TOT * 128);
    short* wob   = wqkvb + 12288;
    short* wsb   = wob + 4096;
    short* Wf    = wsb + 4096;
    short* We0   = Wf + 102400;
    short* We1   = We0 + 1024;

    k_cvt2<<<400, 256, 0, stream>>>(inp_w, outp_w, sa_w, self_w, pool_w, ent0_w, ent1_w,
                                    wqkvb, wob, wsb, Wf, We0, We1);

    k_frontM<<<256, 256, FM_TOTAL, stream>>>(
        x_agent, x_lidar, x_safe, x_ent0, x_ent1,
        conv_w, conv_b, self_b, ent0_b, ent1_b,
        Wf, We0, We1, z_ent, zin_x);

    k_attnC<<<S_TOT / 2, 256, LDS_TOTAL, stream>>>(
        z_ent, zin_x, mask0, mask1, wqkvb, inp_b, wob, outp_b,
        wsb, sa_b, pool_w, pool_b, zin);

    size_t lstm_lds = (size_t)(64 * 512 + 128 + 128 + 512) * sizeof(float);
    k_lstm<<<BA, 512, lstm_lds, stream>>>(zin, w_ih, w_hh, b_ih, b_hh, done, h_all);

    k_heads<<<S_TOT / 256, 256, 0, stream>>>(h_all, actions, h0w, h0b, h1w, h1b, (float*)d_out);
}

// Round 6
// 598.684 us; speedup vs baseline: 10.1738x; 1.1198x over previous
//
#include <hip/hip_runtime.h>
#include <hip/hip_bf16.h>
#include <math.h>

#define T_DIM 64
#define B_DIM 32
#define N_ENT 16
#define M_SLOTS 33
#define S_TOT 16384
#define BA 256
#define SB 64

#define ACT_OFF 0
#define LP_OFF 32768
#define ENT_OFF 49152

typedef __attribute__((ext_vector_type(8))) short short8;
typedef __attribute__((ext_vector_type(4))) float f32x4;
typedef unsigned int uint32;

__device__ __forceinline__ float sigf(float x) { return 1.0f / (1.0f + expf(-x)); }
__device__ __forceinline__ float bf2f(unsigned short u) {
    union { unsigned int i; float f; } a; a.i = ((unsigned int)u) << 16; return a.f;
}
__device__ __forceinline__ short f2bs(float v) {
    __hip_bfloat16 h = __float2bfloat16(v); return *(short*)&h;
}
__device__ __forceinline__ int pswz(int row) { return (((row & 3) ^ ((row >> 2) & 3)) << 4); }

// ---------------------------------------------------------------------------
// k_cvt2: pack all MFMA weights to bf16 in ws (unchanged from round 5).
// ---------------------------------------------------------------------------
__global__ __launch_bounds__(256) void k_cvt2(
    const float* __restrict__ inp_w, const float* __restrict__ outp_w,
    const float* __restrict__ sa_w, const float* __restrict__ self_w,
    const float* __restrict__ pool_w, const float* __restrict__ ent0_w,
    const float* __restrict__ ent1_w,
    short* __restrict__ wq, short* __restrict__ wo, short* __restrict__ ws,
    short* __restrict__ Wf, short* __restrict__ We0, short* __restrict__ We1)
{
    int i = blockIdx.x * 256 + threadIdx.x;
    if (i < 12288) wq[i] = f2bs(inp_w[i]);
    if (i < 4096) { wo[i] = f2bs(outp_w[i]); ws[i] = f2bs(sa_w[i]); }
    if (i < 1024) {
        int e = i >> 4, k = i & 15;
        We0[i] = f2bs(k < 12 ? ent0_w[e * 302 + k] : 0.f);
        We1[i] = f2bs(k < 8 ? ent1_w[e * 298 + k] : 0.f);
    }
    if (i < 102400) {
        int c = i / 320, k = i - c * 320;
        float v = 0.f;
        if (k < 290) {
            if (c < 64) v = self_w[c * 580 + k] + self_w[c * 580 + 290 + k];
            else if (c < 192) v = pool_w[(size_t)(c - 64) * 354 + k];
            else if (c < 256) v = ent0_w[(c - 192) * 302 + 12 + k];
            else v = ent1_w[(c - 256) * 298 + 8 + k];
        }
        Wf[i] = f2bs(v);
    }
}

// ---------------------------------------------------------------------------
// k_frontM: MFMA front end (unchanged from round 5).
// ---------------------------------------------------------------------------
#define FM_XSB 0
#define FM_XP0 40960
#define FM_XP1 58368
#define FM_AE  75776
#define FM_TOTAL 141312

__global__ __launch_bounds__(256, 1) void k_frontM(
    const float* __restrict__ xag, const float* __restrict__ xlid,
    const float* __restrict__ xsz, const float* __restrict__ xe0,
    const float* __restrict__ xe1,
    const float* __restrict__ conv_w, const float* __restrict__ conv_b,
    const float* __restrict__ self_b, const float* __restrict__ ent0_b,
    const float* __restrict__ ent1_b,
    const short* __restrict__ Wf, const short* __restrict__ We0,
    const short* __restrict__ We1,
    __hip_bfloat16* __restrict__ z_ent, float* __restrict__ zin_x)
{
    extern __shared__ char smem[];
    char* xsb = smem + FM_XSB;
    float* xp0f = (float*)(smem + FM_XP0);
    float* xp1f = (float*)(smem + FM_XP1);
    char* ae = smem + FM_AE;
    float* lidf = (float*)(smem + FM_AE);

    const int tid = threadIdx.x;
    const int s0 = blockIdx.x * SB;
    const int wv = __builtin_amdgcn_readfirstlane(tid >> 6);
    const int l = tid & 63;
    const int lr = l & 15;
    const int lg = l >> 4;

    for (int i = tid; i < SB * 32; i += 256) {
        int d = i & 31, sl = i >> 5;
        lidf[d * 66 + sl] = xlid[(size_t)s0 * 32 + i];
    }
    for (int i = tid; i < SB * 16; i += 256) {
        int sl = i >> 4, d = i & 15;
        *(short*)(xsb + ((sl * 640 + d * 2) ^ ((sl & 7) << 4))) = f2bs(xag[(size_t)s0 * 16 + i]);
    }
    for (int i = tid; i < SB * 4; i += 256) {
        int sl = i >> 2, d = i & 3;
        *(short*)(xsb + ((sl * 640 + (286 + d) * 2) ^ ((sl & 7) << 4))) = f2bs(xsz[(size_t)s0 * 4 + i]);
    }
    for (int i = tid; i < SB * 30; i += 256) {
        int sl = i / 30, d = 290 + (i - (i / 30) * 30);
        *(short*)(xsb + ((sl * 640 + d * 2) ^ ((sl & 7) << 4))) = 0;
    }
    __syncthreads();
    for (int i = tid; i < 270 * 64; i += 256) {
        int cp = i >> 6, sl = i & 63;
        int c = cp / 30, p = cp - c * 30;
        float v = conv_b[c] + conv_w[c * 3] * lidf[p * 66 + sl]
                + conv_w[c * 3 + 1] * lidf[(p + 1) * 66 + sl]
                + conv_w[c * 3 + 2] * lidf[(p + 2) * 66 + sl];
        *(short*)(xsb + ((sl * 640 + (16 + cp) * 2) ^ ((sl & 7) << 4))) = f2bs(fmaxf(v, 0.f));
    }
    __syncthreads();

    f32x4 acc[4][5];
    #pragma unroll
    for (int rt = 0; rt < 4; ++rt)
        #pragma unroll
        for (int c = 0; c < 5; ++c) acc[rt][c] = (f32x4){0.f, 0.f, 0.f, 0.f};

    for (int kk = 0; kk < 10; ++kk) {
        short8 af[4];
        #pragma unroll
        for (int rt = 0; rt < 4; ++rt) {
            int row = rt * 16 + lr;
            af[rt] = *(const short8*)(xsb + ((row * 640 + kk * 64 + lg * 16) ^ ((row & 7) << 4)));
        }
        short8 bf[5];
        #pragma unroll
        for (int c = 0; c < 5; ++c) {
            int col = (wv * 5 + c) * 16 + lr;
            bf[c] = *(const short8*)(Wf + (size_t)col * 320 + kk * 32 + lg * 8);
        }
        #pragma unroll
        for (int rt = 0; rt < 4; ++rt)
            #pragma unroll
            for (int c = 0; c < 5; ++c)
                acc[rt][c] = __builtin_amdgcn_mfma_f32_16x16x32_bf16(af[rt], bf[c], acc[rt][c], 0, 0, 0);
    }

    for (int i = tid; i < 16384; i += 256) ((uint32*)ae)[i] = 0;

    #pragma unroll
    for (int rt = 0; rt < 4; ++rt) {
        #pragma unroll
        for (int c = 0; c < 5; ++c) {
            int ct = wv * 5 + c;
            int gc = ct * 16 + lr;
            int rowb = rt * 16 + lg * 4;
            f32x4 a = acc[rt][c];
            if (ct * 16 < 64) {
                float bias = self_b[gc];
                #pragma unroll
                for (int r = 0; r < 4; ++r)
                    z_ent[(size_t)(s0 + rowb + r) * 2112 + gc] = __float2bfloat16(fmaxf(a[r] + bias, 0.f));
            } else if (ct * 16 < 192) {
                int r2 = gc - 64;
                #pragma unroll
                for (int r = 0; r < 4; ++r)
                    zin_x[(size_t)(s0 + rowb + r) * 128 + r2] = a[r];
            } else if (ct * 16 < 256) {
                float bias = ent0_b[gc - 192];
                #pragma unroll
                for (int r = 0; r < 4; ++r)
                    xp0f[(rowb + r) * 68 + (gc - 192)] = a[r] + bias;
            } else {
                float bias = ent1_b[gc - 256];
                #pragma unroll
                for (int r = 0; r < 4; ++r)
                    xp1f[(rowb + r) * 68 + (gc - 256)] = a[r] + bias;
            }
        }
    }
    __syncthreads();

    for (int i = tid; i < SB * 192; i += 256) {
        int sl = i / 192, r = i - sl * 192;
        int n = r / 12, d = r - n * 12;
        int row = sl * 16 + n;
        *(short*)(ae + ((row * 64 + d * 2) ^ ((row & 3) << 4))) = f2bs(xe0[(size_t)s0 * 192 + i]);
    }
    __syncthreads();

    {
        short8 bz = {0, 0, 0, 0, 0, 0, 0, 0};
        short8 be[4];
        #pragma unroll
        for (int ct = 0; ct < 4; ++ct) {
            int col = ct * 16 + lr;
            short8 bv = *(const short8*)(We0 + col * 16 + (lg & 1) * 8);
            be[ct] = (lg < 2) ? bv : bz;
        }
        for (int rt8 = 0; rt8 < 16; ++rt8) {
            int rt = wv * 16 + rt8;
            int row = rt * 16 + lr;
            short8 af = *(const short8*)(ae + ((row * 64 + lg * 16) ^ ((row & 3) << 4)));
            #pragma unroll
            for (int ct = 0; ct < 4; ++ct) {
                f32x4 a2 = {0.f, 0.f, 0.f, 0.f};
                a2 = __builtin_amdgcn_mfma_f32_16x16x32_bf16(af, be[ct], a2, 0, 0, 0);
                int e = ct * 16 + lr;
                float xpv = xp0f[rt * 68 + e];
                #pragma unroll
                for (int r = 0; r < 4; ++r) {
                    int n = lg * 4 + r;
                    z_ent[(size_t)(s0 + rt) * 2112 + (1 + n) * 64 + e] =
                        __float2bfloat16(fmaxf(a2[r] + xpv, 0.f));
                }
            }
        }
    }
    __syncthreads();

    for (int i = tid; i < SB * 128; i += 256) {
        int sl = i >> 7, r = i & 127;
        int n = r >> 3, d = r & 7;
        int row = sl * 16 + n;
        *(short*)(ae + ((row * 64 + d * 2) ^ ((row & 3) << 4))) = f2bs(xe1[(size_t)s0 * 128 + i]);
    }
    for (int i = tid; i < SB * 16 * 4; i += 256) {
        int row = i >> 2, d = 8 + (i & 3);
        *(short*)(ae + ((row * 64 + d * 2) ^ ((row & 3) << 4))) = 0;
    }
    __syncthreads();

    {
        short8 bz = {0, 0, 0, 0, 0, 0, 0, 0};
        short8 be[4];
        #pragma unroll
        for (int ct = 0; ct < 4; ++ct) {
            int col = ct * 16 + lr;
            short8 bv = *(const short8*)(We1 + col * 16 + (lg & 1) * 8);
            be[ct] = (lg < 2) ? bv : bz;
        }
        for (int rt8 = 0; rt8 < 16; ++rt8) {
            int rt = wv * 16 + rt8;
            int row = rt * 16 + lr;
            short8 af = *(const short8*)(ae + ((row * 64 + lg * 16) ^ ((row & 3) << 4)));
            #pragma unroll
            for (int ct = 0; ct < 4; ++ct) {
                f32x4 a2 = {0.f, 0.f, 0.f, 0.f};
                a2 = __builtin_amdgcn_mfma_f32_16x16x32_bf16(af, be[ct], a2, 0, 0, 0);
                int e = ct * 16 + lr;
                float xpv = xp1f[rt * 68 + e];
                #pragma unroll
                for (int r = 0; r < 4; ++r) {
                    int n = lg * 4 + r;
                    z_ent[(size_t)(s0 + rt) * 2112 + (17 + n) * 64 + e] =
                        __float2bfloat16(fmaxf(a2[r] + xpv, 0.f));
                }
            }
        }
    }
}

// ---------------------------------------------------------------------------
// k_attnD: full-MFMA attention. 8192 blocks x 256 thr, 2 samples/block,
// 2 blocks/CU (68.4 KB LDS). QK^T and PV via MFMA; softmax in registers
// with shfl_xor row-reduction over the MFMA C-layout; slot 32 via rank-1.
// ---------------------------------------------------------------------------
#define AT_ZEB  0
#define AT_QB   10240
#define AT_KB   22528
#define AT_VT   34816
#define AT_PW   43008
#define AT_P32  55296
#define AT_V32  56832
#define AT_OB   57344
#define AT_MSK  67584
#define AT_POOL 67872
#define AT_TOTAL 68384

__global__ __launch_bounds__(256, 2) void k_attnD(
    const __hip_bfloat16* __restrict__ z_ent, const float* __restrict__ zin_x_ws,
    const int* __restrict__ mask0, const int* __restrict__ mask1,
    const short* __restrict__ wqkvb, const float* __restrict__ inp_b,
    const short* __restrict__ wob_g, const float* __restrict__ outp_b,
    const short* __restrict__ wsb_g, const float* __restrict__ sa_b,
    const float* __restrict__ pool_w, const float* __restrict__ pool_b,
    float* __restrict__ zin)
{
    extern __shared__ char smem[];
    char*  zeb = smem + AT_ZEB;           // bf16 [80][64] swz8 (rows 0-65 valid)
    char*  Qb  = smem + AT_QB;            // bf16 [8 pair][48 q][16 d]
    char*  Kb  = smem + AT_KB;            // bf16 [8 pair][48 slot][16 d]
    char*  Vt  = smem + AT_VT;            // bf16 [8 pair][16 d][32 slot] swz64
    char*  Pw  = smem + AT_PW;            // bf16 [4 wave][48 q][32 slot] swz64
    float* P32 = (float*)(smem + AT_P32); // f32 [8 pair][48 q]
    float* V32 = (float*)(smem + AT_V32); // f32 [8 pair][16 d]
    char*  ob  = smem + AT_OB;            // bf16 [80][64] swz8
    float* msk = (float*)(smem + AT_MSK);
    float* pooled = (float*)(smem + AT_POOL);
    char*  o2b = Pw;                      // alias: Pw+P32 dead after PV
    float* res = (float*)Qb;              // alias: Qb+Kb dead after QK

    const int tid = threadIdx.x;
    const int gs0 = blockIdx.x * 2;

    // ---- P0: stage zeb (swizzled) + mask ----
    {
        const uint32* zsrc = (const uint32*)(z_ent + (size_t)gs0 * 2112);
        for (int i = tid; i < 2112; i += 256) {
            int s = (i >= 1056) ? 1 : 0;
            int idx = i - s * 1056;
            int row = s * 33 + (idx >> 5);
            int c2 = idx & 31;
            int byteo = (row * 128 + c2 * 4) ^ ((row & 7) << 4);
            *(uint32*)(zeb + byteo) = zsrc[i];
        }
    }
    if (tid < 32) { int s = tid >> 4, i2 = tid & 15; msk[s * 36 + 1 + i2] = (float)mask0[(size_t)(gs0 + s) * 16 + i2]; }
    else if (tid < 64) { int u = tid - 32; int s = u >> 4, i2 = u & 15; msk[s * 36 + 17 + i2] = (float)mask1[(size_t)(gs0 + s) * 16 + i2]; }
    else if (tid < 66) msk[(tid - 64) * 36] = 1.0f;
    __syncthreads();

    const int wv = __builtin_amdgcn_readfirstlane(tid >> 6);
    const int l  = tid & 63;
    const int lr = l & 15;
    const int lg = l >> 4;

    // ---- P1: in_proj GEMM -> Qb / Kb / Vt / V32 ----
    {
        short8 bw[3][2]; float bias[3];
        #pragma unroll
        for (int c = 0; c < 3; ++c) {
            int col = (wv * 3 + c) * 16 + lr;
            bw[c][0] = *(const short8*)(wqkvb + col * 64 + lg * 8);
            bw[c][1] = *(const short8*)(wqkvb + col * 64 + 32 + lg * 8);
            bias[c] = inp_b[col];
        }
        for (int rt = 0; rt < 5; ++rt) {
            int arow = rt * 16 + lr;
            int sw = (arow & 7) << 4;
            short8 a0 = *(const short8*)(zeb + ((arow * 128 + lg * 16) ^ sw));
            short8 a1 = *(const short8*)(zeb + ((arow * 128 + 64 + lg * 16) ^ sw));
            #pragma unroll
            for (int c = 0; c < 3; ++c) {
                f32x4 acc = {0.f, 0.f, 0.f, 0.f};
                acc = __builtin_amdgcn_mfma_f32_16x16x32_bf16(a0, bw[c][0], acc, 0, 0, 0);
                acc = __builtin_amdgcn_mfma_f32_16x16x32_bf16(a1, bw[c][1], acc, 0, 0, 0);
                int col = (wv * 3 + c) * 16 + lr;
                int rb = rt * 16 + lg * 4;
                #pragma unroll
                for (int r = 0; r < 4; ++r) {
                    int row = rb + r;
                    if (row < 66) {
                        int s = (row >= 33) ? 1 : 0;
                        int q = row - s * 33;
                        float val = acc[r] + bias[c];
                        if (col < 64) {
                            int h = col >> 4, d = col & 15;
                            *(short*)(Qb + ((s * 4 + h) * 48 + q) * 32 + d * 2) = f2bs(val);
                        } else if (col < 128) {
                            int kc = col - 64; int h = kc >> 4, d = kc & 15;
                            *(short*)(Kb + ((s * 4 + h) * 48 + q) * 32 + d * 2) = f2bs(val);
                        } else {
                            int vc = col - 128; int h = vc >> 4, d = vc & 15;
                            if (q < 32)
                                *(short*)(Vt + ((s * 4 + h) * 16 + d) * 64 + ((q * 2) ^ pswz(d))) = f2bs(val);
                            else
                                V32[(s * 4 + h) * 16 + d] = val;
                        }
                    }
                }
            }
        }
    }
    __syncthreads();

    // ---- P2: per-wave QK -> softmax -> PV -> ob (wave owns pairs 2w, 2w+1) ----
    {
        const short8 zero8 = {0, 0, 0, 0, 0, 0, 0, 0};
        for (int pp = 0; pp < 2; ++pp) {
            int pair = 2 * wv + pp;
            int s = pair >> 2, h = pair & 3;
            // QK MFMA (K-dim 16 real + 16 zero in regs)
            short8 qf[3], kf[3];
            #pragma unroll
            for (int t = 0; t < 3; ++t) {
                qf[t] = (lg < 2) ? *(const short8*)(Qb + (pair * 48 + t * 16 + lr) * 32 + lg * 16) : zero8;
                kf[t] = (lg < 2) ? *(const short8*)(Kb + (pair * 48 + t * 16 + lr) * 32 + lg * 16) : zero8;
            }
            f32x4 S0q0 = {0,0,0,0}, S1q0 = {0,0,0,0}, S2q0 = {0,0,0,0};
            f32x4 S0q1 = {0,0,0,0}, S1q1 = {0,0,0,0}, S2q1 = {0,0,0,0};
            f32x4 S0q2 = {0,0,0,0}, S1q2 = {0,0,0,0}, S2q2 = {0,0,0,0};
            S0q0 = __builtin_amdgcn_mfma_f32_16x16x32_bf16(qf[0], kf[0], S0q0, 0, 0, 0);
            S1q0 = __builtin_amdgcn_mfma_f32_16x16x32_bf16(qf[0], kf[1], S1q0, 0, 0, 0);
            S2q0 = __builtin_amdgcn_mfma_f32_16x16x32_bf16(qf[0], kf[2], S2q0, 0, 0, 0);
            S0q1 = __builtin_amdgcn_mfma_f32_16x16x32_bf16(qf[1], kf[0], S0q1, 0, 0, 0);
            S1q1 = __builtin_amdgcn_mfma_f32_16x16x32_bf16(qf[1], kf[1], S1q1, 0, 0, 0);
            S2q1 = __builtin_amdgcn_mfma_f32_16x16x32_bf16(qf[1], kf[2], S2q1, 0, 0, 0);
            S0q2 = __builtin_amdgcn_mfma_f32_16x16x32_bf16(qf[2], kf[0], S0q2, 0, 0, 0);
            S1q2 = __builtin_amdgcn_mfma_f32_16x16x32_bf16(qf[2], kf[1], S1q2, 0, 0, 0);
            S2q2 = __builtin_amdgcn_mfma_f32_16x16x32_bf16(qf[2], kf[2], S2q2, 0, 0, 0);

            float mk0 = msk[s * 36 + lr];
            float mk1 = msk[s * 36 + 16 + lr];
            float mk2 = (lr == 0) ? msk[s * 36 + 32] : 0.f;

            // softmax per row (shfl_xor over the 16-lane col groups), write P
            #pragma unroll
            for (int qt = 0; qt < 3; ++qt) {
                f32x4 A0 = (qt == 0) ? S0q0 : (qt == 1) ? S0q1 : S0q2;
                f32x4 A1 = (qt == 0) ? S1q0 : (qt == 1) ? S1q1 : S1q2;
                f32x4 A2 = (qt == 0) ? S2q0 : (qt == 1) ? S2q1 : S2q2;
                #pragma unroll
                for (int r = 0; r < 4; ++r) {
                    float v0 = (mk0 > 0.f) ? A0[r] * 0.25f : -1e9f;
                    float v1 = (mk1 > 0.f) ? A1[r] * 0.25f : -1e9f;
                    float v2 = (mk2 > 0.f) ? A2[r] * 0.25f : -1e9f;
                    float m = fmaxf(fmaxf(v0, v1), v2);
                    m = fmaxf(m, __shfl_xor(m, 1));
                    m = fmaxf(m, __shfl_xor(m, 2));
                    m = fmaxf(m, __shfl_xor(m, 4));
                    m = fmaxf(m, __shfl_xor(m, 8));
                    float e0 = __expf(v0 - m), e1 = __expf(v1 - m), e2 = __expf(v2 - m);
                    float sm = e0 + e1 + e2;
                    sm += __shfl_xor(sm, 1);
                    sm += __shfl_xor(sm, 2);
                    sm += __shfl_xor(sm, 4);
                    sm += __shfl_xor(sm, 8);
                    float inv = 1.0f / sm;
                    int q = qt * 16 + lg * 4 + r;
                    int sz = pswz(q);
                    char* prow = Pw + wv * 3072 + q * 64;
                    *(short*)(prow + ((lr * 2) ^ sz)) = f2bs(e0 * inv);
                    *(short*)(prow + (((16 + lr) * 2) ^ sz)) = f2bs(e1 * inv);
                    if (lr == 0) P32[pair * 48 + q] = e2 * inv;
                }
            }

            // PV MFMA (slots 0-31) + rank-1 slot 32
            short8 vf = *(const short8*)(Vt + (pair * 16 + lr) * 64 + ((lg * 16) ^ pswz(lr)));
            float v32reg = V32[pair * 16 + lr];
            f32x4 C0 = {0,0,0,0}, C1 = {0,0,0,0}, C2 = {0,0,0,0};
            {
                short8 pf0 = *(const short8*)(Pw + wv * 3072 + (0 * 16 + lr) * 64 + ((lg * 16) ^ pswz(0 * 16 + lr)));
                short8 pf1 = *(const short8*)(Pw + wv * 3072 + (1 * 16 + lr) * 64 + ((lg * 16) ^ pswz(1 * 16 + lr)));
                short8 pf2 = *(const short8*)(Pw + wv * 3072 + (2 * 16 + lr) * 64 + ((lg * 16) ^ pswz(2 * 16 + lr)));
                C0 = __builtin_amdgcn_mfma_f32_16x16x32_bf16(pf0, vf, C0, 0, 0, 0);
                C1 = __builtin_amdgcn_mfma_f32_16x16x32_bf16(pf1, vf, C1, 0, 0, 0);
                C2 = __builtin_amdgcn_mfma_f32_16x16x32_bf16(pf2, vf, C2, 0, 0, 0);
            }
            #pragma unroll
            for (int qt = 0; qt < 3; ++qt) {
                f32x4 C = (qt == 0) ? C0 : (qt == 1) ? C1 : C2;
                #pragma unroll
                for (int r = 0; r < 4; ++r) {
                    int q = qt * 16 + lg * 4 + r;
                    float cv = C[r] + P32[pair * 48 + q] * v32reg;
                    if (q <= 32) {
                        int row = s * 33 + q;
                        *(short*)(ob + ((row * 128 + (h * 16 + lr) * 2) ^ ((row & 7) << 4))) = f2bs(cv);
                    }
                }
            }
        }
    }
    __syncthreads();

    // ---- P3: out_proj GEMM: ob -> o2b ----
    {
        int col = wv * 16 + lr;
        short8 b0 = *(const short8*)(wob_g + col * 64 + lg * 8);
        short8 b1 = *(const short8*)(wob_g + col * 64 + 32 + lg * 8);
        float bias = outp_b[col];
        for (int rt = 0; rt < 5; ++rt) {
            int arow = rt * 16 + lr;
            int sw = (arow & 7) << 4;
            short8 a0 = *(const short8*)(ob + ((arow * 128 + lg * 16) ^ sw));
            short8 a1 = *(const short8*)(ob + ((arow * 128 + 64 + lg * 16) ^ sw));
            f32x4 acc = {0.f, 0.f, 0.f, 0.f};
            acc = __builtin_amdgcn_mfma_f32_16x16x32_bf16(a0, b0, acc, 0, 0, 0);
            acc = __builtin_amdgcn_mfma_f32_16x16x32_bf16(a1, b1, acc, 0, 0, 0);
            int rb = rt * 16 + lg * 4;
            #pragma unroll
            for (int r = 0; r < 4; ++r) {
                int row = rb + r;
                if (row < 66)
                    *(short*)(o2b + ((row * 128 + col * 2) ^ ((row & 7) << 4))) = f2bs(acc[r] + bias);
            }
        }
    }
    __syncthreads();

    // ---- P4: sa GEMM + residual + mask -> res (aliases Qb/Kb) ----
    {
        int col = wv * 16 + lr;
        short8 b0 = *(const short8*)(wsb_g + col * 64 + lg * 8);
        short8 b1 = *(const short8*)(wsb_g + col * 64 + 32 + lg * 8);
        float bias = sa_b[col];
        for (int rt = 0; rt < 5; ++rt) {
            int arow = rt * 16 + lr;
            int sw = (arow & 7) << 4;
            short8 a0 = *(const short8*)(o2b + ((arow * 128 + lg * 16) ^ sw));
            short8 a1 = *(const short8*)(o2b + ((arow * 128 + 64 + lg * 16) ^ sw));
            f32x4 acc = {0.f, 0.f, 0.f, 0.f};
            acc = __builtin_amdgcn_mfma_f32_16x16x32_bf16(a0, b0, acc, 0, 0, 0);
            acc = __builtin_amdgcn_mfma_f32_16x16x32_bf16(a1, b1, acc, 0, 0, 0);
            int rb = rt * 16 + lg * 4;
            #pragma unroll
            for (int r = 0; r < 4; ++r) {
                int row = rb + r;
                if (row < 66) {
                    int ss = (row >= 33) ? 1 : 0;
                    int m = row - ss * 33;
                    float zev = bf2f(*(const unsigned short*)(zeb + ((row * 128 + col * 2) ^ ((row & 7) << 4))));
                    res[row * 68 + col] = msk[ss * 36 + m] * (zev + fmaxf(acc[r] + bias, 0.f));
                }
            }
        }
    }
    __syncthreads();

    // ---- P5: pool + zin ----
    if (tid < 128) {
        int s = tid >> 6, e = tid & 63;
        float acc = 0.f;
        #pragma unroll
        for (int m = 0; m < 33; ++m) acc += res[(s * 33 + m) * 68 + e];
        pooled[s * 64 + e] = acc * (1.0f / 33.0f);
    }
    __syncthreads();
    {
        int s = tid >> 7, r = tid & 127;
        float acc = pool_b[r] + zin_x_ws[(size_t)(gs0 + s) * 128 + r];
        const float* wrow = pool_w + (size_t)r * 354 + 290;
        const float* pl = pooled + s * 64;
        #pragma unroll 8
        for (int e = 0; e < 64; ++e) acc = fmaf(wrow[e], pl[e], acc);
        zin[(size_t)(gs0 + s) * 128 + r] = fmaxf(acc, 0.f);
    }
}

// ---------------------------------------------------------------------------
// Kernel: LSTM scan (unchanged)
// ---------------------------------------------------------------------------
__global__ __launch_bounds__(512) void k_lstm(
    const float* __restrict__ zin, const float* __restrict__ w_ih,
    const float* __restrict__ w_hh, const float* __restrict__ b_ih,
    const float* __restrict__ b_hh, const int* __restrict__ done,
    float* __restrict__ h_all)
{
    extern __shared__ float lds[];
    float* xp = lds;
    float* zl = xp + 64 * 512;
    float* hl = zl + 128;
    float* gl = hl + 128;
    const int s = blockIdx.x;
    const int r = threadIdx.x;
    const int b = s >> 3;

    float4 w[32];
    {
        const float4* wsrc = (const float4*)(w_ih + (size_t)r * 128);
        #pragma unroll
        for (int j = 0; j < 32; ++j) w[j] = wsrc[j];
    }
    const float bias = b_ih[r] + b_hh[r];

    for (int t = 0; t < T_DIM; ++t) {
        __syncthreads();
        if (r < 128) zl[r] = zin[((size_t)t * BA + s) * 128 + r];
        __syncthreads();
        const float4* x4 = (const float4*)zl;
        float a0 = 0.f, a1 = 0.f, a2 = 0.f, a3 = 0.f;
        #pragma unroll
        for (int j = 0; j < 32; ++j) {
            float4 wa = w[j], xa = x4[j];
            a0 = fmaf(wa.x, xa.x, a0);
            a1 = fmaf(wa.y, xa.y, a1);
            a2 = fmaf(wa.z, xa.z, a2);
            a3 = fmaf(wa.w, xa.w, a3);
        }
        xp[t * 512 + r] = bias + ((a0 + a1) + (a2 + a3));
    }

    {
        const float4* wsrc = (const float4*)(w_hh + (size_t)r * 128);
        #pragma unroll
        for (int j = 0; j < 32; ++j) w[j] = wsrc[j];
    }
    if (r < 128) hl[r] = 0.0f;
    float c = 0.0f;
    __syncthreads();

    for (int t = 0; t < T_DIM; ++t) {
        const float4* h4 = (const float4*)hl;
        float a0 = 0.f, a1 = 0.f, a2 = 0.f, a3 = 0.f;
        #pragma unroll
        for (int j = 0; j < 32; ++j) {
            float4 wa = w[j], xa = h4[j];
            a0 = fmaf(wa.x, xa.x, a0);
            a1 = fmaf(wa.y, xa.y, a1);
            a2 = fmaf(wa.z, xa.z, a2);
            a3 = fmaf(wa.w, xa.w, a3);
        }
        gl[r] = xp[t * 512 + r] + ((a0 + a1) + (a2 + a3));
        __syncthreads();
        if (r < 128) {
            float keep = done[t * B_DIM + b] ? 0.0f : 1.0f;
            float gi = gl[r], gf = gl[r + 128], gg = gl[r + 256], go = gl[r + 384];
            c *= keep;
            c = sigf(gf) * c + sigf(gi) * tanhf(gg);
            float hn = sigf(go) * tanhf(c);
            float keepn = (t < T_DIM - 1) ? (done[(t + 1) * B_DIM + b] ? 0.0f : 1.0f) : 1.0f;
            hl[r] = hn * keepn;
            h_all[((size_t)t * BA + s) * 128 + r] = hn;
        }
        __syncthreads();
    }
}

// ---------------------------------------------------------------------------
// Kernel: categorical heads (unchanged)
// ---------------------------------------------------------------------------
__global__ __launch_bounds__(256) void k_heads(
    const float* __restrict__ h_all, const int* __restrict__ actions,
    const float* __restrict__ h0w, const float* __restrict__ h0b,
    const float* __restrict__ h1w, const float* __restrict__ h1b,
    float* __restrict__ out)
{
    __shared__ float w0[640], w1[640], b0[8], b1[8];
    const int tid = threadIdx.x;
    for (int i = tid; i < 640; i += 256) { w0[i] = h0w[i]; w1[i] = h1w[i]; }
    if (tid < 5) { b0[tid] = h0b[tid]; b1[tid] = h1b[tid]; }
    __syncthreads();
    const int g = blockIdx.x * 256 + tid;
    const float* h = h_all + (size_t)g * 128;
    float l0[5], l1[5];
    #pragma unroll
    for (int cc = 0; cc < 5; ++cc) { l0[cc] = b0[cc]; l1[cc] = b1[cc]; }
    for (int j = 0; j < 128; ++j) {
        float hv = h[j];
        #pragma unroll
        for (int cc = 0; cc < 5; ++cc) {
            l0[cc] = fmaf(w0[cc * 128 + j], hv, l0[cc]);
            l1[cc] = fmaf(w1[cc * 128 + j], hv, l1[cc]);
        }
    }
    int a0 = actions[(size_t)g * 2], a1 = actions[(size_t)g * 2 + 1];
    float m0 = l0[0], m1 = l1[0];
    #pragma unroll
    for (int cc = 1; cc < 5; ++cc) { m0 = fmaxf(m0, l0[cc]); m1 = fmaxf(m1, l1[cc]); }
    float s0 = 0.f, s1 = 0.f;
    #pragma unroll
    for (int cc = 0; cc < 5; ++cc) { s0 += expf(l0[cc] - m0); s1 += expf(l1[cc] - m1); }
    float lse0 = m0 + logf(s0), lse1 = m1 + logf(s1);
    float ent0 = 0.f, ent1 = 0.f, lp0 = 0.f, lp1 = 0.f;
    #pragma unroll
    for (int cc = 0; cc < 5; ++cc) {
        float p0 = l0[cc] - lse0, p1 = l1[cc] - lse1;
        ent0 -= expf(p0) * p0;
        ent1 -= expf(p1) * p1;
        if (cc == a0) lp0 = p0;
        if (cc == a1) lp1 = p1;
    }
    out[ACT_OFF + (size_t)g * 2]     = (float)a0;
    out[ACT_OFF + (size_t)g * 2 + 1] = (float)a1;
    out[LP_OFF + g]                  = lp0 * lp1;
    out[ENT_OFF + (size_t)g * 2]     = ent0;
    out[ENT_OFF + (size_t)g * 2 + 1] = ent1;
}

extern "C" void kernel_launch(void* const* d_in, const int* in_sizes, int n_in,
                              void* d_out, int out_size, void* d_ws, size_t ws_size,
                              hipStream_t stream)
{
    const float* x_agent = (const float*)d_in[0];
    const float* x_lidar = (const float*)d_in[1];
    const float* x_safe  = (const float*)d_in[2];
    const float* x_ent0  = (const float*)d_in[3];
    const float* x_ent1  = (const float*)d_in[4];
    const int*   mask0   = (const int*)d_in[5];
    const int*   mask1   = (const int*)d_in[6];
    const int*   done    = (const int*)d_in[7];
    const int*   actions = (const int*)d_in[8];
    const float* conv_w  = (const float*)d_in[9];
    const float* conv_b  = (const float*)d_in[10];
    const float* self_w  = (const float*)d_in[11];
    const float* self_b  = (const float*)d_in[12];
    const float* ent0_w  = (const float*)d_in[13];
    const float* ent0_b  = (const float*)d_in[14];
    const float* ent1_w  = (const float*)d_in[15];
    const float* ent1_b  = (const float*)d_in[16];
    const float* inp_w   = (const float*)d_in[17];
    const float* inp_b   = (const float*)d_in[18];
    const float* outp_w  = (const float*)d_in[19];
    const float* outp_b  = (const float*)d_in[20];
    const float* sa_w    = (const float*)d_in[21];
    const float* sa_b    = (const float*)d_in[22];
    const float* pool_w  = (const float*)d_in[23];
    const float* pool_b  = (const float*)d_in[24];
    const float* w_ih    = (const float*)d_in[25];
    const float* w_hh    = (const float*)d_in[26];
    const float* b_ih    = (const float*)d_in[27];
    const float* b_hh    = (const float*)d_in[28];
    const float* h0w     = (const float*)d_in[29];
    const float* h0b     = (const float*)d_in[30];
    const float* h1w     = (const float*)d_in[31];
    const float* h1b     = (const float*)d_in[32];

    __hip_bfloat16* z_ent = (__hip_bfloat16*)d_ws;
    float* zin_x = (float*)((char*)d_ws + (size_t)S_TOT * 2112 * 2);
    float* zin   = zin_x + (size_t)S_TOT * 128;
    float* h_all = zin + (size_t)S_TOT * 128;
    short* wqkvb = (short*)(h_all + (size_t)S_TOT * 128);
    short* wob   = wqkvb + 12288;
    short* wsb   = wob + 4096;
    short* Wf    = wsb + 4096;
    short* We0   = Wf + 102400;
    short* We1   = We0 + 1024;

    k_cvt2<<<400, 256, 0, stream>>>(inp_w, outp_w, sa_w, self_w, pool_w, ent0_w, ent1_w,
                                    wqkvb, wob, wsb, Wf, We0, We1);

    k_frontM<<<256, 256, FM_TOTAL, stream>>>(
        x_agent, x_lidar, x_safe, x_ent0, x_ent1,
        conv_w, conv_b, self_b, ent0_b, ent1_b,
        Wf, We0, We1, z_ent, zin_x);

    k_attnD<<<S_TOT / 2, 256, AT_TOTAL, stream>>>(
        z_ent, zin_x, mask0, mask1, wqkvb, inp_b, wob, outp_b,
        wsb, sa_b, pool_w, pool_b, zin);

    size_t lstm_lds = (size_t)(64 * 512 + 128 + 128 + 512) * sizeof(float);
    k_lstm<<<BA, 512, lstm_lds, stream>>>(zin, w_ih, w_hh, b_ih, b_hh, done, h_all);

    k_heads<<<S_TOT / 256, 256, 0, stream>>>(h_all, actions, h0w, h0b, h1w, h1b, (float*)d_out);
}

// Round 7
// 487.630 us; speedup vs baseline: 12.4908x; 1.2277x over previous
//
#include <hip/hip_runtime.h>
#include <hip/hip_bf16.h>
#include <math.h>

#define T_DIM 64
#define B_DIM 32
#define N_ENT 16
#define M_SLOTS 33
#define S_TOT 16384
#define BA 256
#define SB 64

#define ACT_OFF 0
#define LP_OFF 32768
#define ENT_OFF 49152

typedef __attribute__((ext_vector_type(8))) short short8;
typedef __attribute__((ext_vector_type(4))) float f32x4;
typedef unsigned int uint32;

__device__ __forceinline__ float sigf(float x) { return 1.0f / (1.0f + expf(-x)); }
__device__ __forceinline__ float bf2f(unsigned short u) {
    union { unsigned int i; float f; } a; a.i = ((unsigned int)u) << 16; return a.f;
}
__device__ __forceinline__ uint32 pkbf(float a, float b) {
    __hip_bfloat16 ha = __float2bfloat16(a), hb = __float2bfloat16(b);
    return (uint32)(*(unsigned short*)&ha) | ((uint32)(*(unsigned short*)&hb) << 16);
}
__device__ __forceinline__ short f2bs(float v) {
    __hip_bfloat16 h = __float2bfloat16(v); return *(short*)&h;
}
__device__ __forceinline__ int pswz(int row) { return (((row & 3) ^ ((row >> 2) & 3)) << 4); }

// ---------------------------------------------------------------------------
// k_cvt2: pack all MFMA weights to bf16 in ws (unchanged).
// ---------------------------------------------------------------------------
__global__ __launch_bounds__(256) void k_cvt2(
    const float* __restrict__ inp_w, const float* __restrict__ outp_w,
    const float* __restrict__ sa_w, const float* __restrict__ self_w,
    const float* __restrict__ pool_w, const float* __restrict__ ent0_w,
    const float* __restrict__ ent1_w,
    short* __restrict__ wq, short* __restrict__ wo, short* __restrict__ ws,
    short* __restrict__ Wf, short* __restrict__ We0, short* __restrict__ We1)
{
    int i = blockIdx.x * 256 + threadIdx.x;
    if (i < 12288) wq[i] = f2bs(inp_w[i]);
    if (i < 4096) { wo[i] = f2bs(outp_w[i]); ws[i] = f2bs(sa_w[i]); }
    if (i < 1024) {
        int e = i >> 4, k = i & 15;
        We0[i] = f2bs(k < 12 ? ent0_w[e * 302 + k] : 0.f);
        We1[i] = f2bs(k < 8 ? ent1_w[e * 298 + k] : 0.f);
    }
    if (i < 102400) {
        int c = i / 320, k = i - c * 320;
        float v = 0.f;
        if (k < 290) {
            if (c < 64) v = self_w[c * 580 + k] + self_w[c * 580 + 290 + k];
            else if (c < 192) v = pool_w[(size_t)(c - 64) * 354 + k];
            else if (c < 256) v = ent0_w[(c - 192) * 302 + 12 + k];
            else v = ent1_w[(c - 256) * 298 + 8 + k];
        }
        Wf[i] = f2bs(v);
    }
}

// ---------------------------------------------------------------------------
// k_frontM: MFMA front end (unchanged).
// ---------------------------------------------------------------------------
#define FM_XSB 0
#define FM_XP0 40960
#define FM_XP1 58368
#define FM_AE  75776
#define FM_TOTAL 141312

__global__ __launch_bounds__(256, 1) void k_frontM(
    const float* __restrict__ xag, const float* __restrict__ xlid,
    const float* __restrict__ xsz, const float* __restrict__ xe0,
    const float* __restrict__ xe1,
    const float* __restrict__ conv_w, const float* __restrict__ conv_b,
    const float* __restrict__ self_b, const float* __restrict__ ent0_b,
    const float* __restrict__ ent1_b,
    const short* __restrict__ Wf, const short* __restrict__ We0,
    const short* __restrict__ We1,
    __hip_bfloat16* __restrict__ z_ent, float* __restrict__ zin_x)
{
    extern __shared__ char smem[];
    char* xsb = smem + FM_XSB;
    float* xp0f = (float*)(smem + FM_XP0);
    float* xp1f = (float*)(smem + FM_XP1);
    char* ae = smem + FM_AE;
    float* lidf = (float*)(smem + FM_AE);

    const int tid = threadIdx.x;
    const int s0 = blockIdx.x * SB;
    const int wv = __builtin_amdgcn_readfirstlane(tid >> 6);
    const int l = tid & 63;
    const int lr = l & 15;
    const int lg = l >> 4;

    for (int i = tid; i < SB * 32; i += 256) {
        int d = i & 31, sl = i >> 5;
        lidf[d * 66 + sl] = xlid[(size_t)s0 * 32 + i];
    }
    for (int i = tid; i < SB * 16; i += 256) {
        int sl = i >> 4, d = i & 15;
        *(short*)(xsb + ((sl * 640 + d * 2) ^ ((sl & 7) << 4))) = f2bs(xag[(size_t)s0 * 16 + i]);
    }
    for (int i = tid; i < SB * 4; i += 256) {
        int sl = i >> 2, d = i & 3;
        *(short*)(xsb + ((sl * 640 + (286 + d) * 2) ^ ((sl & 7) << 4))) = f2bs(xsz[(size_t)s0 * 4 + i]);
    }
    for (int i = tid; i < SB * 30; i += 256) {
        int sl = i / 30, d = 290 + (i - (i / 30) * 30);
        *(short*)(xsb + ((sl * 640 + d * 2) ^ ((sl & 7) << 4))) = 0;
    }
    __syncthreads();
    for (int i = tid; i < 270 * 64; i += 256) {
        int cp = i >> 6, sl = i & 63;
        int c = cp / 30, p = cp - c * 30;
        float v = conv_b[c] + conv_w[c * 3] * lidf[p * 66 + sl]
                + conv_w[c * 3 + 1] * lidf[(p + 1) * 66 + sl]
                + conv_w[c * 3 + 2] * lidf[(p + 2) * 66 + sl];
        *(short*)(xsb + ((sl * 640 + (16 + cp) * 2) ^ ((sl & 7) << 4))) = f2bs(fmaxf(v, 0.f));
    }
    __syncthreads();

    f32x4 acc[4][5];
    #pragma unroll
    for (int rt = 0; rt < 4; ++rt)
        #pragma unroll
        for (int c = 0; c < 5; ++c) acc[rt][c] = (f32x4){0.f, 0.f, 0.f, 0.f};

    for (int kk = 0; kk < 10; ++kk) {
        short8 af[4];
        #pragma unroll
        for (int rt = 0; rt < 4; ++rt) {
            int row = rt * 16 + lr;
            af[rt] = *(const short8*)(xsb + ((row * 640 + kk * 64 + lg * 16) ^ ((row & 7) << 4)));
        }
        short8 bf[5];
        #pragma unroll
        for (int c = 0; c < 5; ++c) {
            int col = (wv * 5 + c) * 16 + lr;
            bf[c] = *(const short8*)(Wf + (size_t)col * 320 + kk * 32 + lg * 8);
        }
        #pragma unroll
        for (int rt = 0; rt < 4; ++rt)
            #pragma unroll
            for (int c = 0; c < 5; ++c)
                acc[rt][c] = __builtin_amdgcn_mfma_f32_16x16x32_bf16(af[rt], bf[c], acc[rt][c], 0, 0, 0);
    }

    for (int i = tid; i < 16384; i += 256) ((uint32*)ae)[i] = 0;

    #pragma unroll
    for (int rt = 0; rt < 4; ++rt) {
        #pragma unroll
        for (int c = 0; c < 5; ++c) {
            int ct = wv * 5 + c;
            int gc = ct * 16 + lr;
            int rowb = rt * 16 + lg * 4;
            f32x4 a = acc[rt][c];
            if (ct * 16 < 64) {
                float bias = self_b[gc];
                #pragma unroll
                for (int r = 0; r < 4; ++r)
                    z_ent[(size_t)(s0 + rowb + r) * 2112 + gc] = __float2bfloat16(fmaxf(a[r] + bias, 0.f));
            } else if (ct * 16 < 192) {
                int r2 = gc - 64;
                #pragma unroll
                for (int r = 0; r < 4; ++r)
                    zin_x[(size_t)(s0 + rowb + r) * 128 + r2] = a[r];
            } else if (ct * 16 < 256) {
                float bias = ent0_b[gc - 192];
                #pragma unroll
                for (int r = 0; r < 4; ++r)
                    xp0f[(rowb + r) * 68 + (gc - 192)] = a[r] + bias;
            } else {
                float bias = ent1_b[gc - 256];
                #pragma unroll
                for (int r = 0; r < 4; ++r)
                    xp1f[(rowb + r) * 68 + (gc - 256)] = a[r] + bias;
            }
        }
    }
    __syncthreads();

    for (int i = tid; i < SB * 192; i += 256) {
        int sl = i / 192, r = i - sl * 192;
        int n = r / 12, d = r - n * 12;
        int row = sl * 16 + n;
        *(short*)(ae + ((row * 64 + d * 2) ^ ((row & 3) << 4))) = f2bs(xe0[(size_t)s0 * 192 + i]);
    }
    __syncthreads();

    {
        short8 bz = {0, 0, 0, 0, 0, 0, 0, 0};
        short8 be[4];
        #pragma unroll
        for (int ct = 0; ct < 4; ++ct) {
            int col = ct * 16 + lr;
            short8 bv = *(const short8*)(We0 + col * 16 + (lg & 1) * 8);
            be[ct] = (lg < 2) ? bv : bz;
        }
        for (int rt8 = 0; rt8 < 16; ++rt8) {
            int rt = wv * 16 + rt8;
            int row = rt * 16 + lr;
            short8 af = *(const short8*)(ae + ((row * 64 + lg * 16) ^ ((row & 3) << 4)));
            #pragma unroll
            for (int ct = 0; ct < 4; ++ct) {
                f32x4 a2 = {0.f, 0.f, 0.f, 0.f};
                a2 = __builtin_amdgcn_mfma_f32_16x16x32_bf16(af, be[ct], a2, 0, 0, 0);
                int e = ct * 16 + lr;
                float xpv = xp0f[rt * 68 + e];
                #pragma unroll
                for (int r = 0; r < 4; ++r) {
                    int n = lg * 4 + r;
                    z_ent[(size_t)(s0 + rt) * 2112 + (1 + n) * 64 + e] =
                        __float2bfloat16(fmaxf(a2[r] + xpv, 0.f));
                }
            }
        }
    }
    __syncthreads();

    for (int i = tid; i < SB * 128; i += 256) {
        int sl = i >> 7, r = i & 127;
        int n = r >> 3, d = r & 7;
        int row = sl * 16 + n;
        *(short*)(ae + ((row * 64 + d * 2) ^ ((row & 3) << 4))) = f2bs(xe1[(size_t)s0 * 128 + i]);
    }
    for (int i = tid; i < SB * 16 * 4; i += 256) {
        int row = i >> 2, d = 8 + (i & 3);
        *(short*)(ae + ((row * 64 + d * 2) ^ ((row & 3) << 4))) = 0;
    }
    __syncthreads();

    {
        short8 bz = {0, 0, 0, 0, 0, 0, 0, 0};
        short8 be[4];
        #pragma unroll
        for (int ct = 0; ct < 4; ++ct) {
            int col = ct * 16 + lr;
            short8 bv = *(const short8*)(We1 + col * 16 + (lg & 1) * 8);
            be[ct] = (lg < 2) ? bv : bz;
        }
        for (int rt8 = 0; rt8 < 16; ++rt8) {
            int rt = wv * 16 + rt8;
            int row = rt * 16 + lr;
            short8 af = *(const short8*)(ae + ((row * 64 + lg * 16) ^ ((row & 3) << 4)));
            #pragma unroll
            for (int ct = 0; ct < 4; ++ct) {
                f32x4 a2 = {0.f, 0.f, 0.f, 0.f};
                a2 = __builtin_amdgcn_mfma_f32_16x16x32_bf16(af, be[ct], a2, 0, 0, 0);
                int e = ct * 16 + lr;
                float xpv = xp1f[rt * 68 + e];
                #pragma unroll
                for (int r = 0; r < 4; ++r) {
                    int n = lg * 4 + r;
                    z_ent[(size_t)(s0 + rt) * 2112 + (17 + n) * 64 + e] =
                        __float2bfloat16(fmaxf(a2[r] + xpv, 0.f));
                }
            }
        }
    }
}

// ---------------------------------------------------------------------------
// k_attnE: full-MFMA attention, 49.95 KB LDS -> 3 blocks/CU.
// P2 split (QK+softmax | PV) so ob aliases Qb, o2b aliases Kb; per-wave
// single-tile Pw; pool fused into sa-GEMM epilogue via shfl_xor.
// ---------------------------------------------------------------------------
#define AT_ZEB  0
#define AT_QB   10240
#define AT_KB   22528
#define AT_VT   34816
#define AT_PW   43008
#define AT_P32  47104
#define AT_V32  48640
#define AT_MSK  49152
#define AT_POOL 49440
#define AT_TOTAL 49952

__global__ __launch_bounds__(256, 3) void k_attnE(
    const __hip_bfloat16* __restrict__ z_ent, const float* __restrict__ zin_x_ws,
    const int* __restrict__ mask0, const int* __restrict__ mask1,
    const short* __restrict__ wqkvb, const float* __restrict__ inp_b,
    const short* __restrict__ wob_g, const float* __restrict__ outp_b,
    const short* __restrict__ wsb_g, const float* __restrict__ sa_b,
    const float* __restrict__ pool_w, const float* __restrict__ pool_b,
    float* __restrict__ zin)
{
    extern __shared__ char smem[];
    char*  zeb = smem + AT_ZEB;           // bf16 [80][64] swz8 (rows 0-65 valid)
    char*  Qb  = smem + AT_QB;            // bf16 [8 pair][48 q][16 d]; later ob
    char*  Kb  = smem + AT_KB;            // bf16 [8 pair][48 slot][16 d]; later o2b
    char*  Vt  = smem + AT_VT;            // bf16 [8 pair][16 d][32 slot] swz
    char*  Pw  = smem + AT_PW;            // bf16 [4 wave][16 row][32 slot] swz
    float* P32 = (float*)(smem + AT_P32); // f32 [8 pair][48 q]
    float* V32 = (float*)(smem + AT_V32); // f32 [8 pair][16 d]
    float* msk = (float*)(smem + AT_MSK);
    float* pooled = (float*)(smem + AT_POOL);
    char*  ob  = Qb;                      // alias (after P2a barrier)
    char*  o2b = Kb;                      // alias (after P2b barrier)

    const int tid = threadIdx.x;
    const int gs0 = blockIdx.x * 2;

    // ---- P0: stage zeb (swizzled) + mask ----
    {
        const uint32* zsrc = (const uint32*)(z_ent + (size_t)gs0 * 2112);
        for (int i = tid; i < 2112; i += 256) {
            int s = (i >= 1056) ? 1 : 0;
            int idx = i - s * 1056;
            int row = s * 33 + (idx >> 5);
            int c2 = idx & 31;
            int byteo = (row * 128 + c2 * 4) ^ ((row & 7) << 4);
            *(uint32*)(zeb + byteo) = zsrc[i];
        }
    }
    if (tid < 32) { int s = tid >> 4, i2 = tid & 15; msk[s * 36 + 1 + i2] = (float)mask0[(size_t)(gs0 + s) * 16 + i2]; }
    else if (tid < 64) { int u = tid - 32; int s = u >> 4, i2 = u & 15; msk[s * 36 + 17 + i2] = (float)mask1[(size_t)(gs0 + s) * 16 + i2]; }
    else if (tid < 66) msk[(tid - 64) * 36] = 1.0f;
    __syncthreads();

    const int wv = __builtin_amdgcn_readfirstlane(tid >> 6);
    const int l  = tid & 63;
    const int lr = l & 15;
    const int lg = l >> 4;

    // ---- P1: in_proj GEMM -> Qb / Kb / Vt / V32 ----
    {
        short8 bw[3][2]; float bias[3];
        #pragma unroll
        for (int c = 0; c < 3; ++c) {
            int col = (wv * 3 + c) * 16 + lr;
            bw[c][0] = *(const short8*)(wqkvb + col * 64 + lg * 8);
            bw[c][1] = *(const short8*)(wqkvb + col * 64 + 32 + lg * 8);
            bias[c] = inp_b[col];
        }
        for (int rt = 0; rt < 5; ++rt) {
            int arow = rt * 16 + lr;
            int sw = (arow & 7) << 4;
            short8 a0 = *(const short8*)(zeb + ((arow * 128 + lg * 16) ^ sw));
            short8 a1 = *(const short8*)(zeb + ((arow * 128 + 64 + lg * 16) ^ sw));
            #pragma unroll
            for (int c = 0; c < 3; ++c) {
                f32x4 acc = {0.f, 0.f, 0.f, 0.f};
                acc = __builtin_amdgcn_mfma_f32_16x16x32_bf16(a0, bw[c][0], acc, 0, 0, 0);
                acc = __builtin_amdgcn_mfma_f32_16x16x32_bf16(a1, bw[c][1], acc, 0, 0, 0);
                int col = (wv * 3 + c) * 16 + lr;
                int rb = rt * 16 + lg * 4;
                #pragma unroll
                for (int r = 0; r < 4; ++r) {
                    int row = rb + r;
                    if (row < 66) {
                        int s = (row >= 33) ? 1 : 0;
                        int q = row - s * 33;
                        float val = acc[r] + bias[c];
                        if (col < 64) {
                            int h = col >> 4, d = col & 15;
                            *(short*)(Qb + ((s * 4 + h) * 48 + q) * 32 + d * 2) = f2bs(val);
                        } else if (col < 128) {
                            int kc = col - 64; int h = kc >> 4, d = kc & 15;
                            *(short*)(Kb + ((s * 4 + h) * 48 + q) * 32 + d * 2) = f2bs(val);
                        } else {
                            int vc = col - 128; int h = vc >> 4, d = vc & 15;
                            if (q < 32)
                                *(short*)(Vt + ((s * 4 + h) * 16 + d) * 64 + ((q * 2) ^ pswz(d))) = f2bs(val);
                            else
                                V32[(s * 4 + h) * 16 + d] = val;
                        }
                    }
                }
            }
        }
    }
    __syncthreads();

    // ---- P2a: QK MFMA + softmax for both pairs; P kept packed in regs ----
    uint32 pk[2][3][4];
    {
        const short8 zero8 = {0, 0, 0, 0, 0, 0, 0, 0};
        #pragma unroll
        for (int pp = 0; pp < 2; ++pp) {
            int pair = 2 * wv + pp;
            int s = pair >> 2;
            short8 qf[3], kf[3];
            #pragma unroll
            for (int t = 0; t < 3; ++t) {
                qf[t] = (lg < 2) ? *(const short8*)(Qb + (pair * 48 + t * 16 + lr) * 32 + lg * 16) : zero8;
                kf[t] = (lg < 2) ? *(const short8*)(Kb + (pair * 48 + t * 16 + lr) * 32 + lg * 16) : zero8;
            }
            f32x4 S[3][3];
            #pragma unroll
            for (int qt = 0; qt < 3; ++qt)
                #pragma unroll
                for (int kt = 0; kt < 3; ++kt) {
                    f32x4 z = {0.f, 0.f, 0.f, 0.f};
                    S[qt][kt] = __builtin_amdgcn_mfma_f32_16x16x32_bf16(qf[qt], kf[kt], z, 0, 0, 0);
                }
            float mk0 = msk[s * 36 + lr];
            float mk1 = msk[s * 36 + 16 + lr];
            float mk2 = (lr == 0) ? msk[s * 36 + 32] : 0.f;
            #pragma unroll
            for (int qt = 0; qt < 3; ++qt) {
                #pragma unroll
                for (int r = 0; r < 4; ++r) {
                    float v0 = (mk0 > 0.f) ? S[qt][0][r] * 0.25f : -1e9f;
                    float v1 = (mk1 > 0.f) ? S[qt][1][r] * 0.25f : -1e9f;
                    float v2 = (mk2 > 0.f) ? S[qt][2][r] * 0.25f : -1e9f;
                    float m = fmaxf(fmaxf(v0, v1), v2);
                    m = fmaxf(m, __shfl_xor(m, 1));
                    m = fmaxf(m, __shfl_xor(m, 2));
                    m = fmaxf(m, __shfl_xor(m, 4));
                    m = fmaxf(m, __shfl_xor(m, 8));
                    float e0 = __expf(v0 - m), e1 = __expf(v1 - m), e2 = __expf(v2 - m);
                    float sm = e0 + e1 + e2;
                    sm += __shfl_xor(sm, 1);
                    sm += __shfl_xor(sm, 2);
                    sm += __shfl_xor(sm, 4);
                    sm += __shfl_xor(sm, 8);
                    float inv = 1.0f / sm;
                    pk[pp][qt][r] = pkbf(e0 * inv, e1 * inv);
                    if (lr == 0) P32[pair * 48 + qt * 16 + lg * 4 + r] = e2 * inv;
                }
            }
        }
    }
    __syncthreads();   // all Qb/Kb reads done; ob may now overwrite Qb

    // ---- P2b: PV MFMA via per-wave single-tile Pw; write ob (aliases Qb) ----
    {
        #pragma unroll
        for (int pp = 0; pp < 2; ++pp) {
            int pair = 2 * wv + pp;
            int s = pair >> 2, h = pair & 3;
            short8 vf = *(const short8*)(Vt + (pair * 16 + lr) * 64 + ((lg * 16) ^ pswz(lr)));
            float v32reg = V32[pair * 16 + lr];
            f32x4 C[3];
            #pragma unroll
            for (int qt = 0; qt < 3; ++qt) {
                // write this q-tile of P into per-wave Pw (rows = q local)
                #pragma unroll
                for (int r = 0; r < 4; ++r) {
                    int ql = lg * 4 + r;
                    uint32 p = pk[pp][qt][r];
                    char* prow = Pw + wv * 1024 + ql * 64;
                    int sz = pswz(ql);
                    *(short*)(prow + ((lr * 2) ^ sz)) = (short)(p & 0xffffu);
                    *(short*)(prow + (((16 + lr) * 2) ^ sz)) = (short)(p >> 16);
                }
                short8 pf = *(const short8*)(Pw + wv * 1024 + lr * 64 + ((lg * 16) ^ pswz(lr)));
                f32x4 z = {0.f, 0.f, 0.f, 0.f};
                C[qt] = __builtin_amdgcn_mfma_f32_16x16x32_bf16(pf, vf, z, 0, 0, 0);
            }
            #pragma unroll
            for (int qt = 0; qt < 3; ++qt) {
                #pragma unroll
                for (int r = 0; r < 4; ++r) {
                    int q = qt * 16 + lg * 4 + r;
                    if (q <= 32) {
                        float cv = C[qt][r] + P32[pair * 48 + q] * v32reg;
                        int row = s * 33 + q;
                        *(short*)(ob + ((row * 128 + (h * 16 + lr) * 2) ^ ((row & 7) << 4))) = f2bs(cv);
                    }
                }
            }
        }
    }
    __syncthreads();

    // ---- P3: out_proj GEMM: ob -> o2b (aliases Kb) ----
    {
        int col = wv * 16 + lr;
        short8 b0 = *(const short8*)(wob_g + col * 64 + lg * 8);
        short8 b1 = *(const short8*)(wob_g + col * 64 + 32 + lg * 8);
        float bias = outp_b[col];
        for (int rt = 0; rt < 5; ++rt) {
            int arow = rt * 16 + lr;
            int sw = (arow & 7) << 4;
            short8 a0 = *(const short8*)(ob + ((arow * 128 + lg * 16) ^ sw));
            short8 a1 = *(const short8*)(ob + ((arow * 128 + 64 + lg * 16) ^ sw));
            f32x4 acc = {0.f, 0.f, 0.f, 0.f};
            acc = __builtin_amdgcn_mfma_f32_16x16x32_bf16(a0, b0, acc, 0, 0, 0);
            acc = __builtin_amdgcn_mfma_f32_16x16x32_bf16(a1, b1, acc, 0, 0, 0);
            int rb = rt * 16 + lg * 4;
            #pragma unroll
            for (int r = 0; r < 4; ++r) {
                int row = rb + r;
                if (row < 66)
                    *(short*)(o2b + ((row * 128 + col * 2) ^ ((row & 7) << 4))) = f2bs(acc[r] + bias);
            }
        }
    }
    __syncthreads();

    // ---- P4: sa GEMM + residual + mask, pool fused via shfl (no res buf) ----
    {
        int col = wv * 16 + lr;
        short8 b0 = *(const short8*)(wsb_g + col * 64 + lg * 8);
        short8 b1 = *(const short8*)(wsb_g + col * 64 + 32 + lg * 8);
        float bias = sa_b[col];
        float ps0 = 0.f, ps1 = 0.f;
        for (int rt = 0; rt < 5; ++rt) {
            int arow = rt * 16 + lr;
            int sw = (arow & 7) << 4;
            short8 a0 = *(const short8*)(o2b + ((arow * 128 + lg * 16) ^ sw));
            short8 a1 = *(const short8*)(o2b + ((arow * 128 + 64 + lg * 16) ^ sw));
            f32x4 acc = {0.f, 0.f, 0.f, 0.f};
            acc = __builtin_amdgcn_mfma_f32_16x16x32_bf16(a0, b0, acc, 0, 0, 0);
            acc = __builtin_amdgcn_mfma_f32_16x16x32_bf16(a1, b1, acc, 0, 0, 0);
            int rb = rt * 16 + lg * 4;
            #pragma unroll
            for (int r = 0; r < 4; ++r) {
                int row = rb + r;
                if (row < 66) {
                    int ss = (row >= 33) ? 1 : 0;
                    int m = row - ss * 33;
                    float zev = bf2f(*(const unsigned short*)(zeb + ((row * 128 + col * 2) ^ ((row & 7) << 4))));
                    float rv = msk[ss * 36 + m] * (zev + fmaxf(acc[r] + bias, 0.f));
                    if (ss) ps1 += rv; else ps0 += rv;
                }
            }
        }
        ps0 += __shfl_xor(ps0, 16); ps0 += __shfl_xor(ps0, 32);
        ps1 += __shfl_xor(ps1, 16); ps1 += __shfl_xor(ps1, 32);
        if (lg == 0) {
            pooled[col] = ps0 * (1.0f / 33.0f);
            pooled[64 + col] = ps1 * (1.0f / 33.0f);
        }
    }
    __syncthreads();

    // ---- P5: zin = relu(zin_x + pool_w[:,290:] @ pooled + b) ----
    {
        int s = tid >> 7, r = tid & 127;
        float acc = pool_b[r] + zin_x_ws[(size_t)(gs0 + s) * 128 + r];
        const float* wrow = pool_w + (size_t)r * 354 + 290;
        const float* pl = pooled + s * 64;
        #pragma unroll 8
        for (int e = 0; e < 64; ++e) acc = fmaf(wrow[e], pl[e], acc);
        zin[(size_t)(gs0 + s) * 128 + r] = fmaxf(acc, 0.f);
    }
}

// ---------------------------------------------------------------------------
// Kernel: LSTM scan (unchanged)
// ---------------------------------------------------------------------------
__global__ __launch_bounds__(512) void k_lstm(
    const float* __restrict__ zin, const float* __restrict__ w_ih,
    const float* __restrict__ w_hh, const float* __restrict__ b_ih,
    const float* __restrict__ b_hh, const int* __restrict__ done,
    float* __restrict__ h_all)
{
    extern __shared__ float lds[];
    float* xp = lds;
    float* zl = xp + 64 * 512;
    float* hl = zl + 128;
    float* gl = hl + 128;
    const int s = blockIdx.x;
    const int r = threadIdx.x;
    const int b = s >> 3;

    float4 w[32];
    {
        const float4* wsrc = (const float4*)(w_ih + (size_t)r * 128);
        #pragma unroll
        for (int j = 0; j < 32; ++j) w[j] = wsrc[j];
    }
    const float bias = b_ih[r] + b_hh[r];

    for (int t = 0; t < T_DIM; ++t) {
        __syncthreads();
        if (r < 128) zl[r] = zin[((size_t)t * BA + s) * 128 + r];
        __syncthreads();
        const float4* x4 = (const float4*)zl;
        float a0 = 0.f, a1 = 0.f, a2 = 0.f, a3 = 0.f;
        #pragma unroll
        for (int j = 0; j < 32; ++j) {
            float4 wa = w[j], xa = x4[j];
            a0 = fmaf(wa.x, xa.x, a0);
            a1 = fmaf(wa.y, xa.y, a1);
            a2 = fmaf(wa.z, xa.z, a2);
            a3 = fmaf(wa.w, xa.w, a3);
        }
        xp[t * 512 + r] = bias + ((a0 + a1) + (a2 + a3));
    }

    {
        const float4* wsrc = (const float4*)(w_hh + (size_t)r * 128);
        #pragma unroll
        for (int j = 0; j < 32; ++j) w[j] = wsrc[j];
    }
    if (r < 128) hl[r] = 0.0f;
    float c = 0.0f;
    __syncthreads();

    for (int t = 0; t < T_DIM; ++t) {
        const float4* h4 = (const float4*)hl;
        float a0 = 0.f, a1 = 0.f, a2 = 0.f, a3 = 0.f;
        #pragma unroll
        for (int j = 0; j < 32; ++j) {
            float4 wa = w[j], xa = h4[j];
            a0 = fmaf(wa.x, xa.x, a0);
            a1 = fmaf(wa.y, xa.y, a1);
            a2 = fmaf(wa.z, xa.z, a2);
            a3 = fmaf(wa.w, xa.w, a3);
        }
        gl[r] = xp[t * 512 + r] + ((a0 + a1) + (a2 + a3));
        __syncthreads();
        if (r < 128) {
            float keep = done[t * B_DIM + b] ? 0.0f : 1.0f;
            float gi = gl[r], gf = gl[r + 128], gg = gl[r + 256], go = gl[r + 384];
            c *= keep;
            c = sigf(gf) * c + sigf(gi) * tanhf(gg);
            float hn = sigf(go) * tanhf(c);
            float keepn = (t < T_DIM - 1) ? (done[(t + 1) * B_DIM + b] ? 0.0f : 1.0f) : 1.0f;
            hl[r] = hn * keepn;
            h_all[((size_t)t * BA + s) * 128 + r] = hn;
        }
        __syncthreads();
    }
}

// ---------------------------------------------------------------------------
// Kernel: categorical heads (unchanged)
// ---------------------------------------------------------------------------
__global__ __launch_bounds__(256) void k_heads(
    const float* __restrict__ h_all, const int* __restrict__ actions,
    const float* __restrict__ h0w, const float* __restrict__ h0b,
    const float* __restrict__ h1w, const float* __restrict__ h1b,
    float* __restrict__ out)
{
    __shared__ float w0[640], w1[640], b0[8], b1[8];
    const int tid = threadIdx.x;
    for (int i = tid; i < 640; i += 256) { w0[i] = h0w[i]; w1[i] = h1w[i]; }
    if (tid < 5) { b0[tid] = h0b[tid]; b1[tid] = h1b[tid]; }
    __syncthreads();
    const int g = blockIdx.x * 256 + tid;
    const float* h = h_all + (size_t)g * 128;
    float l0[5], l1[5];
    #pragma unroll
    for (int cc = 0; cc < 5; ++cc) { l0[cc] = b0[cc]; l1[cc] = b1[cc]; }
    for (int j = 0; j < 128; ++j) {
        float hv = h[j];
        #pragma unroll
        for (int cc = 0; cc < 5; ++cc) {
            l0[cc] = fmaf(w0[cc * 128 + j], hv, l0[cc]);
            l1[cc] = fmaf(w1[cc * 128 + j], hv, l1[cc]);
        }
    }
    int a0 = actions[(size_t)g * 2], a1 = actions[(size_t)g * 2 + 1];
    float m0 = l0[0], m1 = l1[0];
    #pragma unroll
    for (int cc = 1; cc < 5; ++cc) { m0 = fmaxf(m0, l0[cc]); m1 = fmaxf(m1, l1[cc]); }
    float s0 = 0.f, s1 = 0.f;
    #pragma unroll
    for (int cc = 0; cc < 5; ++cc) { s0 += expf(l0[cc] - m0); s1 += expf(l1[cc] - m1); }
    float lse0 = m0 + logf(s0), lse1 = m1 + logf(s1);
    float ent0 = 0.f, ent1 = 0.f, lp0 = 0.f, lp1 = 0.f;
    #pragma unroll
    for (int cc = 0; cc < 5; ++cc) {
        float p0 = l0[cc] - lse0, p1 = l1[cc] - lse1;
        ent0 -= expf(p0) * p0;
        ent1 -= expf(p1) * p1;
        if (cc == a0) lp0 = p0;
        if (cc == a1) lp1 = p1;
    }
    out[ACT_OFF + (size_t)g * 2]     = (float)a0;
    out[ACT_OFF + (size_t)g * 2 + 1] = (float)a1;
    out[LP_OFF + g]                  = lp0 * lp1;
    out[ENT_OFF + (size_t)g * 2]     = ent0;
    out[ENT_OFF + (size_t)g * 2 + 1] = ent1;
}

extern "C" void kernel_launch(void* const* d_in, const int* in_sizes, int n_in,
                              void* d_out, int out_size, void* d_ws, size_t ws_size,
                              hipStream_t stream)
{
    const float* x_agent = (const float*)d_in[0];
    const float* x_lidar = (const float*)d_in[1];
    const float* x_safe  = (const float*)d_in[2];
    const float* x_ent0  = (const float*)d_in[3];
    const float* x_ent1  = (const float*)d_in[4];
    const int*   mask0   = (const int*)d_in[5];
    const int*   mask1   = (const int*)d_in[6];
    const int*   done    = (const int*)d_in[7];
    const int*   actions = (const int*)d_in[8];
    const float* conv_w  = (const float*)d_in[9];
    const float* conv_b  = (const float*)d_in[10];
    const float* self_w  = (const float*)d_in[11];
    const float* self_b  = (const float*)d_in[12];
    const float* ent0_w  = (const float*)d_in[13];
    const float* ent0_b  = (const float*)d_in[14];
    const float* ent1_w  = (const float*)d_in[15];
    const float* ent1_b  = (const float*)d_in[16];
    const float* inp_w   = (const float*)d_in[17];
    const float* inp_b   = (const float*)d_in[18];
    const float* outp_w  = (const float*)d_in[19];
    const float* outp_b  = (const float*)d_in[20];
    const float* sa_w    = (const float*)d_in[21];
    const float* sa_b    = (const float*)d_in[22];
    const float* pool_w  = (const float*)d_in[23];
    const float* pool_b  = (const float*)d_in[24];
    const float* w_ih    = (const float*)d_in[25];
    const float* w_hh    = (const float*)d_in[26];
    const float* b_ih    = (const float*)d_in[27];
    const float* b_hh    = (const float*)d_in[28];
    const float* h0w     = (const float*)d_in[29];
    const float* h0b     = (const float*)d_in[30];
    const float* h1w     = (const float*)d_in[31];
    const float* h1b     = (const float*)d_in[32];

    __hip_bfloat16* z_ent = (__hip_bfloat16*)d_ws;
    float* zin_x = (float*)((char*)d_ws + (size_t)S_TOT * 2112 * 2);
    float* zin   = zin_x + (size_t)S_TOT * 128;
    float* h_all = zin + (size_t)S_TOT * 128;
    short* wqkvb = (short*)(h_all + (size_t)S_TOT * 128);
    short* wob   = wqkvb + 12288;
    short* wsb   = wob + 4096;
    short* Wf    = wsb + 4096;
    short* We0   = Wf + 102400;
    short* We1   = We0 + 1024;

    k_cvt2<<<400, 256, 0, stream>>>(inp_w, outp_w, sa_w, self_w, pool_w, ent0_w, ent1_w,
                                    wqkvb, wob, wsb, Wf, We0, We1);

    k_frontM<<<256, 256, FM_TOTAL, stream>>>(
        x_agent, x_lidar, x_safe, x_ent0, x_ent1,
        conv_w, conv_b, self_b, ent0_b, ent1_b,
        Wf, We0, We1, z_ent, zin_x);

    k_attnE<<<S_TOT / 2, 256, AT_TOTAL, stream>>>(
        z_ent, zin_x, mask0, mask1, wqkvb, inp_b, wob, outp_b,
        wsb, sa_b, pool_w, pool_b, zin);

    size_t lstm_lds = (size_t)(64 * 512 + 128 + 128 + 512) * sizeof(float);
    k_lstm<<<BA, 512, lstm_lds, stream>>>(zin, w_ih, w_hh, b_ih, b_hh, done, h_all);

    k_heads<<<S_TOT / 256, 256, 0, stream>>>(h_all, actions, h0w, h0b, h1w, h1b, (float*)d_out);
}

// Round 8
// 442.253 us; speedup vs baseline: 13.7724x; 1.1026x over previous
//
#include <hip/hip_runtime.h>
#include <hip/hip_bf16.h>
#include <math.h>

#define T_DIM 64
#define B_DIM 32
#define N_ENT 16
#define M_SLOTS 33
#define S_TOT 16384
#define BA 256
#define SB 64

#define ACT_OFF 0
#define LP_OFF 32768
#define ENT_OFF 49152

typedef __attribute__((ext_vector_type(8))) short short8;
typedef __attribute__((ext_vector_type(4))) float f32x4;
typedef unsigned int uint32;

__device__ __forceinline__ float sigf(float x) { return 1.0f / (1.0f + expf(-x)); }
__device__ __forceinline__ float bf2f(unsigned short u) {
    union { unsigned int i; float f; } a; a.i = ((unsigned int)u) << 16; return a.f;
}
__device__ __forceinline__ uint32 pkbf(float a, float b) {
    __hip_bfloat16 ha = __float2bfloat16(a), hb = __float2bfloat16(b);
    return (uint32)(*(unsigned short*)&ha) | ((uint32)(*(unsigned short*)&hb) << 16);
}
__device__ __forceinline__ short f2bs(float v) {
    __hip_bfloat16 h = __float2bfloat16(v); return *(short*)&h;
}
__device__ __forceinline__ int pswz(int row) { return (((row & 3) ^ ((row >> 2) & 3)) << 4); }

// ---------------------------------------------------------------------------
// k_cvt2: pack all MFMA weights to bf16 in ws (unchanged).
// ---------------------------------------------------------------------------
__global__ __launch_bounds__(256) void k_cvt2(
    const float* __restrict__ inp_w, const float* __restrict__ outp_w,
    const float* __restrict__ sa_w, const float* __restrict__ self_w,
    const float* __restrict__ pool_w, const float* __restrict__ ent0_w,
    const float* __restrict__ ent1_w,
    short* __restrict__ wq, short* __restrict__ wo, short* __restrict__ ws,
    short* __restrict__ Wf, short* __restrict__ We0, short* __restrict__ We1)
{
    int i = blockIdx.x * 256 + threadIdx.x;
    if (i < 12288) wq[i] = f2bs(inp_w[i]);
    if (i < 4096) { wo[i] = f2bs(outp_w[i]); ws[i] = f2bs(sa_w[i]); }
    if (i < 1024) {
        int e = i >> 4, k = i & 15;
        We0[i] = f2bs(k < 12 ? ent0_w[e * 302 + k] : 0.f);
        We1[i] = f2bs(k < 8 ? ent1_w[e * 298 + k] : 0.f);
    }
    if (i < 102400) {
        int c = i / 320, k = i - c * 320;
        float v = 0.f;
        if (k < 290) {
            if (c < 64) v = self_w[c * 580 + k] + self_w[c * 580 + 290 + k];
            else if (c < 192) v = pool_w[(size_t)(c - 64) * 354 + k];
            else if (c < 256) v = ent0_w[(c - 192) * 302 + 12 + k];
            else v = ent1_w[(c - 256) * 298 + 8 + k];
        }
        Wf[i] = f2bs(v);
    }
}

// ---------------------------------------------------------------------------
// k_frontM: MFMA front end (unchanged).
// ---------------------------------------------------------------------------
#define FM_XSB 0
#define FM_XP0 40960
#define FM_XP1 58368
#define FM_AE  75776
#define FM_TOTAL 141312

__global__ __launch_bounds__(256, 1) void k_frontM(
    const float* __restrict__ xag, const float* __restrict__ xlid,
    const float* __restrict__ xsz, const float* __restrict__ xe0,
    const float* __restrict__ xe1,
    const float* __restrict__ conv_w, const float* __restrict__ conv_b,
    const float* __restrict__ self_b, const float* __restrict__ ent0_b,
    const float* __restrict__ ent1_b,
    const short* __restrict__ Wf, const short* __restrict__ We0,
    const short* __restrict__ We1,
    __hip_bfloat16* __restrict__ z_ent, float* __restrict__ zin_x)
{
    extern __shared__ char smem[];
    char* xsb = smem + FM_XSB;
    float* xp0f = (float*)(smem + FM_XP0);
    float* xp1f = (float*)(smem + FM_XP1);
    char* ae = smem + FM_AE;
    float* lidf = (float*)(smem + FM_AE);

    const int tid = threadIdx.x;
    const int s0 = blockIdx.x * SB;
    const int wv = __builtin_amdgcn_readfirstlane(tid >> 6);
    const int l = tid & 63;
    const int lr = l & 15;
    const int lg = l >> 4;

    for (int i = tid; i < SB * 32; i += 256) {
        int d = i & 31, sl = i >> 5;
        lidf[d * 66 + sl] = xlid[(size_t)s0 * 32 + i];
    }
    for (int i = tid; i < SB * 16; i += 256) {
        int sl = i >> 4, d = i & 15;
        *(short*)(xsb + ((sl * 640 + d * 2) ^ ((sl & 7) << 4))) = f2bs(xag[(size_t)s0 * 16 + i]);
    }
    for (int i = tid; i < SB * 4; i += 256) {
        int sl = i >> 2, d = i & 3;
        *(short*)(xsb + ((sl * 640 + (286 + d) * 2) ^ ((sl & 7) << 4))) = f2bs(xsz[(size_t)s0 * 4 + i]);
    }
    for (int i = tid; i < SB * 30; i += 256) {
        int sl = i / 30, d = 290 + (i - (i / 30) * 30);
        *(short*)(xsb + ((sl * 640 + d * 2) ^ ((sl & 7) << 4))) = 0;
    }
    __syncthreads();
    for (int i = tid; i < 270 * 64; i += 256) {
        int cp = i >> 6, sl = i & 63;
        int c = cp / 30, p = cp - c * 30;
        float v = conv_b[c] + conv_w[c * 3] * lidf[p * 66 + sl]
                + conv_w[c * 3 + 1] * lidf[(p + 1) * 66 + sl]
                + conv_w[c * 3 + 2] * lidf[(p + 2) * 66 + sl];
        *(short*)(xsb + ((sl * 640 + (16 + cp) * 2) ^ ((sl & 7) << 4))) = f2bs(fmaxf(v, 0.f));
    }
    __syncthreads();

    f32x4 acc[4][5];
    #pragma unroll
    for (int rt = 0; rt < 4; ++rt)
        #pragma unroll
        for (int c = 0; c < 5; ++c) acc[rt][c] = (f32x4){0.f, 0.f, 0.f, 0.f};

    for (int kk = 0; kk < 10; ++kk) {
        short8 af[4];
        #pragma unroll
        for (int rt = 0; rt < 4; ++rt) {
            int row = rt * 16 + lr;
            af[rt] = *(const short8*)(xsb + ((row * 640 + kk * 64 + lg * 16) ^ ((row & 7) << 4)));
        }
        short8 bf[5];
        #pragma unroll
        for (int c = 0; c < 5; ++c) {
            int col = (wv * 5 + c) * 16 + lr;
            bf[c] = *(const short8*)(Wf + (size_t)col * 320 + kk * 32 + lg * 8);
        }
        #pragma unroll
        for (int rt = 0; rt < 4; ++rt)
            #pragma unroll
            for (int c = 0; c < 5; ++c)
                acc[rt][c] = __builtin_amdgcn_mfma_f32_16x16x32_bf16(af[rt], bf[c], acc[rt][c], 0, 0, 0);
    }

    for (int i = tid; i < 16384; i += 256) ((uint32*)ae)[i] = 0;

    #pragma unroll
    for (int rt = 0; rt < 4; ++rt) {
        #pragma unroll
        for (int c = 0; c < 5; ++c) {
            int ct = wv * 5 + c;
            int gc = ct * 16 + lr;
            int rowb = rt * 16 + lg * 4;
            f32x4 a = acc[rt][c];
            if (ct * 16 < 64) {
                float bias = self_b[gc];
                #pragma unroll
                for (int r = 0; r < 4; ++r)
                    z_ent[(size_t)(s0 + rowb + r) * 2112 + gc] = __float2bfloat16(fmaxf(a[r] + bias, 0.f));
            } else if (ct * 16 < 192) {
                int r2 = gc - 64;
                #pragma unroll
                for (int r = 0; r < 4; ++r)
                    zin_x[(size_t)(s0 + rowb + r) * 128 + r2] = a[r];
            } else if (ct * 16 < 256) {
                float bias = ent0_b[gc - 192];
                #pragma unroll
                for (int r = 0; r < 4; ++r)
                    xp0f[(rowb + r) * 68 + (gc - 192)] = a[r] + bias;
            } else {
                float bias = ent1_b[gc - 256];
                #pragma unroll
                for (int r = 0; r < 4; ++r)
                    xp1f[(rowb + r) * 68 + (gc - 256)] = a[r] + bias;
            }
        }
    }
    __syncthreads();

    for (int i = tid; i < SB * 192; i += 256) {
        int sl = i / 192, r = i - sl * 192;
        int n = r / 12, d = r - n * 12;
        int row = sl * 16 + n;
        *(short*)(ae + ((row * 64 + d * 2) ^ ((row & 3) << 4))) = f2bs(xe0[(size_t)s0 * 192 + i]);
    }
    __syncthreads();

    {
        short8 bz = {0, 0, 0, 0, 0, 0, 0, 0};
        short8 be[4];
        #pragma unroll
        for (int ct = 0; ct < 4; ++ct) {
            int col = ct * 16 + lr;
            short8 bv = *(const short8*)(We0 + col * 16 + (lg & 1) * 8);
            be[ct] = (lg < 2) ? bv : bz;
        }
        for (int rt8 = 0; rt8 < 16; ++rt8) {
            int rt = wv * 16 + rt8;
            int row = rt * 16 + lr;
            short8 af = *(const short8*)(ae + ((row * 64 + lg * 16) ^ ((row & 3) << 4)));
            #pragma unroll
            for (int ct = 0; ct < 4; ++ct) {
                f32x4 a2 = {0.f, 0.f, 0.f, 0.f};
                a2 = __builtin_amdgcn_mfma_f32_16x16x32_bf16(af, be[ct], a2, 0, 0, 0);
                int e = ct * 16 + lr;
                float xpv = xp0f[rt * 68 + e];
                #pragma unroll
                for (int r = 0; r < 4; ++r) {
                    int n = lg * 4 + r;
                    z_ent[(size_t)(s0 + rt) * 2112 + (1 + n) * 64 + e] =
                        __float2bfloat16(fmaxf(a2[r] + xpv, 0.f));
                }
            }
        }
    }
    __syncthreads();

    for (int i = tid; i < SB * 128; i += 256) {
        int sl = i >> 7, r = i & 127;
        int n = r >> 3, d = r & 7;
        int row = sl * 16 + n;
        *(short*)(ae + ((row * 64 + d * 2) ^ ((row & 3) << 4))) = f2bs(xe1[(size_t)s0 * 128 + i]);
    }
    for (int i = tid; i < SB * 16 * 4; i += 256) {
        int row = i >> 2, d = 8 + (i & 3);
        *(short*)(ae + ((row * 64 + d * 2) ^ ((row & 3) << 4))) = 0;
    }
    __syncthreads();

    {
        short8 bz = {0, 0, 0, 0, 0, 0, 0, 0};
        short8 be[4];
        #pragma unroll
        for (int ct = 0; ct < 4; ++ct) {
            int col = ct * 16 + lr;
            short8 bv = *(const short8*)(We1 + col * 16 + (lg & 1) * 8);
            be[ct] = (lg < 2) ? bv : bz;
        }
        for (int rt8 = 0; rt8 < 16; ++rt8) {
            int rt = wv * 16 + rt8;
            int row = rt * 16 + lr;
            short8 af = *(const short8*)(ae + ((row * 64 + lg * 16) ^ ((row & 3) << 4)));
            #pragma unroll
            for (int ct = 0; ct < 4; ++ct) {
                f32x4 a2 = {0.f, 0.f, 0.f, 0.f};
                a2 = __builtin_amdgcn_mfma_f32_16x16x32_bf16(af, be[ct], a2, 0, 0, 0);
                int e = ct * 16 + lr;
                float xpv = xp1f[rt * 68 + e];
                #pragma unroll
                for (int r = 0; r < 4; ++r) {
                    int n = lg * 4 + r;
                    z_ent[(size_t)(s0 + rt) * 2112 + (17 + n) * 64 + e] =
                        __float2bfloat16(fmaxf(a2[r] + xpv, 0.f));
                }
            }
        }
    }
}

// ---------------------------------------------------------------------------
// k_attnF: full-MFMA attention, 39.7 KB LDS -> 4 blocks/CU.
// zeb eliminated: P1 A-frags and P4 residual read z_ent from global (L1/L2).
// ---------------------------------------------------------------------------
#define AT_QB   0
#define AT_KB   12288
#define AT_VT   24576
#define AT_PW   32768
#define AT_P32  36864
#define AT_V32  38400
#define AT_MSK  38912
#define AT_POOL 39200
#define AT_TOTAL 39712

__global__ __launch_bounds__(256, 4) void k_attnF(
    const __hip_bfloat16* __restrict__ z_ent, const float* __restrict__ zin_x_ws,
    const int* __restrict__ mask0, const int* __restrict__ mask1,
    const short* __restrict__ wqkvb, const float* __restrict__ inp_b,
    const short* __restrict__ wob_g, const float* __restrict__ outp_b,
    const short* __restrict__ wsb_g, const float* __restrict__ sa_b,
    const float* __restrict__ pool_w, const float* __restrict__ pool_b,
    float* __restrict__ zin)
{
    extern __shared__ char smem[];
    char*  Qb  = smem + AT_QB;            // bf16 [8 pair][48 q][16 d]; later ob
    char*  Kb  = smem + AT_KB;            // bf16 [8 pair][48 slot][16 d]; later o2b
    char*  Vt  = smem + AT_VT;            // bf16 [8 pair][16 d][32 slot] swz
    char*  Pw  = smem + AT_PW;            // bf16 [4 wave][16 row][32 slot] swz
    float* P32 = (float*)(smem + AT_P32); // f32 [8 pair][48 q]
    float* V32 = (float*)(smem + AT_V32); // f32 [8 pair][16 d]
    float* msk = (float*)(smem + AT_MSK);
    float* pooled = (float*)(smem + AT_POOL);
    char*  ob  = Qb;                      // alias (after P2a barrier)
    char*  o2b = Kb;                      // alias (after P2b barrier)

    const int tid = threadIdx.x;
    const int gs0 = blockIdx.x * 2;
    const short* zg = (const short*)(z_ent + (size_t)gs0 * 2112);  // [66 rows][64]

    // ---- P0: mask only (zeb staging eliminated) ----
    if (tid < 32) { int s = tid >> 4, i2 = tid & 15; msk[s * 36 + 1 + i2] = (float)mask0[(size_t)(gs0 + s) * 16 + i2]; }
    else if (tid < 64) { int u = tid - 32; int s = u >> 4, i2 = u & 15; msk[s * 36 + 17 + i2] = (float)mask1[(size_t)(gs0 + s) * 16 + i2]; }
    else if (tid < 66) msk[(tid - 64) * 36] = 1.0f;
    __syncthreads();

    const int wv = __builtin_amdgcn_readfirstlane(tid >> 6);
    const int l  = tid & 63;
    const int lr = l & 15;
    const int lg = l >> 4;

    // ---- P1: in_proj GEMM (A from global) -> Qb / Kb / Vt / V32 ----
    {
        short8 bw[3][2]; float bias[3];
        #pragma unroll
        for (int c = 0; c < 3; ++c) {
            int col = (wv * 3 + c) * 16 + lr;
            bw[c][0] = *(const short8*)(wqkvb + col * 64 + lg * 8);
            bw[c][1] = *(const short8*)(wqkvb + col * 64 + 32 + lg * 8);
            bias[c] = inp_b[col];
        }
        for (int rt = 0; rt < 5; ++rt) {
            int arow = rt * 16 + lr;
            // rows >= 66 read trailing data (next sample / ws) -> garbage,
            // row-contained in MFMA, discarded by row<66 guards below.
            short8 a0 = *(const short8*)(zg + arow * 64 + lg * 8);
            short8 a1 = *(const short8*)(zg + arow * 64 + 32 + lg * 8);
            #pragma unroll
            for (int c = 0; c < 3; ++c) {
                f32x4 acc = {0.f, 0.f, 0.f, 0.f};
                acc = __builtin_amdgcn_mfma_f32_16x16x32_bf16(a0, bw[c][0], acc, 0, 0, 0);
                acc = __builtin_amdgcn_mfma_f32_16x16x32_bf16(a1, bw[c][1], acc, 0, 0, 0);
                int col = (wv * 3 + c) * 16 + lr;
                int rb = rt * 16 + lg * 4;
                #pragma unroll
                for (int r = 0; r < 4; ++r) {
                    int row = rb + r;
                    if (row < 66) {
                        int s = (row >= 33) ? 1 : 0;
                        int q = row - s * 33;
                        float val = acc[r] + bias[c];
                        if (col < 64) {
                            int h = col >> 4, d = col & 15;
                            *(short*)(Qb + ((s * 4 + h) * 48 + q) * 32 + d * 2) = f2bs(val);
                        } else if (col < 128) {
                            int kc = col - 64; int h = kc >> 4, d = kc & 15;
                            *(short*)(Kb + ((s * 4 + h) * 48 + q) * 32 + d * 2) = f2bs(val);
                        } else {
                            int vc = col - 128; int h = vc >> 4, d = vc & 15;
                            if (q < 32)
                                *(short*)(Vt + ((s * 4 + h) * 16 + d) * 64 + ((q * 2) ^ pswz(d))) = f2bs(val);
                            else
                                V32[(s * 4 + h) * 16 + d] = val;
                        }
                    }
                }
            }
        }
    }
    __syncthreads();

    // ---- P2a: QK MFMA + softmax for both pairs; P kept packed in regs ----
    uint32 pk[2][3][4];
    {
        const short8 zero8 = {0, 0, 0, 0, 0, 0, 0, 0};
        #pragma unroll
        for (int pp = 0; pp < 2; ++pp) {
            int pair = 2 * wv + pp;
            int s = pair >> 2;
            short8 qf[3], kf[3];
            #pragma unroll
            for (int t = 0; t < 3; ++t) {
                qf[t] = (lg < 2) ? *(const short8*)(Qb + (pair * 48 + t * 16 + lr) * 32 + lg * 16) : zero8;
                kf[t] = (lg < 2) ? *(const short8*)(Kb + (pair * 48 + t * 16 + lr) * 32 + lg * 16) : zero8;
            }
            f32x4 S[3][3];
            #pragma unroll
            for (int qt = 0; qt < 3; ++qt)
                #pragma unroll
                for (int kt = 0; kt < 3; ++kt) {
                    f32x4 z = {0.f, 0.f, 0.f, 0.f};
                    S[qt][kt] = __builtin_amdgcn_mfma_f32_16x16x32_bf16(qf[qt], kf[kt], z, 0, 0, 0);
                }
            float mk0 = msk[s * 36 + lr];
            float mk1 = msk[s * 36 + 16 + lr];
            float mk2 = (lr == 0) ? msk[s * 36 + 32] : 0.f;
            #pragma unroll
            for (int qt = 0; qt < 3; ++qt) {
                #pragma unroll
                for (int r = 0; r < 4; ++r) {
                    float v0 = (mk0 > 0.f) ? S[qt][0][r] * 0.25f : -1e9f;
                    float v1 = (mk1 > 0.f) ? S[qt][1][r] * 0.25f : -1e9f;
                    float v2 = (mk2 > 0.f) ? S[qt][2][r] * 0.25f : -1e9f;
                    float m = fmaxf(fmaxf(v0, v1), v2);
                    m = fmaxf(m, __shfl_xor(m, 1));
                    m = fmaxf(m, __shfl_xor(m, 2));
                    m = fmaxf(m, __shfl_xor(m, 4));
                    m = fmaxf(m, __shfl_xor(m, 8));
                    float e0 = __expf(v0 - m), e1 = __expf(v1 - m), e2 = __expf(v2 - m);
                    float sm = e0 + e1 + e2;
                    sm += __shfl_xor(sm, 1);
                    sm += __shfl_xor(sm, 2);
                    sm += __shfl_xor(sm, 4);
                    sm += __shfl_xor(sm, 8);
                    float inv = 1.0f / sm;
                    pk[pp][qt][r] = pkbf(e0 * inv, e1 * inv);
                    if (lr == 0) P32[pair * 48 + qt * 16 + lg * 4 + r] = e2 * inv;
                }
            }
        }
    }
    __syncthreads();   // all Qb/Kb reads done; ob may now overwrite Qb

    // ---- P2b: PV MFMA via per-wave single-tile Pw; write ob (aliases Qb) ----
    {
        #pragma unroll
        for (int pp = 0; pp < 2; ++pp) {
            int pair = 2 * wv + pp;
            int s = pair >> 2, h = pair & 3;
            short8 vf = *(const short8*)(Vt + (pair * 16 + lr) * 64 + ((lg * 16) ^ pswz(lr)));
            float v32reg = V32[pair * 16 + lr];
            f32x4 C[3];
            #pragma unroll
            for (int qt = 0; qt < 3; ++qt) {
                #pragma unroll
                for (int r = 0; r < 4; ++r) {
                    int ql = lg * 4 + r;
                    uint32 p = pk[pp][qt][r];
                    char* prow = Pw + wv * 1024 + ql * 64;
                    int sz = pswz(ql);
                    *(short*)(prow + ((lr * 2) ^ sz)) = (short)(p & 0xffffu);
                    *(short*)(prow + (((16 + lr) * 2) ^ sz)) = (short)(p >> 16);
                }
                short8 pf = *(const short8*)(Pw + wv * 1024 + lr * 64 + ((lg * 16) ^ pswz(lr)));
                f32x4 z = {0.f, 0.f, 0.f, 0.f};
                C[qt] = __builtin_amdgcn_mfma_f32_16x16x32_bf16(pf, vf, z, 0, 0, 0);
            }
            #pragma unroll
            for (int qt = 0; qt < 3; ++qt) {
                #pragma unroll
                for (int r = 0; r < 4; ++r) {
                    int q = qt * 16 + lg * 4 + r;
                    if (q <= 32) {
                        float cv = C[qt][r] + P32[pair * 48 + q] * v32reg;
                        int row = s * 33 + q;
                        *(short*)(ob + ((row * 128 + (h * 16 + lr) * 2) ^ ((row & 7) << 4))) = f2bs(cv);
                    }
                }
            }
        }
    }
    __syncthreads();

    // ---- P3: out_proj GEMM: ob -> o2b (aliases Kb) ----
    {
        int col = wv * 16 + lr;
        short8 b0 = *(const short8*)(wob_g + col * 64 + lg * 8);
        short8 b1 = *(const short8*)(wob_g + col * 64 + 32 + lg * 8);
        float bias = outp_b[col];
        for (int rt = 0; rt < 5; ++rt) {
            int arow = rt * 16 + lr;
            int sw = (arow & 7) << 4;
            short8 a0 = *(const short8*)(ob + ((arow * 128 + lg * 16) ^ sw));
            short8 a1 = *(const short8*)(ob + ((arow * 128 + 64 + lg * 16) ^ sw));
            f32x4 acc = {0.f, 0.f, 0.f, 0.f};
            acc = __builtin_amdgcn_mfma_f32_16x16x32_bf16(a0, b0, acc, 0, 0, 0);
            acc = __builtin_amdgcn_mfma_f32_16x16x32_bf16(a1, b1, acc, 0, 0, 0);
            int rb = rt * 16 + lg * 4;
            #pragma unroll
            for (int r = 0; r < 4; ++r) {
                int row = rb + r;
                if (row < 66)
                    *(short*)(o2b + ((row * 128 + col * 2) ^ ((row & 7) << 4))) = f2bs(acc[r] + bias);
            }
        }
    }
    __syncthreads();

    // ---- P4: sa GEMM + residual (z_ent from global) + mask, pool via shfl ----
    {
        int col = wv * 16 + lr;
        short8 b0 = *(const short8*)(wsb_g + col * 64 + lg * 8);
        short8 b1 = *(const short8*)(wsb_g + col * 64 + 32 + lg * 8);
        float bias = sa_b[col];
        float ps0 = 0.f, ps1 = 0.f;
        for (int rt = 0; rt < 5; ++rt) {
            int arow = rt * 16 + lr;
            int sw = (arow & 7) << 4;
            short8 a0 = *(const short8*)(o2b + ((arow * 128 + lg * 16) ^ sw));
            short8 a1 = *(const short8*)(o2b + ((arow * 128 + 64 + lg * 16) ^ sw));
            f32x4 acc = {0.f, 0.f, 0.f, 0.f};
            acc = __builtin_amdgcn_mfma_f32_16x16x32_bf16(a0, b0, acc, 0, 0, 0);
            acc = __builtin_amdgcn_mfma_f32_16x16x32_bf16(a1, b1, acc, 0, 0, 0);
            int rb = rt * 16 + lg * 4;
            #pragma unroll
            for (int r = 0; r < 4; ++r) {
                int row = rb + r;
                if (row < 66) {
                    int ss = (row >= 33) ? 1 : 0;
                    int m = row - ss * 33;
                    float zev = bf2f(*(const unsigned short*)(zg + row * 64 + col));
                    float rv = msk[ss * 36 + m] * (zev + fmaxf(acc[r] + bias, 0.f));
                    if (ss) ps1 += rv; else ps0 += rv;
                }
            }
        }
        ps0 += __shfl_xor(ps0, 16); ps0 += __shfl_xor(ps0, 32);
        ps1 += __shfl_xor(ps1, 16); ps1 += __shfl_xor(ps1, 32);
        if (lg == 0) {
            pooled[col] = ps0 * (1.0f / 33.0f);
            pooled[64 + col] = ps1 * (1.0f / 33.0f);
        }
    }
    __syncthreads();

    // ---- P5: zin = relu(zin_x + pool_w[:,290:] @ pooled + b) ----
    {
        int s = tid >> 7, r = tid & 127;
        float acc = pool_b[r] + zin_x_ws[(size_t)(gs0 + s) * 128 + r];
        const float* wrow = pool_w + (size_t)r * 354 + 290;
        const float* pl = pooled + s * 64;
        #pragma unroll 8
        for (int e = 0; e < 64; ++e) acc = fmaf(wrow[e], pl[e], acc);
        zin[(size_t)(gs0 + s) * 128 + r] = fmaxf(acc, 0.f);
    }
}

// ---------------------------------------------------------------------------
// Kernel: LSTM scan (unchanged)
// ---------------------------------------------------------------------------
__global__ __launch_bounds__(512) void k_lstm(
    const float* __restrict__ zin, const float* __restrict__ w_ih,
    const float* __restrict__ w_hh, const float* __restrict__ b_ih,
    const float* __restrict__ b_hh, const int* __restrict__ done,
    float* __restrict__ h_all)
{
    extern __shared__ float lds[];
    float* xp = lds;
    float* zl = xp + 64 * 512;
    float* hl = zl + 128;
    float* gl = hl + 128;
    const int s = blockIdx.x;
    const int r = threadIdx.x;
    const int b = s >> 3;

    float4 w[32];
    {
        const float4* wsrc = (const float4*)(w_ih + (size_t)r * 128);
        #pragma unroll
        for (int j = 0; j < 32; ++j) w[j] = wsrc[j];
    }
    const float bias = b_ih[r] + b_hh[r];

    for (int t = 0; t < T_DIM; ++t) {
        __syncthreads();
        if (r < 128) zl[r] = zin[((size_t)t * BA + s) * 128 + r];
        __syncthreads();
        const float4* x4 = (const float4*)zl;
        float a0 = 0.f, a1 = 0.f, a2 = 0.f, a3 = 0.f;
        #pragma unroll
        for (int j = 0; j < 32; ++j) {
            float4 wa = w[j], xa = x4[j];
            a0 = fmaf(wa.x, xa.x, a0);
            a1 = fmaf(wa.y, xa.y, a1);
            a2 = fmaf(wa.z, xa.z, a2);
            a3 = fmaf(wa.w, xa.w, a3);
        }
        xp[t * 512 + r] = bias + ((a0 + a1) + (a2 + a3));
    }

    {
        const float4* wsrc = (const float4*)(w_hh + (size_t)r * 128);
        #pragma unroll
        for (int j = 0; j < 32; ++j) w[j] = wsrc[j];
    }
    if (r < 128) hl[r] = 0.0f;
    float c = 0.0f;
    __syncthreads();

    for (int t = 0; t < T_DIM; ++t) {
        const float4* h4 = (const float4*)hl;
        float a0 = 0.f, a1 = 0.f, a2 = 0.f, a3 = 0.f;
        #pragma unroll
        for (int j = 0; j < 32; ++j) {
            float4 wa = w[j], xa = h4[j];
            a0 = fmaf(wa.x, xa.x, a0);
            a1 = fmaf(wa.y, xa.y, a1);
            a2 = fmaf(wa.z, xa.z, a2);
            a3 = fmaf(wa.w, xa.w, a3);
        }
        gl[r] = xp[t * 512 + r] + ((a0 + a1) + (a2 + a3));
        __syncthreads();
        if (r < 128) {
            float keep = done[t * B_DIM + b] ? 0.0f : 1.0f;
            float gi = gl[r], gf = gl[r + 128], gg = gl[r + 256], go = gl[r + 384];
            c *= keep;
            c = sigf(gf) * c + sigf(gi) * tanhf(gg);
            float hn = sigf(go) * tanhf(c);
            float keepn = (t < T_DIM - 1) ? (done[(t + 1) * B_DIM + b] ? 0.0f : 1.0f) : 1.0f;
            hl[r] = hn * keepn;
            h_all[((size_t)t * BA + s) * 128 + r] = hn;
        }
        __syncthreads();
    }
}

// ---------------------------------------------------------------------------
// Kernel: categorical heads (unchanged)
// ---------------------------------------------------------------------------
__global__ __launch_bounds__(256) void k_heads(
    const float* __restrict__ h_all, const int* __restrict__ actions,
    const float* __restrict__ h0w, const float* __restrict__ h0b,
    const float* __restrict__ h1w, const float* __restrict__ h1b,
    float* __restrict__ out)
{
    __shared__ float w0[640], w1[640], b0[8], b1[8];
    const int tid = threadIdx.x;
    for (int i = tid; i < 640; i += 256) { w0[i] = h0w[i]; w1[i] = h1w[i]; }
    if (tid < 5) { b0[tid] = h0b[tid]; b1[tid] = h1b[tid]; }
    __syncthreads();
    const int g = blockIdx.x * 256 + tid;
    const float* h = h_all + (size_t)g * 128;
    float l0[5], l1[5];
    #pragma unroll
    for (int cc = 0; cc < 5; ++cc) { l0[cc] = b0[cc]; l1[cc] = b1[cc]; }
    for (int j = 0; j < 128; ++j) {
        float hv = h[j];
        #pragma unroll
        for (int cc = 0; cc < 5; ++cc) {
            l0[cc] = fmaf(w0[cc * 128 + j], hv, l0[cc]);
            l1[cc] = fmaf(w1[cc * 128 + j], hv, l1[cc]);
        }
    }
    int a0 = actions[(size_t)g * 2], a1 = actions[(size_t)g * 2 + 1];
    float m0 = l0[0], m1 = l1[0];
    #pragma unroll
    for (int cc = 1; cc < 5; ++cc) { m0 = fmaxf(m0, l0[cc]); m1 = fmaxf(m1, l1[cc]); }
    float s0 = 0.f, s1 = 0.f;
    #pragma unroll
    for (int cc = 0; cc < 5; ++cc) { s0 += expf(l0[cc] - m0); s1 += expf(l1[cc] - m1); }
    float lse0 = m0 + logf(s0), lse1 = m1 + logf(s1);
    float ent0 = 0.f, ent1 = 0.f, lp0 = 0.f, lp1 = 0.f;
    #pragma unroll
    for (int cc = 0; cc < 5; ++cc) {
        float p0 = l0[cc] - lse0, p1 = l1[cc] - lse1;
        ent0 -= expf(p0) * p0;
        ent1 -= expf(p1) * p1;
        if (cc == a0) lp0 = p0;
        if (cc == a1) lp1 = p1;
    }
    out[ACT_OFF + (size_t)g * 2]     = (float)a0;
    out[ACT_OFF + (size_t)g * 2 + 1] = (float)a1;
    out[LP_OFF + g]                  = lp0 * lp1;
    out[ENT_OFF + (size_t)g * 2]     = ent0;
    out[ENT_OFF + (size_t)g * 2 + 1] = ent1;
}

extern "C" void kernel_launch(void* const* d_in, const int* in_sizes, int n_in,
                              void* d_out, int out_size, void* d_ws, size_t ws_size,
                              hipStream_t stream)
{
    const float* x_agent = (const float*)d_in[0];
    const float* x_lidar = (const float*)d_in[1];
    const float* x_safe  = (const float*)d_in[2];
    const float* x_ent0  = (const float*)d_in[3];
    const float* x_ent1  = (const float*)d_in[4];
    const int*   mask0   = (const int*)d_in[5];
    const int*   mask1   = (const int*)d_in[6];
    const int*   done    = (const int*)d_in[7];
    const int*   actions = (const int*)d_in[8];
    const float* conv_w  = (const float*)d_in[9];
    const float* conv_b  = (const float*)d_in[10];
    const float* self_w  = (const float*)d_in[11];
    const float* self_b  = (const float*)d_in[12];
    const float* ent0_w  = (const float*)d_in[13];
    const float* ent0_b  = (const float*)d_in[14];
    const float* ent1_w  = (const float*)d_in[15];
    const float* ent1_b  = (const float*)d_in[16];
    const float* inp_w   = (const float*)d_in[17];
    const float* inp_b   = (const float*)d_in[18];
    const float* outp_w  = (const float*)d_in[19];
    const float* outp_b  = (const float*)d_in[20];
    const float* sa_w    = (const float*)d_in[21];
    const float* sa_b    = (const float*)d_in[22];
    const float* pool_w  = (const float*)d_in[23];
    const float* pool_b  = (const float*)d_in[24];
    const float* w_ih    = (const float*)d_in[25];
    const float* w_hh    = (const float*)d_in[26];
    const float* b_ih    = (const float*)d_in[27];
    const float* b_hh    = (const float*)d_in[28];
    const float* h0w     = (const float*)d_in[29];
    const float* h0b     = (const float*)d_in[30];
    const float* h1w     = (const float*)d_in[31];
    const float* h1b     = (const float*)d_in[32];

    __hip_bfloat16* z_ent = (__hip_bfloat16*)d_ws;
    float* zin_x = (float*)((char*)d_ws + (size_t)S_TOT * 2112 * 2);
    float* zin   = zin_x + (size_t)S_TOT * 128;
    float* h_all = zin + (size_t)S_TOT * 128;
    short* wqkvb = (short*)(h_all + (size_t)S_TOT * 128);
    short* wob   = wqkvb + 12288;
    short* wsb   = wob + 4096;
    short* Wf    = wsb + 4096;
    short* We0   = Wf + 102400;
    short* We1   = We0 + 1024;

    k_cvt2<<<400, 256, 0, stream>>>(inp_w, outp_w, sa_w, self_w, pool_w, ent0_w, ent1_w,
                                    wqkvb, wob, wsb, Wf, We0, We1);

    k_frontM<<<256, 256, FM_TOTAL, stream>>>(
        x_agent, x_lidar, x_safe, x_ent0, x_ent1,
        conv_w, conv_b, self_b, ent0_b, ent1_b,
        Wf, We0, We1, z_ent, zin_x);

    k_attnF<<<S_TOT / 2, 256, AT_TOTAL, stream>>>(
        z_ent, zin_x, mask0, mask1, wqkvb, inp_b, wob, outp_b,
        wsb, sa_b, pool_w, pool_b, zin);

    size_t lstm_lds = (size_t)(64 * 512 + 128 + 128 + 512) * sizeof(float);
    k_lstm<<<BA, 512, lstm_lds, stream>>>(zin, w_ih, w_hh, b_ih, b_hh, done, h_all);

    k_heads<<<S_TOT / 256, 256, 0, stream>>>(h_all, actions, h0w, h0b, h1w, h1b, (float*)d_out);
}

// Round 9
// 436.265 us; speedup vs baseline: 13.9615x; 1.0137x over previous
//
#include <hip/hip_runtime.h>
#include <hip/hip_bf16.h>
#include <math.h>

#define T_DIM 64
#define B_DIM 32
#define N_ENT 16
#define M_SLOTS 33
#define S_TOT 16384
#define BA 256
#define FN_SB 32

#define ACT_OFF 0
#define LP_OFF 32768
#define ENT_OFF 49152

typedef __attribute__((ext_vector_type(8))) short short8;
typedef __attribute__((ext_vector_type(4))) float f32x4;
typedef unsigned int uint32;

__device__ __forceinline__ float sigf(float x) { return 1.0f / (1.0f + expf(-x)); }
__device__ __forceinline__ float bf2f(unsigned short u) {
    union { unsigned int i; float f; } a; a.i = ((unsigned int)u) << 16; return a.f;
}
__device__ __forceinline__ uint32 pkbf(float a, float b) {
    __hip_bfloat16 ha = __float2bfloat16(a), hb = __float2bfloat16(b);
    return (uint32)(*(unsigned short*)&ha) | ((uint32)(*(unsigned short*)&hb) << 16);
}
__device__ __forceinline__ short f2bs(float v) {
    __hip_bfloat16 h = __float2bfloat16(v); return *(short*)&h;
}
__device__ __forceinline__ int pswz(int row) { return (((row & 3) ^ ((row >> 2) & 3)) << 4); }

// ---------------------------------------------------------------------------
// k_cvt2: pack all MFMA weights to bf16 in ws (unchanged).
// ---------------------------------------------------------------------------
__global__ __launch_bounds__(256) void k_cvt2(
    const float* __restrict__ inp_w, const float* __restrict__ outp_w,
    const float* __restrict__ sa_w, const float* __restrict__ self_w,
    const float* __restrict__ pool_w, const float* __restrict__ ent0_w,
    const float* __restrict__ ent1_w,
    short* __restrict__ wq, short* __restrict__ wo, short* __restrict__ ws,
    short* __restrict__ Wf, short* __restrict__ We0, short* __restrict__ We1)
{
    int i = blockIdx.x * 256 + threadIdx.x;
    if (i < 12288) wq[i] = f2bs(inp_w[i]);
    if (i < 4096) { wo[i] = f2bs(outp_w[i]); ws[i] = f2bs(sa_w[i]); }
    if (i < 1024) {
        int e = i >> 4, k = i & 15;
        We0[i] = f2bs(k < 12 ? ent0_w[e * 302 + k] : 0.f);
        We1[i] = f2bs(k < 8 ? ent1_w[e * 298 + k] : 0.f);
    }
    if (i < 102400) {
        int c = i / 320, k = i - c * 320;
        float v = 0.f;
        if (k < 290) {
            if (c < 64) v = self_w[c * 580 + k] + self_w[c * 580 + 290 + k];
            else if (c < 192) v = pool_w[(size_t)(c - 64) * 354 + k];
            else if (c < 256) v = ent0_w[(c - 192) * 302 + 12 + k];
            else v = ent1_w[(c - 256) * 298 + 8 + k];
        }
        Wf[i] = f2bs(v);
    }
}

// ---------------------------------------------------------------------------
// k_frontN: MFMA front end, 32 samples/block, grid 512, 37.9 KB LDS.
// Entity A-tile (ae, [256][32] bf16) aliases the dead xsb region (2 chunks);
// lidf aliases xp0f region.
// ---------------------------------------------------------------------------
#define FN_XSB 0
#define FN_XP0 20480
#define FN_XP1 29184
#define FN_TOTAL 37888

__global__ __launch_bounds__(256, 4) void k_frontN(
    const float* __restrict__ xag, const float* __restrict__ xlid,
    const float* __restrict__ xsz, const float* __restrict__ xe0,
    const float* __restrict__ xe1,
    const float* __restrict__ conv_w, const float* __restrict__ conv_b,
    const float* __restrict__ self_b, const float* __restrict__ ent0_b,
    const float* __restrict__ ent1_b,
    const short* __restrict__ Wf, const short* __restrict__ We0,
    const short* __restrict__ We1,
    __hip_bfloat16* __restrict__ z_ent, float* __restrict__ zin_x)
{
    extern __shared__ char smem[];
    char* xsb = smem + FN_XSB;               // bf16 [32][320] swz8
    float* xp0f = (float*)(smem + FN_XP0);   // f32 [32][68]
    float* xp1f = (float*)(smem + FN_XP1);   // f32 [32][68]
    char* ae = smem + FN_XSB;                // bf16 [256][32] swz4, aliases xsb
    float* lidf = (float*)(smem + FN_XP0);   // f32 [32][34], aliases xp0f

    const int tid = threadIdx.x;
    const int s0 = blockIdx.x * FN_SB;
    const int wv = __builtin_amdgcn_readfirstlane(tid >> 6);
    const int l = tid & 63;
    const int lr = l & 15;
    const int lg = l >> 4;

    // ---- stage inputs ----
    for (int i = tid; i < FN_SB * 32; i += 256) {      // lidar -> lidf [32][34]
        int d = i & 31, sl = i >> 5;
        lidf[d * 34 + sl] = xlid[(size_t)s0 * 32 + i];
    }
    for (int i = tid; i < FN_SB * 16; i += 256) {
        int sl = i >> 4, d = i & 15;
        *(short*)(xsb + ((sl * 640 + d * 2) ^ ((sl & 7) << 4))) = f2bs(xag[(size_t)s0 * 16 + i]);
    }
    for (int i = tid; i < FN_SB * 4; i += 256) {
        int sl = i >> 2, d = i & 3;
        *(short*)(xsb + ((sl * 640 + (286 + d) * 2) ^ ((sl & 7) << 4))) = f2bs(xsz[(size_t)s0 * 4 + i]);
    }
    for (int i = tid; i < FN_SB * 30; i += 256) {      // K pad 290..319 = 0
        int sl = i / 30, d = 290 + (i - (i / 30) * 30);
        *(short*)(xsb + ((sl * 640 + d * 2) ^ ((sl & 7) << 4))) = 0;
    }
    __syncthreads();
    // ---- conv -> xsb[sl][16+cp] ----
    for (int i = tid; i < 270 * FN_SB; i += 256) {
        int cp = i >> 5, sl = i & 31;
        int c = cp / 30, p = cp - c * 30;
        float v = conv_b[c] + conv_w[c * 3] * lidf[p * 34 + sl]
                + conv_w[c * 3 + 1] * lidf[(p + 1) * 34 + sl]
                + conv_w[c * 3 + 2] * lidf[(p + 2) * 34 + sl];
        *(short*)(xsb + ((sl * 640 + (16 + cp) * 2) ^ ((sl & 7) << 4))) = f2bs(fmaxf(v, 0.f));
    }
    __syncthreads();

    // ---- Phase 1 GEMM: [32 x 320] @ Wf^T; acc[rt 0..1][c 0..4] ----
    f32x4 acc[2][5];
    #pragma unroll
    for (int rt = 0; rt < 2; ++rt)
        #pragma unroll
        for (int c = 0; c < 5; ++c) acc[rt][c] = (f32x4){0.f, 0.f, 0.f, 0.f};

    for (int kk = 0; kk < 10; ++kk) {
        short8 af[2];
        #pragma unroll
        for (int rt = 0; rt < 2; ++rt) {
            int row = rt * 16 + lr;
            af[rt] = *(const short8*)(xsb + ((row * 640 + kk * 64 + lg * 16) ^ ((row & 7) << 4)));
        }
        short8 bf[5];
        #pragma unroll
        for (int c = 0; c < 5; ++c) {
            int col = (wv * 5 + c) * 16 + lr;
            bf[c] = *(const short8*)(Wf + (size_t)col * 320 + kk * 32 + lg * 8);
        }
        #pragma unroll
        for (int rt = 0; rt < 2; ++rt)
            #pragma unroll
            for (int c = 0; c < 5; ++c)
                acc[rt][c] = __builtin_amdgcn_mfma_f32_16x16x32_bf16(af[rt], bf[c], acc[rt][c], 0, 0, 0);
    }

    // ---- Phase 1 epilogue (all 32 rows valid) ----
    #pragma unroll
    for (int rt = 0; rt < 2; ++rt) {
        #pragma unroll
        for (int c = 0; c < 5; ++c) {
            int ct = wv * 5 + c;
            int gc = ct * 16 + lr;
            int rowb = rt * 16 + lg * 4;
            f32x4 a = acc[rt][c];
            if (ct * 16 < 64) {
                float bias = self_b[gc];
                #pragma unroll
                for (int r = 0; r < 4; ++r)
                    z_ent[(size_t)(s0 + rowb + r) * 2112 + gc] = __float2bfloat16(fmaxf(a[r] + bias, 0.f));
            } else if (ct * 16 < 192) {
                int r2 = gc - 64;
                #pragma unroll
                for (int r = 0; r < 4; ++r)
                    zin_x[(size_t)(s0 + rowb + r) * 128 + r2] = a[r];
            } else if (ct * 16 < 256) {
                float bias = ent0_b[gc - 192];
                #pragma unroll
                for (int r = 0; r < 4; ++r)
                    xp0f[(rowb + r) * 68 + (gc - 192)] = a[r] + bias;
            } else {
                float bias = ent1_b[gc - 256];
                #pragma unroll
                for (int r = 0; r < 4; ++r)
                    xp1f[(rowb + r) * 68 + (gc - 256)] = a[r] + bias;
            }
        }
    }
    __syncthreads();   // xsb reads done -> ae may alias it

    // ---- ent0 MLP: 2 chunks of 16 samples (256 rows) ----
    {
        short8 bz = {0, 0, 0, 0, 0, 0, 0, 0};
        short8 be[4];
        #pragma unroll
        for (int ct = 0; ct < 4; ++ct) {
            int col = ct * 16 + lr;
            short8 bv = *(const short8*)(We0 + col * 16 + (lg & 1) * 8);
            be[ct] = (lg < 2) ? bv : bz;
        }
        for (int cc = 0; cc < 2; ++cc) {
            for (int i = tid; i < 4096; i += 256) ((uint32*)ae)[i] = 0;
            __syncthreads();
            for (int i = tid; i < 16 * 192; i += 256) {
                int sl = i / 192, r = i - sl * 192;
                int n = r / 12, d = r - n * 12;
                int lrow = sl * 16 + n;
                *(short*)(ae + ((lrow * 64 + d * 2) ^ ((lrow & 3) << 4))) =
                    f2bs(xe0[(size_t)(s0 + cc * 16) * 192 + i]);
            }
            __syncthreads();
            #pragma unroll
            for (int j = 0; j < 4; ++j) {
                int rtl = wv * 4 + j;          // local sample 0..15
                int row = rtl * 16 + lr;
                short8 af = *(const short8*)(ae + ((row * 64 + lg * 16) ^ ((row & 3) << 4)));
                int gs = cc * 16 + rtl;
                #pragma unroll
                for (int ct = 0; ct < 4; ++ct) {
                    f32x4 a2 = {0.f, 0.f, 0.f, 0.f};
                    a2 = __builtin_amdgcn_mfma_f32_16x16x32_bf16(af, be[ct], a2, 0, 0, 0);
                    int e = ct * 16 + lr;
                    float xpv = xp0f[gs * 68 + e];
                    #pragma unroll
                    for (int r = 0; r < 4; ++r) {
                        int n = lg * 4 + r;
                        z_ent[(size_t)(s0 + gs) * 2112 + (1 + n) * 64 + e] =
                            __float2bfloat16(fmaxf(a2[r] + xpv, 0.f));
                    }
                }
            }
            __syncthreads();
        }
    }

    // ---- ent1 MLP: 2 chunks ----
    {
        short8 bz = {0, 0, 0, 0, 0, 0, 0, 0};
        short8 be[4];
        #pragma unroll
        for (int ct = 0; ct < 4; ++ct) {
            int col = ct * 16 + lr;
            short8 bv = *(const short8*)(We1 + col * 16 + (lg & 1) * 8);
            be[ct] = (lg < 2) ? bv : bz;
        }
        for (int cc = 0; cc < 2; ++cc) {
            for (int i = tid; i < 4096; i += 256) ((uint32*)ae)[i] = 0;
            __syncthreads();
            for (int i = tid; i < 16 * 128; i += 256) {
                int sl = i >> 7, r = i & 127;
                int n = r >> 3, d = r & 7;
                int lrow = sl * 16 + n;
                *(short*)(ae + ((lrow * 64 + d * 2) ^ ((lrow & 3) << 4))) =
                    f2bs(xe1[(size_t)(s0 + cc * 16) * 128 + i]);
            }
            __syncthreads();
            #pragma unroll
            for (int j = 0; j < 4; ++j) {
                int rtl = wv * 4 + j;
                int row = rtl * 16 + lr;
                short8 af = *(const short8*)(ae + ((row * 64 + lg * 16) ^ ((row & 3) << 4)));
                int gs = cc * 16 + rtl;
                #pragma unroll
                for (int ct = 0; ct < 4; ++ct) {
                    f32x4 a2 = {0.f, 0.f, 0.f, 0.f};
                    a2 = __builtin_amdgcn_mfma_f32_16x16x32_bf16(af, be[ct], a2, 0, 0, 0);
                    int e = ct * 16 + lr;
                    float xpv = xp1f[gs * 68 + e];
                    #pragma unroll
                    for (int r = 0; r < 4; ++r) {
                        int n = lg * 4 + r;
                        z_ent[(size_t)(s0 + gs) * 2112 + (17 + n) * 64 + e] =
                            __float2bfloat16(fmaxf(a2[r] + xpv, 0.f));
                    }
                }
            }
            __syncthreads();
        }
    }
}

// ---------------------------------------------------------------------------
// k_attnG: full-MFMA attention, 1 sample/block, 21.9 KB LDS -> 7 blocks/CU.
// Wave wv owns head wv. ob aliases Qb, o2b aliases Kb (phase-split barriers).
// ---------------------------------------------------------------------------
#define AG_QB   0
#define AG_KB   6144
#define AG_VT   12288
#define AG_PW   16384
#define AG_P32  20480
#define AG_V32  21248
#define AG_MSK  21504
#define AG_POOL 21664
#define AG_TOTAL 21920

__global__ __launch_bounds__(256, 6) void k_attnG(
    const __hip_bfloat16* __restrict__ z_ent, const float* __restrict__ zin_x_ws,
    const int* __restrict__ mask0, const int* __restrict__ mask1,
    const short* __restrict__ wqkvb, const float* __restrict__ inp_b,
    const short* __restrict__ wob_g, const float* __restrict__ outp_b,
    const short* __restrict__ wsb_g, const float* __restrict__ sa_b,
    const float* __restrict__ pool_w, const float* __restrict__ pool_b,
    float* __restrict__ zin)
{
    extern __shared__ char smem[];
    char*  Qb  = smem + AG_QB;            // bf16 [4 head][48 q][16 d]; later ob
    char*  Kb  = smem + AG_KB;            // bf16 [4 head][48 slot][16 d]; later o2b
    char*  Vt  = smem + AG_VT;            // bf16 [4 head][16 d][32 slot] swz
    char*  Pw  = smem + AG_PW;            // bf16 [4 wave][16 row][32 slot] swz
    float* P32 = (float*)(smem + AG_P32); // f32 [4 head][48]
    float* V32 = (float*)(smem + AG_V32); // f32 [4 head][16]
    float* msk = (float*)(smem + AG_MSK); // f32 [36]
    float* pooled = (float*)(smem + AG_POOL);
    char*  ob  = Qb;                      // alias (after P2a barrier)
    char*  o2b = Kb;                      // alias (after P2b barrier)

    const int tid = threadIdx.x;
    const int s = blockIdx.x;
    const short* zg = (const short*)(z_ent + (size_t)s * 2112);  // [33 rows][64]

    // ---- P0: mask ----
    if (tid < 16) msk[1 + tid] = (float)mask0[(size_t)s * 16 + tid];
    else if (tid < 32) msk[17 + (tid - 16)] = (float)mask1[(size_t)s * 16 + (tid - 16)];
    else if (tid == 32) msk[0] = 1.0f;
    __syncthreads();

    const int wv = __builtin_amdgcn_readfirstlane(tid >> 6);
    const int l  = tid & 63;
    const int lr = l & 15;
    const int lg = l >> 4;

    // ---- P1: in_proj GEMM (A from global) -> Qb / Kb / Vt / V32 ----
    {
        short8 bw[3][2]; float bias[3];
        #pragma unroll
        for (int c = 0; c < 3; ++c) {
            int col = (wv * 3 + c) * 16 + lr;
            bw[c][0] = *(const short8*)(wqkvb + col * 64 + lg * 8);
            bw[c][1] = *(const short8*)(wqkvb + col * 64 + 32 + lg * 8);
            bias[c] = inp_b[col];
        }
        for (int rt = 0; rt < 3; ++rt) {
            int arow = rt * 16 + lr;   // rows 33..47 read trailing data: row-contained garbage
            short8 a0 = *(const short8*)(zg + arow * 64 + lg * 8);
            short8 a1 = *(const short8*)(zg + arow * 64 + 32 + lg * 8);
            #pragma unroll
            for (int c = 0; c < 3; ++c) {
                f32x4 acc = {0.f, 0.f, 0.f, 0.f};
                acc = __builtin_amdgcn_mfma_f32_16x16x32_bf16(a0, bw[c][0], acc, 0, 0, 0);
                acc = __builtin_amdgcn_mfma_f32_16x16x32_bf16(a1, bw[c][1], acc, 0, 0, 0);
                int col = (wv * 3 + c) * 16 + lr;
                int rb = rt * 16 + lg * 4;
                #pragma unroll
                for (int r = 0; r < 4; ++r) {
                    int q = rb + r;
                    if (q < 33) {
                        float val = acc[r] + bias[c];
                        if (col < 64) {
                            int h = col >> 4, d = col & 15;
                            *(short*)(Qb + ((h * 48 + q) * 32) + d * 2) = f2bs(val);
                        } else if (col < 128) {
                            int kc = col - 64; int h = kc >> 4, d = kc & 15;
                            *(short*)(Kb + ((h * 48 + q) * 32) + d * 2) = f2bs(val);
                        } else {
                            int vc = col - 128; int h = vc >> 4, d = vc & 15;
                            if (q < 32)
                                *(short*)(Vt + (h * 16 + d) * 64 + ((q * 2) ^ pswz(d))) = f2bs(val);
                            else
                                V32[h * 16 + d] = val;
                        }
                    }
                }
            }
        }
    }
    __syncthreads();

    // ---- P2a: QK MFMA + softmax (wave = head wv); P packed in regs ----
    uint32 pk[3][4];
    {
        const short8 zero8 = {0, 0, 0, 0, 0, 0, 0, 0};
        short8 kf[3];
        #pragma unroll
        for (int t = 0; t < 3; ++t)
            kf[t] = (lg < 2) ? *(const short8*)(Kb + ((wv * 48 + t * 16 + lr) * 32) + lg * 16) : zero8;
        float mk0 = msk[lr];
        float mk1 = msk[16 + lr];
        float mk2 = (lr == 0) ? msk[32] : 0.f;
        #pragma unroll
        for (int qt = 0; qt < 3; ++qt) {
            short8 qf = (lg < 2) ? *(const short8*)(Qb + ((wv * 48 + qt * 16 + lr) * 32) + lg * 16) : zero8;
            f32x4 z = {0.f, 0.f, 0.f, 0.f};
            f32x4 S0 = __builtin_amdgcn_mfma_f32_16x16x32_bf16(qf, kf[0], z, 0, 0, 0);
            f32x4 S1 = __builtin_amdgcn_mfma_f32_16x16x32_bf16(qf, kf[1], z, 0, 0, 0);
            f32x4 S2 = __builtin_amdgcn_mfma_f32_16x16x32_bf16(qf, kf[2], z, 0, 0, 0);
            #pragma unroll
            for (int r = 0; r < 4; ++r) {
                float v0 = (mk0 > 0.f) ? S0[r] * 0.25f : -1e9f;
                float v1 = (mk1 > 0.f) ? S1[r] * 0.25f : -1e9f;
                float v2 = (mk2 > 0.f) ? S2[r] * 0.25f : -1e9f;
                float m = fmaxf(fmaxf(v0, v1), v2);
                m = fmaxf(m, __shfl_xor(m, 1));
                m = fmaxf(m, __shfl_xor(m, 2));
                m = fmaxf(m, __shfl_xor(m, 4));
                m = fmaxf(m, __shfl_xor(m, 8));
                float e0 = __expf(v0 - m), e1 = __expf(v1 - m), e2 = __expf(v2 - m);
                float sm = e0 + e1 + e2;
                sm += __shfl_xor(sm, 1);
                sm += __shfl_xor(sm, 2);
                sm += __shfl_xor(sm, 4);
                sm += __shfl_xor(sm, 8);
                float inv = 1.0f / sm;
                pk[qt][r] = pkbf(e0 * inv, e1 * inv);
                if (lr == 0) P32[wv * 48 + qt * 16 + lg * 4 + r] = e2 * inv;
            }
        }
    }
    __syncthreads();   // all Qb/Kb reads done; ob may overwrite Qb

    // ---- P2b: PV MFMA via per-wave Pw tile; write ob (aliases Qb) ----
    {
        short8 vf = *(const short8*)(Vt + (wv * 16 + lr) * 64 + ((lg * 16) ^ pswz(lr)));
        float v32reg = V32[wv * 16 + lr];
        f32x4 C[3];
        #pragma unroll
        for (int qt = 0; qt < 3; ++qt) {
            #pragma unroll
            for (int r = 0; r < 4; ++r) {
                int ql = lg * 4 + r;
                uint32 p = pk[qt][r];
                char* prow = Pw + wv * 1024 + ql * 64;
                int sz = pswz(ql);
                *(short*)(prow + ((lr * 2) ^ sz)) = (short)(p & 0xffffu);
                *(short*)(prow + (((16 + lr) * 2) ^ sz)) = (short)(p >> 16);
            }
            short8 pf = *(const short8*)(Pw + wv * 1024 + lr * 64 + ((lg * 16) ^ pswz(lr)));
            f32x4 z = {0.f, 0.f, 0.f, 0.f};
            C[qt] = __builtin_amdgcn_mfma_f32_16x16x32_bf16(pf, vf, z, 0, 0, 0);
        }
        #pragma unroll
        for (int qt = 0; qt < 3; ++qt) {
            #pragma unroll
            for (int r = 0; r < 4; ++r) {
                int q = qt * 16 + lg * 4 + r;
                if (q <= 32) {
                    float cv = C[qt][r] + P32[wv * 48 + q] * v32reg;
                    *(short*)(ob + ((q * 128 + (wv * 16 + lr) * 2) ^ ((q & 7) << 4))) = f2bs(cv);
                }
            }
        }
    }
    __syncthreads();

    // ---- P3: out_proj GEMM: ob -> o2b (aliases Kb) ----
    {
        int col = wv * 16 + lr;
        short8 b0 = *(const short8*)(wob_g + col * 64 + lg * 8);
        short8 b1 = *(const short8*)(wob_g + col * 64 + 32 + lg * 8);
        float bias = outp_b[col];
        for (int rt = 0; rt < 3; ++rt) {
            int arow = rt * 16 + lr;
            int sw = (arow & 7) << 4;
            short8 a0 = *(const short8*)(ob + ((arow * 128 + lg * 16) ^ sw));
            short8 a1 = *(const short8*)(ob + ((arow * 128 + 64 + lg * 16) ^ sw));
            f32x4 acc = {0.f, 0.f, 0.f, 0.f};
            acc = __builtin_amdgcn_mfma_f32_16x16x32_bf16(a0, b0, acc, 0, 0, 0);
            acc = __builtin_amdgcn_mfma_f32_16x16x32_bf16(a1, b1, acc, 0, 0, 0);
            int rb = rt * 16 + lg * 4;
            #pragma unroll
            for (int r = 0; r < 4; ++r) {
                int row = rb + r;
                if (row < 33)
                    *(short*)(o2b + ((row * 128 + col * 2) ^ ((row & 7) << 4))) = f2bs(acc[r] + bias);
            }
        }
    }
    __syncthreads();

    // ---- P4: sa GEMM + residual (z_ent global) + mask; pool fused via shfl ----
    {
        int col = wv * 16 + lr;
        short8 b0 = *(const short8*)(wsb_g + col * 64 + lg * 8);
        short8 b1 = *(const short8*)(wsb_g + col * 64 + 32 + lg * 8);
        float bias = sa_b[col];
        float ps = 0.f;
        for (int rt = 0; rt < 3; ++rt) {
            int arow = rt * 16 + lr;
            int sw = (arow & 7) << 4;
            short8 a0 = *(const short8*)(o2b + ((arow * 128 + lg * 16) ^ sw));
            short8 a1 = *(const short8*)(o2b + ((arow * 128 + 64 + lg * 16) ^ sw));
            f32x4 acc = {0.f, 0.f, 0.f, 0.f};
            acc = __builtin_amdgcn_mfma_f32_16x16x32_bf16(a0, b0, acc, 0, 0, 0);
            acc = __builtin_amdgcn_mfma_f32_16x16x32_bf16(a1, b1, acc, 0, 0, 0);
            int rb = rt * 16 + lg * 4;
            #pragma unroll
            for (int r = 0; r < 4; ++r) {
                int row = rb + r;
                if (row < 33) {
                    float zev = bf2f(*(const unsigned short*)(zg + row * 64 + col));
                    ps += msk[row] * (zev + fmaxf(acc[r] + bias, 0.f));
                }
            }
        }
        ps += __shfl_xor(ps, 16); ps += __shfl_xor(ps, 32);
        if (lg == 0) pooled[col] = ps * (1.0f / 33.0f);
    }
    __syncthreads();

    // ---- P5: zin = relu(zin_x + pool_w[:,290:] @ pooled + b) ----
    if (tid < 128) {
        int r = tid;
        float acc = pool_b[r] + zin_x_ws[(size_t)s * 128 + r];
        const float* wrow = pool_w + (size_t)r * 354 + 290;
        #pragma unroll 8
        for (int e = 0; e < 64; ++e) acc = fmaf(wrow[e], pooled[e], acc);
        zin[(size_t)s * 128 + r] = fmaxf(acc, 0.f);
    }
}

// ---------------------------------------------------------------------------
// Kernel: LSTM scan (unchanged)
// ---------------------------------------------------------------------------
__global__ __launch_bounds__(512) void k_lstm(
    const float* __restrict__ zin, const float* __restrict__ w_ih,
    const float* __restrict__ w_hh, const float* __restrict__ b_ih,
    const float* __restrict__ b_hh, const int* __restrict__ done,
    float* __restrict__ h_all)
{
    extern __shared__ float lds[];
    float* xp = lds;
    float* zl = xp + 64 * 512;
    float* hl = zl + 128;
    float* gl = hl + 128;
    const int s = blockIdx.x;
    const int r = threadIdx.x;
    const int b = s >> 3;

    float4 w[32];
    {
        const float4* wsrc = (const float4*)(w_ih + (size_t)r * 128);
        #pragma unroll
        for (int j = 0; j < 32; ++j) w[j] = wsrc[j];
    }
    const float bias = b_ih[r] + b_hh[r];

    for (int t = 0; t < T_DIM; ++t) {
        __syncthreads();
        if (r < 128) zl[r] = zin[((size_t)t * BA + s) * 128 + r];
        __syncthreads();
        const float4* x4 = (const float4*)zl;
        float a0 = 0.f, a1 = 0.f, a2 = 0.f, a3 = 0.f;
        #pragma unroll
        for (int j = 0; j < 32; ++j) {
            float4 wa = w[j], xa = x4[j];
            a0 = fmaf(wa.x, xa.x, a0);
            a1 = fmaf(wa.y, xa.y, a1);
            a2 = fmaf(wa.z, xa.z, a2);
            a3 = fmaf(wa.w, xa.w, a3);
        }
        xp[t * 512 + r] = bias + ((a0 + a1) + (a2 + a3));
    }

    {
        const float4* wsrc = (const float4*)(w_hh + (size_t)r * 128);
        #pragma unroll
        for (int j = 0; j < 32; ++j) w[j] = wsrc[j];
    }
    if (r < 128) hl[r] = 0.0f;
    float c = 0.0f;
    __syncthreads();

    for (int t = 0; t < T_DIM; ++t) {
        const float4* h4 = (const float4*)hl;
        float a0 = 0.f, a1 = 0.f, a2 = 0.f, a3 = 0.f;
        #pragma unroll
        for (int j = 0; j < 32; ++j) {
            float4 wa = w[j], xa = h4[j];
            a0 = fmaf(wa.x, xa.x, a0);
            a1 = fmaf(wa.y, xa.y, a1);
            a2 = fmaf(wa.z, xa.z, a2);
            a3 = fmaf(wa.w, xa.w, a3);
        }
        gl[r] = xp[t * 512 + r] + ((a0 + a1) + (a2 + a3));
        __syncthreads();
        if (r < 128) {
            float keep = done[t * B_DIM + b] ? 0.0f : 1.0f;
            float gi = gl[r], gf = gl[r + 128], gg = gl[r + 256], go = gl[r + 384];
            c *= keep;
            c = sigf(gf) * c + sigf(gi) * tanhf(gg);
            float hn = sigf(go) * tanhf(c);
            float keepn = (t < T_DIM - 1) ? (done[(t + 1) * B_DIM + b] ? 0.0f : 1.0f) : 1.0f;
            hl[r] = hn * keepn;
            h_all[((size_t)t * BA + s) * 128 + r] = hn;
        }
        __syncthreads();
    }
}

// ---------------------------------------------------------------------------
// Kernel: categorical heads (unchanged)
// ---------------------------------------------------------------------------
__global__ __launch_bounds__(256) void k_heads(
    const float* __restrict__ h_all, const int* __restrict__ actions,
    const float* __restrict__ h0w, const float* __restrict__ h0b,
    const float* __restrict__ h1w, const float* __restrict__ h1b,
    float* __restrict__ out)
{
    __shared__ float w0[640], w1[640], b0[8], b1[8];
    const int tid = threadIdx.x;
    for (int i = tid; i < 640; i += 256) { w0[i] = h0w[i]; w1[i] = h1w[i]; }
    if (tid < 5) { b0[tid] = h0b[tid]; b1[tid] = h1b[tid]; }
    __syncthreads();
    const int g = blockIdx.x * 256 + tid;
    const float* h = h_all + (size_t)g * 128;
    float l0[5], l1[5];
    #pragma unroll
    for (int cc = 0; cc < 5; ++cc) { l0[cc] = b0[cc]; l1[cc] = b1[cc]; }
    for (int j = 0; j < 128; ++j) {
        float hv = h[j];
        #pragma unroll
        for (int cc = 0; cc < 5; ++cc) {
            l0[cc] = fmaf(w0[cc * 128 + j], hv, l0[cc]);
            l1[cc] = fmaf(w1[cc * 128 + j], hv, l1[cc]);
        }
    }
    int a0 = actions[(size_t)g * 2], a1 = actions[(size_t)g * 2 + 1];
    float m0 = l0[0], m1 = l1[0];
    #pragma unroll
    for (int cc = 1; cc < 5; ++cc) { m0 = fmaxf(m0, l0[cc]); m1 = fmaxf(m1, l1[cc]); }
    float s0 = 0.f, s1 = 0.f;
    #pragma unroll
    for (int cc = 0; cc < 5; ++cc) { s0 += expf(l0[cc] - m0); s1 += expf(l1[cc] - m1); }
    float lse0 = m0 + logf(s0), lse1 = m1 + logf(s1);
    float ent0 = 0.f, ent1 = 0.f, lp0 = 0.f, lp1 = 0.f;
    #pragma unroll
    for (int cc = 0; cc < 5; ++cc) {
        float p0 = l0[cc] - lse0, p1 = l1[cc] - lse1;
        ent0 -= expf(p0) * p0;
        ent1 -= expf(p1) * p1;
        if (cc == a0) lp0 = p0;
        if (cc == a1) lp1 = p1;
    }
    out[ACT_OFF + (size_t)g * 2]     = (float)a0;
    out[ACT_OFF + (size_t)g * 2 + 1] = (float)a1;
    out[LP_OFF + g]                  = lp0 * lp1;
    out[ENT_OFF + (size_t)g * 2]     = ent0;
    out[ENT_OFF + (size_t)g * 2 + 1] = ent1;
}

extern "C" void kernel_launch(void* const* d_in, const int* in_sizes, int n_in,
                              void* d_out, int out_size, void* d_ws, size_t ws_size,
                              hipStream_t stream)
{
    const float* x_agent = (const float*)d_in[0];
    const float* x_lidar = (const float*)d_in[1];
    const float* x_safe  = (const float*)d_in[2];
    const float* x_ent0  = (const float*)d_in[3];
    const float* x_ent1  = (const float*)d_in[4];
    const int*   mask0   = (const int*)d_in[5];
    const int*   mask1   = (const int*)d_in[6];
    const int*   done    = (const int*)d_in[7];
    const int*   actions = (const int*)d_in[8];
    const float* conv_w  = (const float*)d_in[9];
    const float* conv_b  = (const float*)d_in[10];
    const float* self_w  = (const float*)d_in[11];
    const float* self_b  = (const float*)d_in[12];
    const float* ent0_w  = (const float*)d_in[13];
    const float* ent0_b  = (const float*)d_in[14];
    const float* ent1_w  = (const float*)d_in[15];
    const float* ent1_b  = (const float*)d_in[16];
    const float* inp_w   = (const float*)d_in[17];
    const float* inp_b   = (const float*)d_in[18];
    const float* outp_w  = (const float*)d_in[19];
    const float* outp_b  = (const float*)d_in[20];
    const float* sa_w    = (const float*)d_in[21];
    const float* sa_b    = (const float*)d_in[22];
    const float* pool_w  = (const float*)d_in[23];
    const float* pool_b  = (const float*)d_in[24];
    const float* w_ih    = (const float*)d_in[25];
    const float* w_hh    = (const float*)d_in[26];
    const float* b_ih    = (const float*)d_in[27];
    const float* b_hh    = (const float*)d_in[28];
    const float* h0w     = (const float*)d_in[29];
    const float* h0b     = (const float*)d_in[30];
    const float* h1w     = (const float*)d_in[31];
    const float* h1b     = (const float*)d_in[32];

    __hip_bfloat16* z_ent = (__hip_bfloat16*)d_ws;
    float* zin_x = (float*)((char*)d_ws + (size_t)S_TOT * 2112 * 2);
    float* zin   = zin_x + (size_t)S_TOT * 128;
    float* h_all = zin + (size_t)S_TOT * 128;
    short* wqkvb = (short*)(h_all + (size_t)S_TOT * 128);
    short* wob   = wqkvb + 12288;
    short* wsb   = wob + 4096;
    short* Wf    = wsb + 4096;
    short* We0   = Wf + 102400;
    short* We1   = We0 + 1024;

    k_cvt2<<<400, 256, 0, stream>>>(inp_w, outp_w, sa_w, self_w, pool_w, ent0_w, ent1_w,
                                    wqkvb, wob, wsb, Wf, We0, We1);

    k_frontN<<<S_TOT / FN_SB, 256, FN_TOTAL, stream>>>(
        x_agent, x_lidar, x_safe, x_ent0, x_ent1,
        conv_w, conv_b, self_b, ent0_b, ent1_b,
        Wf, We0, We1, z_ent, zin_x);

    k_attnG<<<S_TOT, 256, AG_TOTAL, stream>>>(
        z_ent, zin_x, mask0, mask1, wqkvb, inp_b, wob, outp_b,
        wsb, sa_b, pool_w, pool_b, zin);

    size_t lstm_lds = (size_t)(64 * 512 + 128 + 128 + 512) * sizeof(float);
    k_lstm<<<BA, 512, lstm_lds, stream>>>(zin, w_ih, w_hh, b_ih, b_hh, done, h_all);

    k_heads<<<S_TOT / 256, 256, 0, stream>>>(h_all, actions, h0w, h0b, h1w, h1b, (float*)d_out);
}

// Round 10
// 419.696 us; speedup vs baseline: 14.5126x; 1.0395x over previous
//
#include <hip/hip_runtime.h>
#include <hip/hip_bf16.h>
#include <math.h>

#define T_DIM 64
#define B_DIM 32
#define N_ENT 16
#define M_SLOTS 33
#define S_TOT 16384
#define BA 256
#define FN_SB 16

#define ACT_OFF 0
#define LP_OFF 32768
#define ENT_OFF 49152

typedef __attribute__((ext_vector_type(8))) short short8;
typedef __attribute__((ext_vector_type(4))) float f32x4;
typedef unsigned int uint32;

__device__ __forceinline__ float sigf(float x) { return 1.0f / (1.0f + expf(-x)); }
__device__ __forceinline__ float bf2f(unsigned short u) {
    union { unsigned int i; float f; } a; a.i = ((unsigned int)u) << 16; return a.f;
}
__device__ __forceinline__ uint32 pkbf(float a, float b) {
    __hip_bfloat16 ha = __float2bfloat16(a), hb = __float2bfloat16(b);
    return (uint32)(*(unsigned short*)&ha) | ((uint32)(*(unsigned short*)&hb) << 16);
}
__device__ __forceinline__ short f2bs(float v) {
    __hip_bfloat16 h = __float2bfloat16(v); return *(short*)&h;
}
__device__ __forceinline__ int pswz(int row) { return (((row & 3) ^ ((row >> 2) & 3)) << 4); }

// ---------------------------------------------------------------------------
// k_cvt2: pack all MFMA weights to bf16 in ws.
// NEW: W_os = sa_w @ outp_w (bf16) and b_os = sa_w @ outp_b + sa_b (f32),
// fusing out_proj+sa into one GEMM (no nonlinearity between them).
// ---------------------------------------------------------------------------
__global__ __launch_bounds__(256) void k_cvt2(
    const float* __restrict__ inp_w, const float* __restrict__ outp_w,
    const float* __restrict__ outp_b, const float* __restrict__ sa_w,
    const float* __restrict__ sa_b, const float* __restrict__ self_w,
    const float* __restrict__ pool_w, const float* __restrict__ ent0_w,
    const float* __restrict__ ent1_w,
    short* __restrict__ wq, short* __restrict__ Wf,
    short* __restrict__ We0, short* __restrict__ We1,
    short* __restrict__ wos, float* __restrict__ bos)
{
    int i = blockIdx.x * 256 + threadIdx.x;
    if (i < 12288) wq[i] = f2bs(inp_w[i]);
    if (i < 4096) {
        int c = i >> 6, k = i & 63;
        float s = 0.f;
        for (int j = 0; j < 64; ++j) s = fmaf(sa_w[c * 64 + j], outp_w[j * 64 + k], s);
        wos[i] = f2bs(s);
    }
    if (i < 64) {
        float s = sa_b[i];
        for (int j = 0; j < 64; ++j) s = fmaf(sa_w[i * 64 + j], outp_b[j], s);
        bos[i] = s;
    }
    if (i < 1024) {
        int e = i >> 4, k = i & 15;
        We0[i] = f2bs(k < 12 ? ent0_w[e * 302 + k] : 0.f);
        We1[i] = f2bs(k < 8 ? ent1_w[e * 298 + k] : 0.f);
    }
    if (i < 102400) {
        int c = i / 320, k = i - c * 320;
        float v = 0.f;
        if (k < 290) {
            if (c < 64) v = self_w[c * 580 + k] + self_w[c * 580 + 290 + k];
            else if (c < 192) v = pool_w[(size_t)(c - 64) * 354 + k];
            else if (c < 256) v = ent0_w[(c - 192) * 302 + 12 + k];
            else v = ent1_w[(c - 256) * 298 + 8 + k];
        }
        Wf[i] = f2bs(v);
    }
}

// ---------------------------------------------------------------------------
// k_frontN: MFMA front end, 16 samples/block, grid 1024, 24.5 KB LDS
// -> 4 blocks/CU (grid-limited). ae (16 KB) aliases xsb; lidf aliases xp0f.
// ---------------------------------------------------------------------------
#define FN_XSB 0
#define FN_XP0 16384
#define FN_XP1 20736
#define FN_TOTAL 25088

__global__ __launch_bounds__(256, 4) void k_frontN(
    const float* __restrict__ xag, const float* __restrict__ xlid,
    const float* __restrict__ xsz, const float* __restrict__ xe0,
    const float* __restrict__ xe1,
    const float* __restrict__ conv_w, const float* __restrict__ conv_b,
    const float* __restrict__ self_b, const float* __restrict__ ent0_b,
    const float* __restrict__ ent1_b,
    const short* __restrict__ Wf, const short* __restrict__ We0,
    const short* __restrict__ We1,
    __hip_bfloat16* __restrict__ z_ent, float* __restrict__ zin_x)
{
    extern __shared__ char smem[];
    char* xsb = smem + FN_XSB;               // bf16 [16][320] swz8 (10240 B)
    float* xp0f = (float*)(smem + FN_XP0);   // f32 [16][68]
    float* xp1f = (float*)(smem + FN_XP1);   // f32 [16][68]
    char* ae = smem + FN_XSB;                // bf16 [256][32] swz4 (16384 B), aliases xsb
    float* lidf = (float*)(smem + FN_XP0);   // f32 [32][18], aliases xp0f

    const int tid = threadIdx.x;
    const int s0 = blockIdx.x * FN_SB;
    const int wv = __builtin_amdgcn_readfirstlane(tid >> 6);
    const int l = tid & 63;
    const int lr = l & 15;
    const int lg = l >> 4;

    // ---- stage inputs ----
    for (int i = tid; i < FN_SB * 32; i += 256) {      // lidar -> lidf [32][18]
        int d = i & 31, sl = i >> 5;
        lidf[d * 18 + sl] = xlid[(size_t)s0 * 32 + i];
    }
    for (int i = tid; i < FN_SB * 16; i += 256) {
        int sl = i >> 4, d = i & 15;
        *(short*)(xsb + ((sl * 640 + d * 2) ^ ((sl & 7) << 4))) = f2bs(xag[(size_t)s0 * 16 + i]);
    }
    for (int i = tid; i < FN_SB * 4; i += 256) {
        int sl = i >> 2, d = i & 3;
        *(short*)(xsb + ((sl * 640 + (286 + d) * 2) ^ ((sl & 7) << 4))) = f2bs(xsz[(size_t)s0 * 4 + i]);
    }
    for (int i = tid; i < FN_SB * 30; i += 256) {      // K pad 290..319 = 0
        int sl = i / 30, d = 290 + (i - (i / 30) * 30);
        *(short*)(xsb + ((sl * 640 + d * 2) ^ ((sl & 7) << 4))) = 0;
    }
    __syncthreads();
    // ---- conv -> xsb[sl][16+cp] ----
    for (int i = tid; i < 270 * FN_SB; i += 256) {
        int cp = i >> 4, sl = i & 15;
        int c = cp / 30, p = cp - c * 30;
        float v = conv_b[c] + conv_w[c * 3] * lidf[p * 18 + sl]
                + conv_w[c * 3 + 1] * lidf[(p + 1) * 18 + sl]
                + conv_w[c * 3 + 2] * lidf[(p + 2) * 18 + sl];
        *(short*)(xsb + ((sl * 640 + (16 + cp) * 2) ^ ((sl & 7) << 4))) = f2bs(fmaxf(v, 0.f));
    }
    __syncthreads();

    // ---- Phase 1 GEMM: [16 x 320] @ Wf^T; acc[c 0..4] ----
    f32x4 acc[5];
    #pragma unroll
    for (int c = 0; c < 5; ++c) acc[c] = (f32x4){0.f, 0.f, 0.f, 0.f};

    for (int kk = 0; kk < 10; ++kk) {
        short8 af = *(const short8*)(xsb + ((lr * 640 + kk * 64 + lg * 16) ^ ((lr & 7) << 4)));
        short8 bf[5];
        #pragma unroll
        for (int c = 0; c < 5; ++c) {
            int col = (wv * 5 + c) * 16 + lr;
            bf[c] = *(const short8*)(Wf + (size_t)col * 320 + kk * 32 + lg * 8);
        }
        #pragma unroll
        for (int c = 0; c < 5; ++c)
            acc[c] = __builtin_amdgcn_mfma_f32_16x16x32_bf16(af, bf[c], acc[c], 0, 0, 0);
    }

    // ---- Phase 1 epilogue (all 16 rows valid) ----
    #pragma unroll
    for (int c = 0; c < 5; ++c) {
        int ct = wv * 5 + c;
        int gc = ct * 16 + lr;
        int rowb = lg * 4;
        f32x4 a = acc[c];
        if (ct * 16 < 64) {
            float bias = self_b[gc];
            #pragma unroll
            for (int r = 0; r < 4; ++r)
                z_ent[(size_t)(s0 + rowb + r) * 2112 + gc] = __float2bfloat16(fmaxf(a[r] + bias, 0.f));
        } else if (ct * 16 < 192) {
            int r2 = gc - 64;
            #pragma unroll
            for (int r = 0; r < 4; ++r)
                zin_x[(size_t)(s0 + rowb + r) * 128 + r2] = a[r];
        } else if (ct * 16 < 256) {
            float bias = ent0_b[gc - 192];
            #pragma unroll
            for (int r = 0; r < 4; ++r)
                xp0f[(rowb + r) * 68 + (gc - 192)] = a[r] + bias;
        } else {
            float bias = ent1_b[gc - 256];
            #pragma unroll
            for (int r = 0; r < 4; ++r)
                xp1f[(rowb + r) * 68 + (gc - 256)] = a[r] + bias;
        }
    }
    __syncthreads();   // xsb reads done -> ae may alias it

    // ---- ent0 MLP: single chunk (256 rows) ----
    {
        short8 bz = {0, 0, 0, 0, 0, 0, 0, 0};
        short8 be[4];
        #pragma unroll
        for (int ct = 0; ct < 4; ++ct) {
            int col = ct * 16 + lr;
            short8 bv = *(const short8*)(We0 + col * 16 + (lg & 1) * 8);
            be[ct] = (lg < 2) ? bv : bz;
        }
        for (int i = tid; i < 4096; i += 256) ((uint32*)ae)[i] = 0;
        __syncthreads();
        for (int i = tid; i < FN_SB * 192; i += 256) {
            int sl = i / 192, r = i - sl * 192;
            int n = r / 12, d = r - n * 12;
            int lrow = sl * 16 + n;
            *(short*)(ae + ((lrow * 64 + d * 2) ^ ((lrow & 3) << 4))) =
                f2bs(xe0[(size_t)s0 * 192 + i]);
        }
        __syncthreads();
        #pragma unroll
        for (int j = 0; j < 4; ++j) {
            int gs = wv * 4 + j;               // sample 0..15
            int row = gs * 16 + lr;
            short8 af = *(const short8*)(ae + ((row * 64 + lg * 16) ^ ((row & 3) << 4)));
            #pragma unroll
            for (int ct = 0; ct < 4; ++ct) {
                f32x4 a2 = {0.f, 0.f, 0.f, 0.f};
                a2 = __builtin_amdgcn_mfma_f32_16x16x32_bf16(af, be[ct], a2, 0, 0, 0);
                int e = ct * 16 + lr;
                float xpv = xp0f[gs * 68 + e];
                #pragma unroll
                for (int r = 0; r < 4; ++r) {
                    int n = lg * 4 + r;
                    z_ent[(size_t)(s0 + gs) * 2112 + (1 + n) * 64 + e] =
                        __float2bfloat16(fmaxf(a2[r] + xpv, 0.f));
                }
            }
        }
        __syncthreads();
    }

    // ---- ent1 MLP: single chunk ----
    {
        short8 bz = {0, 0, 0, 0, 0, 0, 0, 0};
        short8 be[4];
        #pragma unroll
        for (int ct = 0; ct < 4; ++ct) {
            int col = ct * 16 + lr;
            short8 bv = *(const short8*)(We1 + col * 16 + (lg & 1) * 8);
            be[ct] = (lg < 2) ? bv : bz;
        }
        for (int i = tid; i < 4096; i += 256) ((uint32*)ae)[i] = 0;
        __syncthreads();
        for (int i = tid; i < FN_SB * 128; i += 256) {
            int sl = i >> 7, r = i & 127;
            int n = r >> 3, d = r & 7;
            int lrow = sl * 16 + n;
            *(short*)(ae + ((lrow * 64 + d * 2) ^ ((lrow & 3) << 4))) =
                f2bs(xe1[(size_t)s0 * 128 + i]);
        }
        __syncthreads();
        #pragma unroll
        for (int j = 0; j < 4; ++j) {
            int gs = wv * 4 + j;
            int row = gs * 16 + lr;
            short8 af = *(const short8*)(ae + ((row * 64 + lg * 16) ^ ((row & 3) << 4)));
            #pragma unroll
            for (int ct = 0; ct < 4; ++ct) {
                f32x4 a2 = {0.f, 0.f, 0.f, 0.f};
                a2 = __builtin_amdgcn_mfma_f32_16x16x32_bf16(af, be[ct], a2, 0, 0, 0);
                int e = ct * 16 + lr;
                float xpv = xp1f[gs * 68 + e];
                #pragma unroll
                for (int r = 0; r < 4; ++r) {
                    int n = lg * 4 + r;
                    z_ent[(size_t)(s0 + gs) * 2112 + (17 + n) * 64 + e] =
                        __float2bfloat16(fmaxf(a2[r] + xpv, 0.f));
                }
            }
        }
    }
}

// ---------------------------------------------------------------------------
// k_attnG: full-MFMA attention, 21.9 KB LDS, launch_bounds(256,7).
// out_proj+sa fused into one GEMM via precomputed W_os (P3 deleted).
// ---------------------------------------------------------------------------
#define AG_QB   0
#define AG_KB   6144
#define AG_VT   12288
#define AG_PW   16384
#define AG_P32  20480
#define AG_V32  21248
#define AG_MSK  21504
#define AG_POOL 21664
#define AG_TOTAL 21920

__global__ __launch_bounds__(256, 7) void k_attnG(
    const __hip_bfloat16* __restrict__ z_ent, const float* __restrict__ zin_x_ws,
    const int* __restrict__ mask0, const int* __restrict__ mask1,
    const short* __restrict__ wqkvb, const float* __restrict__ inp_b,
    const short* __restrict__ wos_g, const float* __restrict__ bos_g,
    const float* __restrict__ pool_w, const float* __restrict__ pool_b,
    float* __restrict__ zin)
{
    extern __shared__ char smem[];
    char*  Qb  = smem + AG_QB;            // bf16 [4 head][48 q][16 d]; later ob
    char*  Kb  = smem + AG_KB;            // bf16 [4 head][48 slot][16 d]
    char*  Vt  = smem + AG_VT;            // bf16 [4 head][16 d][32 slot] swz
    char*  Pw  = smem + AG_PW;            // bf16 [4 wave][16 row][32 slot] swz
    float* P32 = (float*)(smem + AG_P32); // f32 [4 head][48]
    float* V32 = (float*)(smem + AG_V32); // f32 [4 head][16]
    float* msk = (float*)(smem + AG_MSK); // f32 [36]
    float* pooled = (float*)(smem + AG_POOL);
    char*  ob  = Qb;                      // alias (after P2a barrier)

    const int tid = threadIdx.x;
    const int s = blockIdx.x;
    const short* zg = (const short*)(z_ent + (size_t)s * 2112);  // [33 rows][64]

    // ---- P0: mask ----
    if (tid < 16) msk[1 + tid] = (float)mask0[(size_t)s * 16 + tid];
    else if (tid < 32) msk[17 + (tid - 16)] = (float)mask1[(size_t)s * 16 + (tid - 16)];
    else if (tid == 32) msk[0] = 1.0f;
    __syncthreads();

    const int wv = __builtin_amdgcn_readfirstlane(tid >> 6);
    const int l  = tid & 63;
    const int lr = l & 15;
    const int lg = l >> 4;

    // ---- P1: in_proj GEMM (A from global) -> Qb / Kb / Vt / V32 ----
    {
        short8 bw[3][2]; float bias[3];
        #pragma unroll
        for (int c = 0; c < 3; ++c) {
            int col = (wv * 3 + c) * 16 + lr;
            bw[c][0] = *(const short8*)(wqkvb + col * 64 + lg * 8);
            bw[c][1] = *(const short8*)(wqkvb + col * 64 + 32 + lg * 8);
            bias[c] = inp_b[col];
        }
        for (int rt = 0; rt < 3; ++rt) {
            int arow = rt * 16 + lr;   // rows 33..47 trailing garbage, row-contained
            short8 a0 = *(const short8*)(zg + arow * 64 + lg * 8);
            short8 a1 = *(const short8*)(zg + arow * 64 + 32 + lg * 8);
            #pragma unroll
            for (int c = 0; c < 3; ++c) {
                f32x4 acc = {0.f, 0.f, 0.f, 0.f};
                acc = __builtin_amdgcn_mfma_f32_16x16x32_bf16(a0, bw[c][0], acc, 0, 0, 0);
                acc = __builtin_amdgcn_mfma_f32_16x16x32_bf16(a1, bw[c][1], acc, 0, 0, 0);
                int col = (wv * 3 + c) * 16 + lr;
                int rb = rt * 16 + lg * 4;
                #pragma unroll
                for (int r = 0; r < 4; ++r) {
                    int q = rb + r;
                    if (q < 33) {
                        float val = acc[r] + bias[c];
                        if (col < 64) {
                            int h = col >> 4, d = col & 15;
                            *(short*)(Qb + ((h * 48 + q) * 32) + d * 2) = f2bs(val);
                        } else if (col < 128) {
                            int kc = col - 64; int h = kc >> 4, d = kc & 15;
                            *(short*)(Kb + ((h * 48 + q) * 32) + d * 2) = f2bs(val);
                        } else {
                            int vc = col - 128; int h = vc >> 4, d = vc & 15;
                            if (q < 32)
                                *(short*)(Vt + (h * 16 + d) * 64 + ((q * 2) ^ pswz(d))) = f2bs(val);
                            else
                                V32[h * 16 + d] = val;
                        }
                    }
                }
            }
        }
    }
    __syncthreads();

    // ---- P2a: QK MFMA + softmax (wave = head wv); P packed in regs ----
    uint32 pk[3][4];
    {
        const short8 zero8 = {0, 0, 0, 0, 0, 0, 0, 0};
        short8 kf[3];
        #pragma unroll
        for (int t = 0; t < 3; ++t)
            kf[t] = (lg < 2) ? *(const short8*)(Kb + ((wv * 48 + t * 16 + lr) * 32) + lg * 16) : zero8;
        float mk0 = msk[lr];
        float mk1 = msk[16 + lr];
        float mk2 = (lr == 0) ? msk[32] : 0.f;
        #pragma unroll
        for (int qt = 0; qt < 3; ++qt) {
            short8 qf = (lg < 2) ? *(const short8*)(Qb + ((wv * 48 + qt * 16 + lr) * 32) + lg * 16) : zero8;
            f32x4 z = {0.f, 0.f, 0.f, 0.f};
            f32x4 S0 = __builtin_amdgcn_mfma_f32_16x16x32_bf16(qf, kf[0], z, 0, 0, 0);
            f32x4 S1 = __builtin_amdgcn_mfma_f32_16x16x32_bf16(qf, kf[1], z, 0, 0, 0);
            f32x4 S2 = __builtin_amdgcn_mfma_f32_16x16x32_bf16(qf, kf[2], z, 0, 0, 0);
            #pragma unroll
            for (int r = 0; r < 4; ++r) {
                float v0 = (mk0 > 0.f) ? S0[r] * 0.25f : -1e9f;
                float v1 = (mk1 > 0.f) ? S1[r] * 0.25f : -1e9f;
                float v2 = (mk2 > 0.f) ? S2[r] * 0.25f : -1e9f;
                float m = fmaxf(fmaxf(v0, v1), v2);
                m = fmaxf(m, __shfl_xor(m, 1));
                m = fmaxf(m, __shfl_xor(m, 2));
                m = fmaxf(m, __shfl_xor(m, 4));
                m = fmaxf(m, __shfl_xor(m, 8));
                float e0 = __expf(v0 - m), e1 = __expf(v1 - m), e2 = __expf(v2 - m);
                float sm = e0 + e1 + e2;
                sm += __shfl_xor(sm, 1);
                sm += __shfl_xor(sm, 2);
                sm += __shfl_xor(sm, 4);
                sm += __shfl_xor(sm, 8);
                float inv = 1.0f / sm;
                pk[qt][r] = pkbf(e0 * inv, e1 * inv);
                if (lr == 0) P32[wv * 48 + qt * 16 + lg * 4 + r] = e2 * inv;
            }
        }
    }
    __syncthreads();   // all Qb/Kb reads done; ob may overwrite Qb

    // ---- P2b: PV MFMA via per-wave Pw tile; write ob (aliases Qb) ----
    {
        short8 vf = *(const short8*)(Vt + (wv * 16 + lr) * 64 + ((lg * 16) ^ pswz(lr)));
        float v32reg = V32[wv * 16 + lr];
        f32x4 C[3];
        #pragma unroll
        for (int qt = 0; qt < 3; ++qt) {
            #pragma unroll
            for (int r = 0; r < 4; ++r) {
                int ql = lg * 4 + r;
                uint32 p = pk[qt][r];
                char* prow = Pw + wv * 1024 + ql * 64;
                int sz = pswz(ql);
                *(short*)(prow + ((lr * 2) ^ sz)) = (short)(p & 0xffffu);
                *(short*)(prow + (((16 + lr) * 2) ^ sz)) = (short)(p >> 16);
            }
            short8 pf = *(const short8*)(Pw + wv * 1024 + lr * 64 + ((lg * 16) ^ pswz(lr)));
            f32x4 z = {0.f, 0.f, 0.f, 0.f};
            C[qt] = __builtin_amdgcn_mfma_f32_16x16x32_bf16(pf, vf, z, 0, 0, 0);
        }
        #pragma unroll
        for (int qt = 0; qt < 3; ++qt) {
            #pragma unroll
            for (int r = 0; r < 4; ++r) {
                int q = qt * 16 + lg * 4 + r;
                if (q <= 32) {
                    float cv = C[qt][r] + P32[wv * 48 + q] * v32reg;
                    *(short*)(ob + ((q * 128 + (wv * 16 + lr) * 2) ^ ((q & 7) << 4))) = f2bs(cv);
                }
            }
        }
    }
    __syncthreads();

    // ---- P4: fused (sa@out_proj) GEMM + residual + mask; pool via shfl ----
    {
        int col = wv * 16 + lr;
        short8 b0 = *(const short8*)(wos_g + col * 64 + lg * 8);
        short8 b1 = *(const short8*)(wos_g + col * 64 + 32 + lg * 8);
        float bias = bos_g[col];
        float ps = 0.f;
        for (int rt = 0; rt < 3; ++rt) {
            int arow = rt * 16 + lr;
            int sw = (arow & 7) << 4;
            short8 a0 = *(const short8*)(ob + ((arow * 128 + lg * 16) ^ sw));
            short8 a1 = *(const short8*)(ob + ((arow * 128 + 64 + lg * 16) ^ sw));
            f32x4 acc = {0.f, 0.f, 0.f, 0.f};
            acc = __builtin_amdgcn_mfma_f32_16x16x32_bf16(a0, b0, acc, 0, 0, 0);
            acc = __builtin_amdgcn_mfma_f32_16x16x32_bf16(a1, b1, acc, 0, 0, 0);
            int rb = rt * 16 + lg * 4;
            #pragma unroll
            for (int r = 0; r < 4; ++r) {
                int row = rb + r;
                if (row < 33) {
                    float zev = bf2f(*(const unsigned short*)(zg + row * 64 + col));
                    ps += msk[row] * (zev + fmaxf(acc[r] + bias, 0.f));
                }
            }
        }
        ps += __shfl_xor(ps, 16); ps += __shfl_xor(ps, 32);
        if (lg == 0) pooled[col] = ps * (1.0f / 33.0f);
    }
    __syncthreads();

    // ---- P5: zin = relu(zin_x + pool_w[:,290:] @ pooled + b) ----
    if (tid < 128) {
        int r = tid;
        float acc = pool_b[r] + zin_x_ws[(size_t)s * 128 + r];
        const float* wrow = pool_w + (size_t)r * 354 + 290;
        #pragma unroll 8
        for (int e = 0; e < 64; ++e) acc = fmaf(wrow[e], pooled[e], acc);
        zin[(size_t)s * 128 + r] = fmaxf(acc, 0.f);
    }
}

// ---------------------------------------------------------------------------
// Kernel: LSTM scan (unchanged)
// ---------------------------------------------------------------------------
__global__ __launch_bounds__(512) void k_lstm(
    const float* __restrict__ zin, const float* __restrict__ w_ih,
    const float* __restrict__ w_hh, const float* __restrict__ b_ih,
    const float* __restrict__ b_hh, const int* __restrict__ done,
    float* __restrict__ h_all)
{
    extern __shared__ float lds[];
    float* xp = lds;
    float* zl = xp + 64 * 512;
    float* hl = zl + 128;
    float* gl = hl + 128;
    const int s = blockIdx.x;
    const int r = threadIdx.x;
    const int b = s >> 3;

    float4 w[32];
    {
        const float4* wsrc = (const float4*)(w_ih + (size_t)r * 128);
        #pragma unroll
        for (int j = 0; j < 32; ++j) w[j] = wsrc[j];
    }
    const float bias = b_ih[r] + b_hh[r];

    for (int t = 0; t < T_DIM; ++t) {
        __syncthreads();
        if (r < 128) zl[r] = zin[((size_t)t * BA + s) * 128 + r];
        __syncthreads();
        const float4* x4 = (const float4*)zl;
        float a0 = 0.f, a1 = 0.f, a2 = 0.f, a3 = 0.f;
        #pragma unroll
        for (int j = 0; j < 32; ++j) {
            float4 wa = w[j], xa = x4[j];
            a0 = fmaf(wa.x, xa.x, a0);
            a1 = fmaf(wa.y, xa.y, a1);
            a2 = fmaf(wa.z, xa.z, a2);
            a3 = fmaf(wa.w, xa.w, a3);
        }
        xp[t * 512 + r] = bias + ((a0 + a1) + (a2 + a3));
    }

    {
        const float4* wsrc = (const float4*)(w_hh + (size_t)r * 128);
        #pragma unroll
        for (int j = 0; j < 32; ++j) w[j] = wsrc[j];
    }
    if (r < 128) hl[r] = 0.0f;
    float c = 0.0f;
    __syncthreads();

    for (int t = 0; t < T_DIM; ++t) {
        const float4* h4 = (const float4*)hl;
        float a0 = 0.f, a1 = 0.f, a2 = 0.f, a3 = 0.f;
        #pragma unroll
        for (int j = 0; j < 32; ++j) {
            float4 wa = w[j], xa = h4[j];
            a0 = fmaf(wa.x, xa.x, a0);
            a1 = fmaf(wa.y, xa.y, a1);
            a2 = fmaf(wa.z, xa.z, a2);
            a3 = fmaf(wa.w, xa.w, a3);
        }
        gl[r] = xp[t * 512 + r] + ((a0 + a1) + (a2 + a3));
        __syncthreads();
        if (r < 128) {
            float keep = done[t * B_DIM + b] ? 0.0f : 1.0f;
            float gi = gl[r], gf = gl[r + 128], gg = gl[r + 256], go = gl[r + 384];
            c *= keep;
            c = sigf(gf) * c + sigf(gi) * tanhf(gg);
            float hn = sigf(go) * tanhf(c);
            float keepn = (t < T_DIM - 1) ? (done[(t + 1) * B_DIM + b] ? 0.0f : 1.0f) : 1.0f;
            hl[r] = hn * keepn;
            h_all[((size_t)t * BA + s) * 128 + r] = hn;
        }
        __syncthreads();
    }
}

// ---------------------------------------------------------------------------
// Kernel: categorical heads (unchanged)
// ---------------------------------------------------------------------------
__global__ __launch_bounds__(256) void k_heads(
    const float* __restrict__ h_all, const int* __restrict__ actions,
    const float* __restrict__ h0w, const float* __restrict__ h0b,
    const float* __restrict__ h1w, const float* __restrict__ h1b,
    float* __restrict__ out)
{
    __shared__ float w0[640], w1[640], b0[8], b1[8];
    const int tid = threadIdx.x;
    for (int i = tid; i < 640; i += 256) { w0[i] = h0w[i]; w1[i] = h1w[i]; }
    if (tid < 5) { b0[tid] = h0b[tid]; b1[tid] = h1b[tid]; }
    __syncthreads();
    const int g = blockIdx.x * 256 + tid;
    const float* h = h_all + (size_t)g * 128;
    float l0[5], l1[5];
    #pragma unroll
    for (int cc = 0; cc < 5; ++cc) { l0[cc] = b0[cc]; l1[cc] = b1[cc]; }
    for (int j = 0; j < 128; ++j) {
        float hv = h[j];
        #pragma unroll
        for (int cc = 0; cc < 5; ++cc) {
            l0[cc] = fmaf(w0[cc * 128 + j], hv, l0[cc]);
            l1[cc] = fmaf(w1[cc * 128 + j], hv, l1[cc]);
        }
    }
    int a0 = actions[(size_t)g * 2], a1 = actions[(size_t)g * 2 + 1];
    float m0 = l0[0], m1 = l1[0];
    #pragma unroll
    for (int cc = 1; cc < 5; ++cc) { m0 = fmaxf(m0, l0[cc]); m1 = fmaxf(m1, l1[cc]); }
    float s0 = 0.f, s1 = 0.f;
    #pragma unroll
    for (int cc = 0; cc < 5; ++cc) { s0 += expf(l0[cc] - m0); s1 += expf(l1[cc] - m1); }
    float lse0 = m0 + logf(s0), lse1 = m1 + logf(s1);
    float ent0 = 0.f, ent1 = 0.f, lp0 = 0.f, lp1 = 0.f;
    #pragma unroll
    for (int cc = 0; cc < 5; ++cc) {
        float p0 = l0[cc] - lse0, p1 = l1[cc] - lse1;
        ent0 -= expf(p0) * p0;
        ent1 -= expf(p1) * p1;
        if (cc == a0) lp0 = p0;
        if (cc == a1) lp1 = p1;
    }
    out[ACT_OFF + (size_t)g * 2]     = (float)a0;
    out[ACT_OFF + (size_t)g * 2 + 1] = (float)a1;
    out[LP_OFF + g]                  = lp0 * lp1;
    out[ENT_OFF + (size_t)g * 2]     = ent0;
    out[ENT_OFF + (size_t)g * 2 + 1] = ent1;
}

extern "C" void kernel_launch(void* const* d_in, const int* in_sizes, int n_in,
                              void* d_out, int out_size, void* d_ws, size_t ws_size,
                              hipStream_t stream)
{
    const float* x_agent = (const float*)d_in[0];
    const float* x_lidar = (const float*)d_in[1];
    const float* x_safe  = (const float*)d_in[2];
    const float* x_ent0  = (const float*)d_in[3];
    const float* x_ent1  = (const float*)d_in[4];
    const int*   mask0   = (const int*)d_in[5];
    const int*   mask1   = (const int*)d_in[6];
    const int*   done    = (const int*)d_in[7];
    const int*   actions = (const int*)d_in[8];
    const float* conv_w  = (const float*)d_in[9];
    const float* conv_b  = (const float*)d_in[10];
    const float* self_w  = (const float*)d_in[11];
    const float* self_b  = (const float*)d_in[12];
    const float* ent0_w  = (const float*)d_in[13];
    const float* ent0_b  = (const float*)d_in[14];
    const float* ent1_w  = (const float*)d_in[15];
    const float* ent1_b  = (const float*)d_in[16];
    const float* inp_w   = (const float*)d_in[17];
    const float* inp_b   = (const float*)d_in[18];
    const float* outp_w  = (const float*)d_in[19];
    const float* outp_b  = (const float*)d_in[20];
    const float* sa_w    = (const float*)d_in[21];
    const float* sa_b    = (const float*)d_in[22];
    const float* pool_w  = (const float*)d_in[23];
    const float* pool_b  = (const float*)d_in[24];
    const float* w_ih    = (const float*)d_in[25];
    const float* w_hh    = (const float*)d_in[26];
    const float* b_ih    = (const float*)d_in[27];
    const float* b_hh    = (const float*)d_in[28];
    const float* h0w     = (const float*)d_in[29];
    const float* h0b     = (const float*)d_in[30];
    const float* h1w     = (const float*)d_in[31];
    const float* h1b     = (const float*)d_in[32];

    __hip_bfloat16* z_ent = (__hip_bfloat16*)d_ws;
    float* zin_x = (float*)((char*)d_ws + (size_t)S_TOT * 2112 * 2);
    float* zin   = zin_x + (size_t)S_TOT * 128;
    float* h_all = zin + (size_t)S_TOT * 128;
    short* wqkvb = (short*)(h_all + (size_t)S_TOT * 128);
    short* Wf    = wqkvb + 12288;
    short* We0   = Wf + 102400;
    short* We1   = We0 + 1024;
    short* wos   = We1 + 1024;
    float* bos   = (float*)(wos + 4096);

    k_cvt2<<<400, 256, 0, stream>>>(inp_w, outp_w, outp_b, sa_w, sa_b, self_w, pool_w,
                                    ent0_w, ent1_w, wqkvb, Wf, We0, We1, wos, bos);

    k_frontN<<<S_TOT / FN_SB, 256, FN_TOTAL, stream>>>(
        x_agent, x_lidar, x_safe, x_ent0, x_ent1,
        conv_w, conv_b, self_b, ent0_b, ent1_b,
        Wf, We0, We1, z_ent, zin_x);

    k_attnG<<<S_TOT, 256, AG_TOTAL, stream>>>(
        z_ent, zin_x, mask0, mask1, wqkvb, inp_b, wos, bos,
        pool_w, pool_b, zin);

    size_t lstm_lds = (size_t)(64 * 512 + 128 + 128 + 512) * sizeof(float);
    k_lstm<<<BA, 512, lstm_lds, stream>>>(zin, w_ih, w_hh, b_ih, b_hh, done, h_all);

    k_heads<<<S_TOT / 256, 256, 0, stream>>>(h_all, actions, h0w, h0b, h1w, h1b, (float*)d_out);
}

// Round 11
// 371.374 us; speedup vs baseline: 16.4010x; 1.1301x over previous
//
#include <hip/hip_runtime.h>
#include <hip/hip_bf16.h>
#include <math.h>

#define T_DIM 64
#define B_DIM 32
#define S_TOT 16384
#define BA 256
#define FN_SB 16

#define ACT_OFF 0
#define LP_OFF 32768
#define ENT_OFF 49152

typedef __attribute__((ext_vector_type(8))) short short8;
typedef __attribute__((ext_vector_type(4))) float f32x4;
typedef unsigned int uint32;

__device__ __forceinline__ float sigf(float x) { return 1.0f / (1.0f + expf(-x)); }
__device__ __forceinline__ float bf2f(unsigned short u) {
    union { unsigned int i; float f; } a; a.i = ((unsigned int)u) << 16; return a.f;
}
__device__ __forceinline__ uint32 pkbf(float a, float b) {
    __hip_bfloat16 ha = __float2bfloat16(a), hb = __float2bfloat16(b);
    return (uint32)(*(unsigned short*)&ha) | ((uint32)(*(unsigned short*)&hb) << 16);
}
__device__ __forceinline__ short f2bs(float v) {
    __hip_bfloat16 h = __float2bfloat16(v); return *(short*)&h;
}
__device__ __forceinline__ int pswz(int row) { return (((row & 3) ^ ((row >> 2) & 3)) << 4); }

// ---------------------------------------------------------------------------
// k_cvt2: pack all MFMA weights to bf16 in ws. Adds w_ih/w_hh bf16.
// ---------------------------------------------------------------------------
__global__ __launch_bounds__(256) void k_cvt2(
    const float* __restrict__ inp_w, const float* __restrict__ outp_w,
    const float* __restrict__ outp_b, const float* __restrict__ sa_w,
    const float* __restrict__ sa_b, const float* __restrict__ self_w,
    const float* __restrict__ pool_w, const float* __restrict__ ent0_w,
    const float* __restrict__ ent1_w, const float* __restrict__ w_ih,
    const float* __restrict__ w_hh,
    short* __restrict__ wq, short* __restrict__ Wf,
    short* __restrict__ We0, short* __restrict__ We1,
    short* __restrict__ wos, float* __restrict__ bos,
    short* __restrict__ wihb, short* __restrict__ whhb)
{
    int i = blockIdx.x * 256 + threadIdx.x;
    if (i < 12288) wq[i] = f2bs(inp_w[i]);
    if (i < 65536) { wihb[i] = f2bs(w_ih[i]); whhb[i] = f2bs(w_hh[i]); }
    if (i < 4096) {
        int c = i >> 6, k = i & 63;
        float s = 0.f;
        for (int j = 0; j < 64; ++j) s = fmaf(sa_w[c * 64 + j], outp_w[j * 64 + k], s);
        wos[i] = f2bs(s);
    }
    if (i < 64) {
        float s = sa_b[i];
        for (int j = 0; j < 64; ++j) s = fmaf(sa_w[i * 64 + j], outp_b[j], s);
        bos[i] = s;
    }
    if (i < 1024) {
        int e = i >> 4, k = i & 15;
        We0[i] = f2bs(k < 12 ? ent0_w[e * 302 + k] : 0.f);
        We1[i] = f2bs(k < 8 ? ent1_w[e * 298 + k] : 0.f);
    }
    if (i < 102400) {
        int c = i / 320, k = i - c * 320;
        float v = 0.f;
        if (k < 290) {
            if (c < 64) v = self_w[c * 580 + k] + self_w[c * 580 + 290 + k];
            else if (c < 192) v = pool_w[(size_t)(c - 64) * 354 + k];
            else if (c < 256) v = ent0_w[(c - 192) * 302 + 12 + k];
            else v = ent1_w[(c - 256) * 298 + 8 + k];
        }
        Wf[i] = f2bs(v);
    }
}

// ---------------------------------------------------------------------------
// k_frontN: MFMA front end (unchanged from round 10).
// ---------------------------------------------------------------------------
#define FN_XSB 0
#define FN_XP0 16384
#define FN_XP1 20736
#define FN_TOTAL 25088

__global__ __launch_bounds__(256, 4) void k_frontN(
    const float* __restrict__ xag, const float* __restrict__ xlid,
    const float* __restrict__ xsz, const float* __restrict__ xe0,
    const float* __restrict__ xe1,
    const float* __restrict__ conv_w, const float* __restrict__ conv_b,
    const float* __restrict__ self_b, const float* __restrict__ ent0_b,
    const float* __restrict__ ent1_b,
    const short* __restrict__ Wf, const short* __restrict__ We0,
    const short* __restrict__ We1,
    __hip_bfloat16* __restrict__ z_ent, float* __restrict__ zin_x)
{
    extern __shared__ char smem[];
    char* xsb = smem + FN_XSB;
    float* xp0f = (float*)(smem + FN_XP0);
    float* xp1f = (float*)(smem + FN_XP1);
    char* ae = smem + FN_XSB;
    float* lidf = (float*)(smem + FN_XP0);

    const int tid = threadIdx.x;
    const int s0 = blockIdx.x * FN_SB;
    const int wv = __builtin_amdgcn_readfirstlane(tid >> 6);
    const int l = tid & 63;
    const int lr = l & 15;
    const int lg = l >> 4;

    for (int i = tid; i < FN_SB * 32; i += 256) {
        int d = i & 31, sl = i >> 5;
        lidf[d * 18 + sl] = xlid[(size_t)s0 * 32 + i];
    }
    for (int i = tid; i < FN_SB * 16; i += 256) {
        int sl = i >> 4, d = i & 15;
        *(short*)(xsb + ((sl * 640 + d * 2) ^ ((sl & 7) << 4))) = f2bs(xag[(size_t)s0 * 16 + i]);
    }
    for (int i = tid; i < FN_SB * 4; i += 256) {
        int sl = i >> 2, d = i & 3;
        *(short*)(xsb + ((sl * 640 + (286 + d) * 2) ^ ((sl & 7) << 4))) = f2bs(xsz[(size_t)s0 * 4 + i]);
    }
    for (int i = tid; i < FN_SB * 30; i += 256) {
        int sl = i / 30, d = 290 + (i - (i / 30) * 30);
        *(short*)(xsb + ((sl * 640 + d * 2) ^ ((sl & 7) << 4))) = 0;
    }
    __syncthreads();
    for (int i = tid; i < 270 * FN_SB; i += 256) {
        int cp = i >> 4, sl = i & 15;
        int c = cp / 30, p = cp - c * 30;
        float v = conv_b[c] + conv_w[c * 3] * lidf[p * 18 + sl]
                + conv_w[c * 3 + 1] * lidf[(p + 1) * 18 + sl]
                + conv_w[c * 3 + 2] * lidf[(p + 2) * 18 + sl];
        *(short*)(xsb + ((sl * 640 + (16 + cp) * 2) ^ ((sl & 7) << 4))) = f2bs(fmaxf(v, 0.f));
    }
    __syncthreads();

    f32x4 acc[5];
    #pragma unroll
    for (int c = 0; c < 5; ++c) acc[c] = (f32x4){0.f, 0.f, 0.f, 0.f};

    for (int kk = 0; kk < 10; ++kk) {
        short8 af = *(const short8*)(xsb + ((lr * 640 + kk * 64 + lg * 16) ^ ((lr & 7) << 4)));
        short8 bf[5];
        #pragma unroll
        for (int c = 0; c < 5; ++c) {
            int col = (wv * 5 + c) * 16 + lr;
            bf[c] = *(const short8*)(Wf + (size_t)col * 320 + kk * 32 + lg * 8);
        }
        #pragma unroll
        for (int c = 0; c < 5; ++c)
            acc[c] = __builtin_amdgcn_mfma_f32_16x16x32_bf16(af, bf[c], acc[c], 0, 0, 0);
    }

    #pragma unroll
    for (int c = 0; c < 5; ++c) {
        int ct = wv * 5 + c;
        int gc = ct * 16 + lr;
        int rowb = lg * 4;
        f32x4 a = acc[c];
        if (ct * 16 < 64) {
            float bias = self_b[gc];
            #pragma unroll
            for (int r = 0; r < 4; ++r)
                z_ent[(size_t)(s0 + rowb + r) * 2112 + gc] = __float2bfloat16(fmaxf(a[r] + bias, 0.f));
        } else if (ct * 16 < 192) {
            int r2 = gc - 64;
            #pragma unroll
            for (int r = 0; r < 4; ++r)
                zin_x[(size_t)(s0 + rowb + r) * 128 + r2] = a[r];
        } else if (ct * 16 < 256) {
            float bias = ent0_b[gc - 192];
            #pragma unroll
            for (int r = 0; r < 4; ++r)
                xp0f[(rowb + r) * 68 + (gc - 192)] = a[r] + bias;
        } else {
            float bias = ent1_b[gc - 256];
            #pragma unroll
            for (int r = 0; r < 4; ++r)
                xp1f[(rowb + r) * 68 + (gc - 256)] = a[r] + bias;
        }
    }
    __syncthreads();

    {
        short8 bz = {0, 0, 0, 0, 0, 0, 0, 0};
        short8 be[4];
        #pragma unroll
        for (int ct = 0; ct < 4; ++ct) {
            int col = ct * 16 + lr;
            short8 bv = *(const short8*)(We0 + col * 16 + (lg & 1) * 8);
            be[ct] = (lg < 2) ? bv : bz;
        }
        for (int i = tid; i < 4096; i += 256) ((uint32*)ae)[i] = 0;
        __syncthreads();
        for (int i = tid; i < FN_SB * 192; i += 256) {
            int sl = i / 192, r = i - sl * 192;
            int n = r / 12, d = r - n * 12;
            int lrow = sl * 16 + n;
            *(short*)(ae + ((lrow * 64 + d * 2) ^ ((lrow & 3) << 4))) =
                f2bs(xe0[(size_t)s0 * 192 + i]);
        }
        __syncthreads();
        #pragma unroll
        for (int j = 0; j < 4; ++j) {
            int gs = wv * 4 + j;
            int row = gs * 16 + lr;
            short8 af = *(const short8*)(ae + ((row * 64 + lg * 16) ^ ((row & 3) << 4)));
            #pragma unroll
            for (int ct = 0; ct < 4; ++ct) {
                f32x4 a2 = {0.f, 0.f, 0.f, 0.f};
                a2 = __builtin_amdgcn_mfma_f32_16x16x32_bf16(af, be[ct], a2, 0, 0, 0);
                int e = ct * 16 + lr;
                float xpv = xp0f[gs * 68 + e];
                #pragma unroll
                for (int r = 0; r < 4; ++r) {
                    int n = lg * 4 + r;
                    z_ent[(size_t)(s0 + gs) * 2112 + (1 + n) * 64 + e] =
                        __float2bfloat16(fmaxf(a2[r] + xpv, 0.f));
                }
            }
        }
        __syncthreads();
    }

    {
        short8 bz = {0, 0, 0, 0, 0, 0, 0, 0};
        short8 be[4];
        #pragma unroll
        for (int ct = 0; ct < 4; ++ct) {
            int col = ct * 16 + lr;
            short8 bv = *(const short8*)(We1 + col * 16 + (lg & 1) * 8);
            be[ct] = (lg < 2) ? bv : bz;
        }
        for (int i = tid; i < 4096; i += 256) ((uint32*)ae)[i] = 0;
        __syncthreads();
        for (int i = tid; i < FN_SB * 128; i += 256) {
            int sl = i >> 7, r = i & 127;
            int n = r >> 3, d = r & 7;
            int lrow = sl * 16 + n;
            *(short*)(ae + ((lrow * 64 + d * 2) ^ ((lrow & 3) << 4))) =
                f2bs(xe1[(size_t)s0 * 128 + i]);
        }
        __syncthreads();
        #pragma unroll
        for (int j = 0; j < 4; ++j) {
            int gs = wv * 4 + j;
            int row = gs * 16 + lr;
            short8 af = *(const short8*)(ae + ((row * 64 + lg * 16) ^ ((row & 3) << 4)));
            #pragma unroll
            for (int ct = 0; ct < 4; ++ct) {
                f32x4 a2 = {0.f, 0.f, 0.f, 0.f};
                a2 = __builtin_amdgcn_mfma_f32_16x16x32_bf16(af, be[ct], a2, 0, 0, 0);
                int e = ct * 16 + lr;
                float xpv = xp1f[gs * 68 + e];
                #pragma unroll
                for (int r = 0; r < 4; ++r) {
                    int n = lg * 4 + r;
                    z_ent[(size_t)(s0 + gs) * 2112 + (17 + n) * 64 + e] =
                        __float2bfloat16(fmaxf(a2[r] + xpv, 0.f));
                }
            }
        }
    }
}

// ---------------------------------------------------------------------------
// k_attnG: full-MFMA attention, 17.7 KB LDS -> 8 blocks/CU (32 waves = 100%).
// Qb/Kb row-stride 48 -> 33. zin written as bf16. Fused W_os GEMM.
// ---------------------------------------------------------------------------
#define AG_QB   0
#define AG_KB   4224
#define AG_VT   8448
#define AG_PW   12544
#define AG_P32  16640
#define AG_V32  17408
#define AG_MSK  17664
#define AG_POOL 17824
#define AG_TOTAL 18080

__global__ __launch_bounds__(256, 8) void k_attnG(
    const __hip_bfloat16* __restrict__ z_ent, const float* __restrict__ zin_x_ws,
    const int* __restrict__ mask0, const int* __restrict__ mask1,
    const short* __restrict__ wqkvb, const float* __restrict__ inp_b,
    const short* __restrict__ wos_g, const float* __restrict__ bos_g,
    const float* __restrict__ pool_w, const float* __restrict__ pool_b,
    short* __restrict__ zinb)
{
    extern __shared__ char smem[];
    char*  Qb  = smem + AG_QB;            // bf16 [4 head][33 q][16 d]; later ob
    char*  Kb  = smem + AG_KB;            // bf16 [4 head][33 slot][16 d]
    char*  Vt  = smem + AG_VT;            // bf16 [4 head][16 d][32 slot] swz
    char*  Pw  = smem + AG_PW;            // bf16 [4 wave][16 row][32 slot] swz
    float* P32 = (float*)(smem + AG_P32); // f32 [4 head][48]
    float* V32 = (float*)(smem + AG_V32); // f32 [4 head][16]
    float* msk = (float*)(smem + AG_MSK); // f32 [36]
    float* pooled = (float*)(smem + AG_POOL);
    char*  ob  = Qb;                      // alias (after P2a barrier)

    const int tid = threadIdx.x;
    const int s = blockIdx.x;
    const short* zg = (const short*)(z_ent + (size_t)s * 2112);  // [33 rows][64]

    if (tid < 16) msk[1 + tid] = (float)mask0[(size_t)s * 16 + tid];
    else if (tid < 32) msk[17 + (tid - 16)] = (float)mask1[(size_t)s * 16 + (tid - 16)];
    else if (tid == 32) msk[0] = 1.0f;
    __syncthreads();

    const int wv = __builtin_amdgcn_readfirstlane(tid >> 6);
    const int l  = tid & 63;
    const int lr = l & 15;
    const int lg = l >> 4;

    // ---- P1: in_proj GEMM (A from global) -> Qb / Kb / Vt / V32 ----
    {
        short8 bw[3][2]; float bias[3];
        #pragma unroll
        for (int c = 0; c < 3; ++c) {
            int col = (wv * 3 + c) * 16 + lr;
            bw[c][0] = *(const short8*)(wqkvb + col * 64 + lg * 8);
            bw[c][1] = *(const short8*)(wqkvb + col * 64 + 32 + lg * 8);
            bias[c] = inp_b[col];
        }
        for (int rt = 0; rt < 3; ++rt) {
            int arow = rt * 16 + lr;
            short8 a0 = *(const short8*)(zg + arow * 64 + lg * 8);
            short8 a1 = *(const short8*)(zg + arow * 64 + 32 + lg * 8);
            #pragma unroll
            for (int c = 0; c < 3; ++c) {
                f32x4 acc = {0.f, 0.f, 0.f, 0.f};
                acc = __builtin_amdgcn_mfma_f32_16x16x32_bf16(a0, bw[c][0], acc, 0, 0, 0);
                acc = __builtin_amdgcn_mfma_f32_16x16x32_bf16(a1, bw[c][1], acc, 0, 0, 0);
                int col = (wv * 3 + c) * 16 + lr;
                int rb = rt * 16 + lg * 4;
                #pragma unroll
                for (int r = 0; r < 4; ++r) {
                    int q = rb + r;
                    if (q < 33) {
                        float val = acc[r] + bias[c];
                        if (col < 64) {
                            int h = col >> 4, d = col & 15;
                            *(short*)(Qb + ((h * 33 + q) * 32) + d * 2) = f2bs(val);
                        } else if (col < 128) {
                            int kc = col - 64; int h = kc >> 4, d = kc & 15;
                            *(short*)(Kb + ((h * 33 + q) * 32) + d * 2) = f2bs(val);
                        } else {
                            int vc = col - 128; int h = vc >> 4, d = vc & 15;
                            if (q < 32)
                                *(short*)(Vt + (h * 16 + d) * 64 + ((q * 2) ^ pswz(d))) = f2bs(val);
                            else
                                V32[h * 16 + d] = val;
                        }
                    }
                }
            }
        }
    }
    __syncthreads();

    // ---- P2a: QK MFMA + softmax (wave = head wv); P packed in regs ----
    uint32 pk[3][4];
    {
        const short8 zero8 = {0, 0, 0, 0, 0, 0, 0, 0};
        short8 kf[3];
        #pragma unroll
        for (int t = 0; t < 3; ++t)
            kf[t] = (lg < 2) ? *(const short8*)(Kb + ((wv * 33 + t * 16 + lr) * 32) + lg * 16) : zero8;
        float mk0 = msk[lr];
        float mk1 = msk[16 + lr];
        float mk2 = (lr == 0) ? msk[32] : 0.f;
        #pragma unroll
        for (int qt = 0; qt < 3; ++qt) {
            short8 qf = (lg < 2) ? *(const short8*)(Qb + ((wv * 33 + qt * 16 + lr) * 32) + lg * 16) : zero8;
            f32x4 z = {0.f, 0.f, 0.f, 0.f};
            f32x4 S0 = __builtin_amdgcn_mfma_f32_16x16x32_bf16(qf, kf[0], z, 0, 0, 0);
            f32x4 S1 = __builtin_amdgcn_mfma_f32_16x16x32_bf16(qf, kf[1], z, 0, 0, 0);
            f32x4 S2 = __builtin_amdgcn_mfma_f32_16x16x32_bf16(qf, kf[2], z, 0, 0, 0);
            #pragma unroll
            for (int r = 0; r < 4; ++r) {
                float v0 = (mk0 > 0.f) ? S0[r] * 0.25f : -1e9f;
                float v1 = (mk1 > 0.f) ? S1[r] * 0.25f : -1e9f;
                float v2 = (mk2 > 0.f) ? S2[r] * 0.25f : -1e9f;
                float m = fmaxf(fmaxf(v0, v1), v2);
                m = fmaxf(m, __shfl_xor(m, 1));
                m = fmaxf(m, __shfl_xor(m, 2));
                m = fmaxf(m, __shfl_xor(m, 4));
                m = fmaxf(m, __shfl_xor(m, 8));
                float e0 = __expf(v0 - m), e1 = __expf(v1 - m), e2 = __expf(v2 - m);
                float sm = e0 + e1 + e2;
                sm += __shfl_xor(sm, 1);
                sm += __shfl_xor(sm, 2);
                sm += __shfl_xor(sm, 4);
                sm += __shfl_xor(sm, 8);
                float inv = 1.0f / sm;
                pk[qt][r] = pkbf(e0 * inv, e1 * inv);
                if (lr == 0) P32[wv * 48 + qt * 16 + lg * 4 + r] = e2 * inv;
            }
        }
    }
    __syncthreads();

    // ---- P2b: PV MFMA via per-wave Pw tile; write ob (aliases Qb) ----
    {
        short8 vf = *(const short8*)(Vt + (wv * 16 + lr) * 64 + ((lg * 16) ^ pswz(lr)));
        float v32reg = V32[wv * 16 + lr];
        f32x4 C[3];
        #pragma unroll
        for (int qt = 0; qt < 3; ++qt) {
            #pragma unroll
            for (int r = 0; r < 4; ++r) {
                int ql = lg * 4 + r;
                uint32 p = pk[qt][r];
                char* prow = Pw + wv * 1024 + ql * 64;
                int sz = pswz(ql);
                *(short*)(prow + ((lr * 2) ^ sz)) = (short)(p & 0xffffu);
                *(short*)(prow + (((16 + lr) * 2) ^ sz)) = (short)(p >> 16);
            }
            short8 pf = *(const short8*)(Pw + wv * 1024 + lr * 64 + ((lg * 16) ^ pswz(lr)));
            f32x4 z = {0.f, 0.f, 0.f, 0.f};
            C[qt] = __builtin_amdgcn_mfma_f32_16x16x32_bf16(pf, vf, z, 0, 0, 0);
        }
        #pragma unroll
        for (int qt = 0; qt < 3; ++qt) {
            #pragma unroll
            for (int r = 0; r < 4; ++r) {
                int q = qt * 16 + lg * 4 + r;
                if (q <= 32) {
                    float cv = C[qt][r] + P32[wv * 48 + q] * v32reg;
                    *(short*)(ob + ((q * 128 + (wv * 16 + lr) * 2) ^ ((q & 7) << 4))) = f2bs(cv);
                }
            }
        }
    }
    __syncthreads();

    // ---- P4: fused (sa@out_proj) GEMM + residual + mask; pool via shfl ----
    {
        int col = wv * 16 + lr;
        short8 b0 = *(const short8*)(wos_g + col * 64 + lg * 8);
        short8 b1 = *(const short8*)(wos_g + col * 64 + 32 + lg * 8);
        float bias = bos_g[col];
        float ps = 0.f;
        for (int rt = 0; rt < 3; ++rt) {
            int arow = rt * 16 + lr;
            int sw = (arow & 7) << 4;
            short8 a0 = *(const short8*)(ob + ((arow * 128 + lg * 16) ^ sw));
            short8 a1 = *(const short8*)(ob + ((arow * 128 + 64 + lg * 16) ^ sw));
            f32x4 acc = {0.f, 0.f, 0.f, 0.f};
            acc = __builtin_amdgcn_mfma_f32_16x16x32_bf16(a0, b0, acc, 0, 0, 0);
            acc = __builtin_amdgcn_mfma_f32_16x16x32_bf16(a1, b1, acc, 0, 0, 0);
            int rb = rt * 16 + lg * 4;
            #pragma unroll
            for (int r = 0; r < 4; ++r) {
                int row = rb + r;
                if (row < 33) {
                    float zev = bf2f(*(const unsigned short*)(zg + row * 64 + col));
                    ps += msk[row] * (zev + fmaxf(acc[r] + bias, 0.f));
                }
            }
        }
        ps += __shfl_xor(ps, 16); ps += __shfl_xor(ps, 32);
        if (lg == 0) pooled[col] = ps * (1.0f / 33.0f);
    }
    __syncthreads();

    // ---- P5: zin(bf16) = relu(zin_x + pool_w[:,290:] @ pooled + b) ----
    if (tid < 128) {
        int r = tid;
        float acc = pool_b[r] + zin_x_ws[(size_t)s * 128 + r];
        const float* wrow = pool_w + (size_t)r * 354 + 290;
        #pragma unroll 8
        for (int e = 0; e < 64; ++e) acc = fmaf(wrow[e], pooled[e], acc);
        zinb[(size_t)s * 128 + r] = f2bs(fmaxf(acc, 0.f));
    }
}

// ---------------------------------------------------------------------------
// k_xproj: xp[t,s][j*4+g] = bf16( zin @ W_ih^T + b_ih + b_hh ).
// 256 blocks x 256 thr, 64 rows/block. GEMM [64 x 512 x 128].
// ---------------------------------------------------------------------------
__global__ __launch_bounds__(256, 2) void k_xproj(
    const short* __restrict__ zinb, const short* __restrict__ wihb,
    const float* __restrict__ b_ih, const float* __restrict__ b_hh,
    short* __restrict__ xp)
{
    extern __shared__ char smem[];
    char* at = smem;   // bf16 [64][128] swz8 (16384 B)
    const int tid = threadIdx.x;
    const size_t r0 = (size_t)blockIdx.x * 64;

    for (int i = tid; i < 64 * 64; i += 256) {
        int row = i >> 6, dw = i & 63;
        uint32 v = ((const uint32*)(zinb + (r0 + row) * 128))[dw];
        *(uint32*)(at + ((row * 256 + dw * 4) ^ ((row & 7) << 4))) = v;
    }
    __syncthreads();

    const int wv = __builtin_amdgcn_readfirstlane(tid >> 6);
    const int l = tid & 63;
    const int lr = l & 15;
    const int lg = l >> 4;

    short8 af[4][4];
    #pragma unroll
    for (int rt = 0; rt < 4; ++rt)
        #pragma unroll
        for (int kc = 0; kc < 4; ++kc) {
            int row = rt * 16 + lr;
            af[rt][kc] = *(const short8*)(at + ((row * 256 + kc * 64 + lg * 16) ^ ((row & 7) << 4)));
        }

    for (int ct8 = 0; ct8 < 8; ++ct8) {
        int ct = wv * 8 + ct8;
        int col = ct * 16 + lr;
        short8 bf[4];
        #pragma unroll
        for (int kc = 0; kc < 4; ++kc)
            bf[kc] = *(const short8*)(wihb + (size_t)col * 128 + kc * 32 + lg * 8);
        float bias = b_ih[col] + b_hh[col];
        int g = col >> 7, j = col & 127;
        #pragma unroll
        for (int rt = 0; rt < 4; ++rt) {
            f32x4 acc = {0.f, 0.f, 0.f, 0.f};
            #pragma unroll
            for (int kc = 0; kc < 4; ++kc)
                acc = __builtin_amdgcn_mfma_f32_16x16x32_bf16(af[rt][kc], bf[kc], acc, 0, 0, 0);
            #pragma unroll
            for (int r = 0; r < 4; ++r)
                xp[(r0 + rt * 16 + lg * 4 + r) * 512 + j * 4 + g] = f2bs(acc[r] + bias);
        }
    }
}

// ---------------------------------------------------------------------------
// k_lstm2: MFMA recurrent scan. 16 blocks x 512 thr, 16 samples/block.
// Wave w owns hidden cols w*16+lr; ct = {w, 8+w, 16+w, 24+w} -> all 4 gates
// of a hidden unit land in one lane. h bf16 in LDS (swz); W_hh frags in regs.
// ---------------------------------------------------------------------------
__global__ __launch_bounds__(512, 1) void k_lstm2(
    const short* __restrict__ xp, const short* __restrict__ whhb,
    const int* __restrict__ done, float* __restrict__ h_all)
{
    __shared__ short hl[16 * 128];     // bf16, swizzled, 4096 B
    __shared__ float keepl[64 * 16];   // 4096 B
    const int tid = threadIdx.x;
    const int s0 = blockIdx.x * 16;
    const int wv = __builtin_amdgcn_readfirstlane(tid >> 6);
    const int l = tid & 63;
    const int lr = l & 15;
    const int lg = l >> 4;

    for (int i = tid; i < 1024; i += 512) {
        int t = i >> 4, ls = i & 15;
        keepl[i] = done[t * 32 + ((s0 + ls) >> 3)] ? 0.f : 1.f;
    }
    for (int i = tid; i < 1024; i += 512) ((uint32*)hl)[i] = 0;

    short8 bf[4][4];
    #pragma unroll
    for (int gi = 0; gi < 4; ++gi) {
        int col = (gi * 8 + wv) * 16 + lr;
        #pragma unroll
        for (int kc = 0; kc < 4; ++kc)
            bf[gi][kc] = *(const short8*)(whhb + (size_t)col * 128 + kc * 32 + lg * 8);
    }
    float c0 = 0.f, c1 = 0.f, c2 = 0.f, c3 = 0.f;
    const int jcol = wv * 16 + lr;

    short4 xn[4];
    #pragma unroll
    for (int r = 0; r < 4; ++r)
        xn[r] = *(const short4*)(xp + ((size_t)(s0 + lg * 4 + r)) * 512 + jcol * 4);
    __syncthreads();

    for (int t = 0; t < T_DIM; ++t) {
        short4 xc[4];
        #pragma unroll
        for (int r = 0; r < 4; ++r) xc[r] = xn[r];
        if (t < 63) {
            #pragma unroll
            for (int r = 0; r < 4; ++r)
                xn[r] = *(const short4*)(xp + ((size_t)(t + 1) * 256 + s0 + lg * 4 + r) * 512 + jcol * 4);
        }
        short8 af[4];
        #pragma unroll
        for (int kc = 0; kc < 4; ++kc)
            af[kc] = *(const short8*)((char*)hl + ((lr * 256 + kc * 64 + lg * 16) ^ ((lr & 7) << 4)));
        f32x4 z = {0.f, 0.f, 0.f, 0.f};
        f32x4 Ci = z, Cf = z, Cg = z, Co = z;
        #pragma unroll
        for (int kc = 0; kc < 4; ++kc) {
            Ci = __builtin_amdgcn_mfma_f32_16x16x32_bf16(af[kc], bf[0][kc], Ci, 0, 0, 0);
            Cf = __builtin_amdgcn_mfma_f32_16x16x32_bf16(af[kc], bf[1][kc], Cf, 0, 0, 0);
            Cg = __builtin_amdgcn_mfma_f32_16x16x32_bf16(af[kc], bf[2][kc], Cg, 0, 0, 0);
            Co = __builtin_amdgcn_mfma_f32_16x16x32_bf16(af[kc], bf[3][kc], Co, 0, 0, 0);
        }
        __syncthreads();   // all reads of h(t-1) complete

        #pragma unroll
        for (int r = 0; r < 4; ++r) {
            int sl = lg * 4 + r;
            float kt = keepl[t * 16 + sl];
            float gi = bf2f((unsigned short)xc[r].x) + Ci[r];
            float gf = bf2f((unsigned short)xc[r].y) + Cf[r];
            float gg = bf2f((unsigned short)xc[r].z) + Cg[r];
            float go = bf2f((unsigned short)xc[r].w) + Co[r];
            float cc = (r == 0 ? c0 : r == 1 ? c1 : r == 2 ? c2 : c3) * kt;
            cc = sigf(gf) * cc + sigf(gi) * tanhf(gg);
            float hn = sigf(go) * tanhf(cc);
            if (r == 0) c0 = cc; else if (r == 1) c1 = cc; else if (r == 2) c2 = cc; else c3 = cc;
            float kn = (t < 63) ? keepl[(t + 1) * 16 + sl] : 1.f;
            *(short*)((char*)hl + ((sl * 256 + jcol * 2) ^ ((sl & 7) << 4))) = f2bs(hn * kn);
            h_all[((size_t)t * 256 + s0 + sl) * 128 + jcol] = hn;
        }
        __syncthreads();
    }
}

// ---------------------------------------------------------------------------
// Kernel: categorical heads (unchanged)
// ---------------------------------------------------------------------------
__global__ __launch_bounds__(256) void k_heads(
    const float* __restrict__ h_all, const int* __restrict__ actions,
    const float* __restrict__ h0w, const float* __restrict__ h0b,
    const float* __restrict__ h1w, const float* __restrict__ h1b,
    float* __restrict__ out)
{
    __shared__ float w0[640], w1[640], b0[8], b1[8];
    const int tid = threadIdx.x;
    for (int i = tid; i < 640; i += 256) { w0[i] = h0w[i]; w1[i] = h1w[i]; }
    if (tid < 5) { b0[tid] = h0b[tid]; b1[tid] = h1b[tid]; }
    __syncthreads();
    const int g = blockIdx.x * 256 + tid;
    const float* h = h_all + (size_t)g * 128;
    float l0[5], l1[5];
    #pragma unroll
    for (int cc = 0; cc < 5; ++cc) { l0[cc] = b0[cc]; l1[cc] = b1[cc]; }
    for (int j = 0; j < 128; ++j) {
        float hv = h[j];
        #pragma unroll
        for (int cc = 0; cc < 5; ++cc) {
            l0[cc] = fmaf(w0[cc * 128 + j], hv, l0[cc]);
            l1[cc] = fmaf(w1[cc * 128 + j], hv, l1[cc]);
        }
    }
    int a0 = actions[(size_t)g * 2], a1 = actions[(size_t)g * 2 + 1];
    float m0 = l0[0], m1 = l1[0];
    #pragma unroll
    for (int cc = 1; cc < 5; ++cc) { m0 = fmaxf(m0, l0[cc]); m1 = fmaxf(m1, l1[cc]); }
    float s0 = 0.f, s1 = 0.f;
    #pragma unroll
    for (int cc = 0; cc < 5; ++cc) { s0 += expf(l0[cc] - m0); s1 += expf(l1[cc] - m1); }
    float lse0 = m0 + logf(s0), lse1 = m1 + logf(s1);
    float ent0 = 0.f, ent1 = 0.f, lp0 = 0.f, lp1 = 0.f;
    #pragma unroll
    for (int cc = 0; cc < 5; ++cc) {
        float p0 = l0[cc] - lse0, p1 = l1[cc] - lse1;
        ent0 -= expf(p0) * p0;
        ent1 -= expf(p1) * p1;
        if (cc == a0) lp0 = p0;
        if (cc == a1) lp1 = p1;
    }
    out[ACT_OFF + (size_t)g * 2]     = (float)a0;
    out[ACT_OFF + (size_t)g * 2 + 1] = (float)a1;
    out[LP_OFF + g]                  = lp0 * lp1;
    out[ENT_OFF + (size_t)g * 2]     = ent0;
    out[ENT_OFF + (size_t)g * 2 + 1] = ent1;
}

extern "C" void kernel_launch(void* const* d_in, const int* in_sizes, int n_in,
                              void* d_out, int out_size, void* d_ws, size_t ws_size,
                              hipStream_t stream)
{
    const float* x_agent = (const float*)d_in[0];
    const float* x_lidar = (const float*)d_in[1];
    const float* x_safe  = (const float*)d_in[2];
    const float* x_ent0  = (const float*)d_in[3];
    const float* x_ent1  = (const float*)d_in[4];
    const int*   mask0   = (const int*)d_in[5];
    const int*   mask1   = (const int*)d_in[6];
    const int*   done    = (const int*)d_in[7];
    const int*   actions = (const int*)d_in[8];
    const float* conv_w  = (const float*)d_in[9];
    const float* conv_b  = (const float*)d_in[10];
    const float* self_w  = (const float*)d_in[11];
    const float* self_b  = (const float*)d_in[12];
    const float* ent0_w  = (const float*)d_in[13];
    const float* ent0_b  = (const float*)d_in[14];
    const float* ent1_w  = (const float*)d_in[15];
    const float* ent1_b  = (const float*)d_in[16];
    const float* inp_w   = (const float*)d_in[17];
    const float* inp_b   = (const float*)d_in[18];
    const float* outp_w  = (const float*)d_in[19];
    const float* outp_b  = (const float*)d_in[20];
    const float* sa_w    = (const float*)d_in[21];
    const float* sa_b    = (const float*)d_in[22];
    const float* pool_w  = (const float*)d_in[23];
    const float* pool_b  = (const float*)d_in[24];
    const float* w_ih    = (const float*)d_in[25];
    const float* w_hh    = (const float*)d_in[26];
    const float* b_ih    = (const float*)d_in[27];
    const float* b_hh    = (const float*)d_in[28];
    const float* h0w     = (const float*)d_in[29];
    const float* h0b     = (const float*)d_in[30];
    const float* h1w     = (const float*)d_in[31];
    const float* h1b     = (const float*)d_in[32];

    // ws layout
    __hip_bfloat16* z_ent = (__hip_bfloat16*)d_ws;                       // 69.2 MB
    float* zin_x = (float*)((char*)d_ws + (size_t)S_TOT * 2112 * 2);     // 8.4 MB
    short* zinb  = (short*)(zin_x + (size_t)S_TOT * 128);                // 4.2 MB
    float* h_all = (float*)(zinb + (size_t)S_TOT * 128);                 // 8.4 MB
    short* xp    = (short*)(h_all + (size_t)S_TOT * 128);                // 16.8 MB
    short* wqkvb = xp + (size_t)S_TOT * 512;
    short* Wf    = wqkvb + 12288;
    short* We0   = Wf + 102400;
    short* We1   = We0 + 1024;
    short* wos   = We1 + 1024;
    float* bos   = (float*)(wos + 4096);
    short* wihb  = (short*)(bos + 64);
    short* whhb  = wihb + 65536;

    k_cvt2<<<400, 256, 0, stream>>>(inp_w, outp_w, outp_b, sa_w, sa_b, self_w, pool_w,
                                    ent0_w, ent1_w, w_ih, w_hh,
                                    wqkvb, Wf, We0, We1, wos, bos, wihb, whhb);

    k_frontN<<<S_TOT / FN_SB, 256, FN_TOTAL, stream>>>(
        x_agent, x_lidar, x_safe, x_ent0, x_ent1,
        conv_w, conv_b, self_b, ent0_b, ent1_b,
        Wf, We0, We1, z_ent, zin_x);

    k_attnG<<<S_TOT, 256, AG_TOTAL, stream>>>(
        z_ent, zin_x, mask0, mask1, wqkvb, inp_b, wos, bos,
        pool_w, pool_b, zinb);

    k_xproj<<<256, 256, 16384, stream>>>(zinb, wihb, b_ih, b_hh, xp);

    k_lstm2<<<16, 512, 0, stream>>>(xp, whhb, done, h_all);

    k_heads<<<S_TOT / 256, 256, 0, stream>>>(h_all, actions, h0w, h0b, h1w, h1b, (float*)d_out);
}

// Round 12
// 341.860 us; speedup vs baseline: 17.8169x; 1.0863x over previous
//
#include <hip/hip_runtime.h>
#include <hip/hip_bf16.h>
#include <math.h>

#define T_DIM 64
#define B_DIM 32
#define S_TOT 16384
#define BA 256
#define FN_SB 16

#define ACT_OFF 0
#define LP_OFF 32768
#define ENT_OFF 49152

typedef __attribute__((ext_vector_type(8))) short short8;
typedef __attribute__((ext_vector_type(4))) float f32x4;
typedef unsigned int uint32;

__device__ __forceinline__ float sigf(float x) { return 1.0f / (1.0f + expf(-x)); }
__device__ __forceinline__ float bf2f(unsigned short u) {
    union { unsigned int i; float f; } a; a.i = ((unsigned int)u) << 16; return a.f;
}
__device__ __forceinline__ uint32 pkbf(float a, float b) {
    __hip_bfloat16 ha = __float2bfloat16(a), hb = __float2bfloat16(b);
    return (uint32)(*(unsigned short*)&ha) | ((uint32)(*(unsigned short*)&hb) << 16);
}
__device__ __forceinline__ short f2bs(float v) {
    __hip_bfloat16 h = __float2bfloat16(v); return *(short*)&h;
}
__device__ __forceinline__ int pswz(int row) { return (((row & 3) ^ ((row >> 2) & 3)) << 4); }

// ---------------------------------------------------------------------------
// k_cvt2: pack all MFMA weights to bf16. We0/We1 columns REMAPPED even/odd
// (tile pair 2t/2t+1 holds even/odd e) so frontN can pack z_ent stores.
// Adds wp2 = pool_w[:,290:354] bf16 for k_zinx.
// ---------------------------------------------------------------------------
__global__ __launch_bounds__(256) void k_cvt2(
    const float* __restrict__ inp_w, const float* __restrict__ outp_w,
    const float* __restrict__ outp_b, const float* __restrict__ sa_w,
    const float* __restrict__ sa_b, const float* __restrict__ self_w,
    const float* __restrict__ pool_w, const float* __restrict__ ent0_w,
    const float* __restrict__ ent1_w, const float* __restrict__ w_ih,
    const float* __restrict__ w_hh,
    short* __restrict__ wq, short* __restrict__ Wf,
    short* __restrict__ We0, short* __restrict__ We1,
    short* __restrict__ wos, float* __restrict__ bos,
    short* __restrict__ wihb, short* __restrict__ whhb,
    short* __restrict__ wp2)
{
    int i = blockIdx.x * 256 + threadIdx.x;
    if (i < 12288) wq[i] = f2bs(inp_w[i]);
    if (i < 65536) { wihb[i] = f2bs(w_ih[i]); whhb[i] = f2bs(w_hh[i]); }
    if (i < 8192) { int c = i >> 6, k = i & 63; wp2[i] = f2bs(pool_w[(size_t)c * 354 + 290 + k]); }
    if (i < 4096) {
        int c = i >> 6, k = i & 63;
        float s = 0.f;
        for (int j = 0; j < 64; ++j) s = fmaf(sa_w[c * 64 + j], outp_w[j * 64 + k], s);
        wos[i] = f2bs(s);
    }
    if (i < 64) {
        float s = sa_b[i];
        for (int j = 0; j < 64; ++j) s = fmaf(sa_w[i * 64 + j], outp_b[j], s);
        bos[i] = s;
    }
    if (i < 1024) {
        int cp = i >> 4, k = i & 15;
        int ct = cp >> 4, lr2 = cp & 15;
        int e = 32 * (ct >> 1) + 2 * lr2 + (ct & 1);   // even/odd remap
        We0[i] = f2bs(k < 12 ? ent0_w[e * 302 + k] : 0.f);
        We1[i] = f2bs(k < 8 ? ent1_w[e * 298 + k] : 0.f);
    }
    if (i < 102400) {
        int c = i / 320, k = i - c * 320;
        float v = 0.f;
        if (k < 290) {
            if (c < 64) v = self_w[c * 580 + k] + self_w[c * 580 + 290 + k];
            else if (c < 192) v = pool_w[(size_t)(c - 64) * 354 + k];
            else if (c < 256) v = ent0_w[(c - 192) * 302 + 12 + k];
            else v = ent1_w[(c - 256) * 298 + 8 + k];
        }
        Wf[i] = f2bs(v);
    }
}

// ---------------------------------------------------------------------------
// k_frontN: MFMA front end. Entity epilogues now use the even/odd column
// remap -> packed uint32 z_ent stores (half the store count).
// ---------------------------------------------------------------------------
#define FN_XSB 0
#define FN_XP0 16384
#define FN_XP1 20736
#define FN_TOTAL 25088

__global__ __launch_bounds__(256, 4) void k_frontN(
    const float* __restrict__ xag, const float* __restrict__ xlid,
    const float* __restrict__ xsz, const float* __restrict__ xe0,
    const float* __restrict__ xe1,
    const float* __restrict__ conv_w, const float* __restrict__ conv_b,
    const float* __restrict__ self_b, const float* __restrict__ ent0_b,
    const float* __restrict__ ent1_b,
    const short* __restrict__ Wf, const short* __restrict__ We0,
    const short* __restrict__ We1,
    __hip_bfloat16* __restrict__ z_ent, float* __restrict__ zin_x)
{
    extern __shared__ char smem[];
    char* xsb = smem + FN_XSB;
    float* xp0f = (float*)(smem + FN_XP0);
    float* xp1f = (float*)(smem + FN_XP1);
    char* ae = smem + FN_XSB;
    float* lidf = (float*)(smem + FN_XP0);

    const int tid = threadIdx.x;
    const int s0 = blockIdx.x * FN_SB;
    const int wv = __builtin_amdgcn_readfirstlane(tid >> 6);
    const int l = tid & 63;
    const int lr = l & 15;
    const int lg = l >> 4;

    for (int i = tid; i < FN_SB * 32; i += 256) {
        int d = i & 31, sl = i >> 5;
        lidf[d * 18 + sl] = xlid[(size_t)s0 * 32 + i];
    }
    for (int i = tid; i < FN_SB * 16; i += 256) {
        int sl = i >> 4, d = i & 15;
        *(short*)(xsb + ((sl * 640 + d * 2) ^ ((sl & 7) << 4))) = f2bs(xag[(size_t)s0 * 16 + i]);
    }
    for (int i = tid; i < FN_SB * 4; i += 256) {
        int sl = i >> 2, d = i & 3;
        *(short*)(xsb + ((sl * 640 + (286 + d) * 2) ^ ((sl & 7) << 4))) = f2bs(xsz[(size_t)s0 * 4 + i]);
    }
    for (int i = tid; i < FN_SB * 30; i += 256) {
        int sl = i / 30, d = 290 + (i - (i / 30) * 30);
        *(short*)(xsb + ((sl * 640 + d * 2) ^ ((sl & 7) << 4))) = 0;
    }
    __syncthreads();
    for (int i = tid; i < 270 * FN_SB; i += 256) {
        int cp = i >> 4, sl = i & 15;
        int c = cp / 30, p = cp - c * 30;
        float v = conv_b[c] + conv_w[c * 3] * lidf[p * 18 + sl]
                + conv_w[c * 3 + 1] * lidf[(p + 1) * 18 + sl]
                + conv_w[c * 3 + 2] * lidf[(p + 2) * 18 + sl];
        *(short*)(xsb + ((sl * 640 + (16 + cp) * 2) ^ ((sl & 7) << 4))) = f2bs(fmaxf(v, 0.f));
    }
    __syncthreads();

    f32x4 acc[5];
    #pragma unroll
    for (int c = 0; c < 5; ++c) acc[c] = (f32x4){0.f, 0.f, 0.f, 0.f};

    for (int kk = 0; kk < 10; ++kk) {
        short8 af = *(const short8*)(xsb + ((lr * 640 + kk * 64 + lg * 16) ^ ((lr & 7) << 4)));
        short8 bf[5];
        #pragma unroll
        for (int c = 0; c < 5; ++c) {
            int col = (wv * 5 + c) * 16 + lr;
            bf[c] = *(const short8*)(Wf + (size_t)col * 320 + kk * 32 + lg * 8);
        }
        #pragma unroll
        for (int c = 0; c < 5; ++c)
            acc[c] = __builtin_amdgcn_mfma_f32_16x16x32_bf16(af, bf[c], acc[c], 0, 0, 0);
    }

    #pragma unroll
    for (int c = 0; c < 5; ++c) {
        int ct = wv * 5 + c;
        int gc = ct * 16 + lr;
        int rowb = lg * 4;
        f32x4 a = acc[c];
        if (ct * 16 < 64) {
            float bias = self_b[gc];
            #pragma unroll
            for (int r = 0; r < 4; ++r)
                z_ent[(size_t)(s0 + rowb + r) * 2112 + gc] = __float2bfloat16(fmaxf(a[r] + bias, 0.f));
        } else if (ct * 16 < 192) {
            int r2 = gc - 64;
            #pragma unroll
            for (int r = 0; r < 4; ++r)
                zin_x[(size_t)(s0 + rowb + r) * 128 + r2] = a[r];
        } else if (ct * 16 < 256) {
            float bias = ent0_b[gc - 192];
            #pragma unroll
            for (int r = 0; r < 4; ++r)
                xp0f[(rowb + r) * 68 + (gc - 192)] = a[r] + bias;
        } else {
            float bias = ent1_b[gc - 256];
            #pragma unroll
            for (int r = 0; r < 4; ++r)
                xp1f[(rowb + r) * 68 + (gc - 256)] = a[r] + bias;
        }
    }
    __syncthreads();   // xsb reads done -> ae may alias it

    // ---- ent0 MLP ----
    {
        short8 bz = {0, 0, 0, 0, 0, 0, 0, 0};
        short8 be[4];
        #pragma unroll
        for (int ct = 0; ct < 4; ++ct) {
            int col = ct * 16 + lr;
            short8 bv = *(const short8*)(We0 + col * 16 + (lg & 1) * 8);
            be[ct] = (lg < 2) ? bv : bz;
        }
        for (int i = tid; i < 4096; i += 256) ((uint32*)ae)[i] = 0;
        __syncthreads();
        for (int i = tid; i < FN_SB * 192; i += 256) {
            int sl = i / 192, r = i - sl * 192;
            int n = r / 12, d = r - n * 12;
            int lrow = sl * 16 + n;
            *(short*)(ae + ((lrow * 64 + d * 2) ^ ((lrow & 3) << 4))) =
                f2bs(xe0[(size_t)s0 * 192 + i]);
        }
        __syncthreads();
        #pragma unroll
        for (int j = 0; j < 4; ++j) {
            int gs = wv * 4 + j;
            int row = gs * 16 + lr;
            short8 af = *(const short8*)(ae + ((row * 64 + lg * 16) ^ ((row & 3) << 4)));
            f32x4 a2[4];
            #pragma unroll
            for (int ct = 0; ct < 4; ++ct) {
                f32x4 z = {0.f, 0.f, 0.f, 0.f};
                a2[ct] = __builtin_amdgcn_mfma_f32_16x16x32_bf16(af, be[ct], z, 0, 0, 0);
            }
            #pragma unroll
            for (int t = 0; t < 2; ++t) {
                int e0 = 32 * t + 2 * lr;
                float xv0 = xp0f[gs * 68 + e0];
                float xv1 = xp0f[gs * 68 + e0 + 1];
                #pragma unroll
                for (int r = 0; r < 4; ++r) {
                    int n = lg * 4 + r;
                    float v0 = fmaxf(a2[2 * t][r] + xv0, 0.f);
                    float v1 = fmaxf(a2[2 * t + 1][r] + xv1, 0.f);
                    *(uint32*)((char*)z_ent + ((size_t)(s0 + gs) * 2112 + (1 + n) * 64 + e0) * 2) = pkbf(v0, v1);
                }
            }
        }
        __syncthreads();
    }

    // ---- ent1 MLP ----
    {
        short8 bz = {0, 0, 0, 0, 0, 0, 0, 0};
        short8 be[4];
        #pragma unroll
        for (int ct = 0; ct < 4; ++ct) {
            int col = ct * 16 + lr;
            short8 bv = *(const short8*)(We1 + col * 16 + (lg & 1) * 8);
            be[ct] = (lg < 2) ? bv : bz;
        }
        for (int i = tid; i < 4096; i += 256) ((uint32*)ae)[i] = 0;
        __syncthreads();
        for (int i = tid; i < FN_SB * 128; i += 256) {
            int sl = i >> 7, r = i & 127;
            int n = r >> 3, d = r & 7;
            int lrow = sl * 16 + n;
            *(short*)(ae + ((lrow * 64 + d * 2) ^ ((lrow & 3) << 4))) =
                f2bs(xe1[(size_t)s0 * 128 + i]);
        }
        __syncthreads();
        #pragma unroll
        for (int j = 0; j < 4; ++j) {
            int gs = wv * 4 + j;
            int row = gs * 16 + lr;
            short8 af = *(const short8*)(ae + ((row * 64 + lg * 16) ^ ((row & 3) << 4)));
            f32x4 a2[4];
            #pragma unroll
            for (int ct = 0; ct < 4; ++ct) {
                f32x4 z = {0.f, 0.f, 0.f, 0.f};
                a2[ct] = __builtin_amdgcn_mfma_f32_16x16x32_bf16(af, be[ct], z, 0, 0, 0);
            }
            #pragma unroll
            for (int t = 0; t < 2; ++t) {
                int e0 = 32 * t + 2 * lr;
                float xv0 = xp1f[gs * 68 + e0];
                float xv1 = xp1f[gs * 68 + e0 + 1];
                #pragma unroll
                for (int r = 0; r < 4; ++r) {
                    int n = lg * 4 + r;
                    float v0 = fmaxf(a2[2 * t][r] + xv0, 0.f);
                    float v1 = fmaxf(a2[2 * t + 1][r] + xv1, 0.f);
                    *(uint32*)((char*)z_ent + ((size_t)(s0 + gs) * 2112 + (17 + n) * 64 + e0) * 2) = pkbf(v0, v1);
                }
            }
        }
    }
}

// ---------------------------------------------------------------------------
// k_attnG: full-MFMA attention, 17.7 KB LDS, 8 blocks/CU. Mask staging folded
// under P1's barrier; A-rows clamped to <=32 (no over-fetch); P5 removed —
// P4 writes pooled directly to ws.
// ---------------------------------------------------------------------------
#define AG_QB   0
#define AG_KB   4224
#define AG_VT   8448
#define AG_PW   12544
#define AG_P32  16640
#define AG_V32  17408
#define AG_MSK  17664
#define AG_TOTAL 17824

__global__ __launch_bounds__(256, 8) void k_attnG(
    const __hip_bfloat16* __restrict__ z_ent,
    const int* __restrict__ mask0, const int* __restrict__ mask1,
    const short* __restrict__ wqkvb, const float* __restrict__ inp_b,
    const short* __restrict__ wos_g, const float* __restrict__ bos_g,
    float* __restrict__ pooled_ws)
{
    extern __shared__ char smem[];
    char*  Qb  = smem + AG_QB;            // bf16 [4 head][33 q][16 d]; later ob
    char*  Kb  = smem + AG_KB;            // bf16 [4 head][33 slot][16 d]
    char*  Vt  = smem + AG_VT;            // bf16 [4 head][16 d][32 slot] swz
    char*  Pw  = smem + AG_PW;            // bf16 [4 wave][16 row][32 slot] swz
    float* P32 = (float*)(smem + AG_P32); // f32 [4 head][48]
    float* V32 = (float*)(smem + AG_V32); // f32 [4 head][16]
    float* msk = (float*)(smem + AG_MSK); // f32 [36]
    char*  ob  = Qb;                      // alias (after P2a barrier)

    const int tid = threadIdx.x;
    const int s = blockIdx.x;
    const short* zg = (const short*)(z_ent + (size_t)s * 2112);  // [33 rows][64]

    // mask staging (covered by P1's barrier — no extra sync)
    if (tid < 16) msk[1 + tid] = (float)mask0[(size_t)s * 16 + tid];
    else if (tid < 32) msk[17 + (tid - 16)] = (float)mask1[(size_t)s * 16 + (tid - 16)];
    else if (tid == 32) msk[0] = 1.0f;

    const int wv = __builtin_amdgcn_readfirstlane(tid >> 6);
    const int l  = tid & 63;
    const int lr = l & 15;
    const int lg = l >> 4;

    // ---- P1: in_proj GEMM (A from global, rows clamped to 32) ----
    {
        short8 bw[3][2]; float bias[3];
        #pragma unroll
        for (int c = 0; c < 3; ++c) {
            int col = (wv * 3 + c) * 16 + lr;
            bw[c][0] = *(const short8*)(wqkvb + col * 64 + lg * 8);
            bw[c][1] = *(const short8*)(wqkvb + col * 64 + 32 + lg * 8);
            bias[c] = inp_b[col];
        }
        for (int rt = 0; rt < 3; ++rt) {
            int arow = rt * 16 + lr;
            if (arow > 32) arow = 32;   // duplicate row 32; results discarded by q<33
            short8 a0 = *(const short8*)(zg + arow * 64 + lg * 8);
            short8 a1 = *(const short8*)(zg + arow * 64 + 32 + lg * 8);
            #pragma unroll
            for (int c = 0; c < 3; ++c) {
                f32x4 acc = {0.f, 0.f, 0.f, 0.f};
                acc = __builtin_amdgcn_mfma_f32_16x16x32_bf16(a0, bw[c][0], acc, 0, 0, 0);
                acc = __builtin_amdgcn_mfma_f32_16x16x32_bf16(a1, bw[c][1], acc, 0, 0, 0);
                int col = (wv * 3 + c) * 16 + lr;
                int rb = rt * 16 + lg * 4;
                #pragma unroll
                for (int r = 0; r < 4; ++r) {
                    int q = rb + r;
                    if (q < 33) {
                        float val = acc[r] + bias[c];
                        if (col < 64) {
                            int h = col >> 4, d = col & 15;
                            *(short*)(Qb + ((h * 33 + q) * 32) + d * 2) = f2bs(val);
                        } else if (col < 128) {
                            int kc = col - 64; int h = kc >> 4, d = kc & 15;
                            *(short*)(Kb + ((h * 33 + q) * 32) + d * 2) = f2bs(val);
                        } else {
                            int vc = col - 128; int h = vc >> 4, d = vc & 15;
                            if (q < 32)
                                *(short*)(Vt + (h * 16 + d) * 64 + ((q * 2) ^ pswz(d))) = f2bs(val);
                            else
                                V32[h * 16 + d] = val;
                        }
                    }
                }
            }
        }
    }
    __syncthreads();

    // ---- P2a: QK MFMA + softmax; P packed in regs ----
    uint32 pk[3][4];
    {
        const short8 zero8 = {0, 0, 0, 0, 0, 0, 0, 0};
        short8 kf[3];
        #pragma unroll
        for (int t = 0; t < 3; ++t)
            kf[t] = (lg < 2) ? *(const short8*)(Kb + ((wv * 33 + t * 16 + lr) * 32) + lg * 16) : zero8;
        float mk0 = msk[lr];
        float mk1 = msk[16 + lr];
        float mk2 = (lr == 0) ? msk[32] : 0.f;
        #pragma unroll
        for (int qt = 0; qt < 3; ++qt) {
            short8 qf = (lg < 2) ? *(const short8*)(Qb + ((wv * 33 + qt * 16 + lr) * 32) + lg * 16) : zero8;
            f32x4 z = {0.f, 0.f, 0.f, 0.f};
            f32x4 S0 = __builtin_amdgcn_mfma_f32_16x16x32_bf16(qf, kf[0], z, 0, 0, 0);
            f32x4 S1 = __builtin_amdgcn_mfma_f32_16x16x32_bf16(qf, kf[1], z, 0, 0, 0);
            f32x4 S2 = __builtin_amdgcn_mfma_f32_16x16x32_bf16(qf, kf[2], z, 0, 0, 0);
            #pragma unroll
            for (int r = 0; r < 4; ++r) {
                float v0 = (mk0 > 0.f) ? S0[r] * 0.25f : -1e9f;
                float v1 = (mk1 > 0.f) ? S1[r] * 0.25f : -1e9f;
                float v2 = (mk2 > 0.f) ? S2[r] * 0.25f : -1e9f;
                float m = fmaxf(fmaxf(v0, v1), v2);
                m = fmaxf(m, __shfl_xor(m, 1));
                m = fmaxf(m, __shfl_xor(m, 2));
                m = fmaxf(m, __shfl_xor(m, 4));
                m = fmaxf(m, __shfl_xor(m, 8));
                float e0 = __expf(v0 - m), e1 = __expf(v1 - m), e2 = __expf(v2 - m);
                float sm = e0 + e1 + e2;
                sm += __shfl_xor(sm, 1);
                sm += __shfl_xor(sm, 2);
                sm += __shfl_xor(sm, 4);
                sm += __shfl_xor(sm, 8);
                float inv = 1.0f / sm;
                pk[qt][r] = pkbf(e0 * inv, e1 * inv);
                if (lr == 0) P32[wv * 48 + qt * 16 + lg * 4 + r] = e2 * inv;
            }
        }
    }
    __syncthreads();   // all Qb/Kb reads done; ob may overwrite Qb

    // ---- P2b: PV MFMA via per-wave Pw tile; write ob (aliases Qb) ----
    {
        short8 vf = *(const short8*)(Vt + (wv * 16 + lr) * 64 + ((lg * 16) ^ pswz(lr)));
        float v32reg = V32[wv * 16 + lr];
        f32x4 C[3];
        #pragma unroll
        for (int qt = 0; qt < 3; ++qt) {
            #pragma unroll
            for (int r = 0; r < 4; ++r) {
                int ql = lg * 4 + r;
                uint32 p = pk[qt][r];
                char* prow = Pw + wv * 1024 + ql * 64;
                int sz = pswz(ql);
                *(short*)(prow + ((lr * 2) ^ sz)) = (short)(p & 0xffffu);
                *(short*)(prow + (((16 + lr) * 2) ^ sz)) = (short)(p >> 16);
            }
            short8 pf = *(const short8*)(Pw + wv * 1024 + lr * 64 + ((lg * 16) ^ pswz(lr)));
            f32x4 z = {0.f, 0.f, 0.f, 0.f};
            C[qt] = __builtin_amdgcn_mfma_f32_16x16x32_bf16(pf, vf, z, 0, 0, 0);
        }
        #pragma unroll
        for (int qt = 0; qt < 3; ++qt) {
            #pragma unroll
            for (int r = 0; r < 4; ++r) {
                int q = qt * 16 + lg * 4 + r;
                if (q <= 32) {
                    float cv = C[qt][r] + P32[wv * 48 + q] * v32reg;
                    *(short*)(ob + ((q * 128 + (wv * 16 + lr) * 2) ^ ((q & 7) << 4))) = f2bs(cv);
                }
            }
        }
    }
    __syncthreads();

    // ---- P4: fused (sa@out_proj) GEMM + residual + mask; pooled -> ws ----
    {
        int col = wv * 16 + lr;
        short8 b0 = *(const short8*)(wos_g + col * 64 + lg * 8);
        short8 b1 = *(const short8*)(wos_g + col * 64 + 32 + lg * 8);
        float bias = bos_g[col];
        float ps = 0.f;
        for (int rt = 0; rt < 3; ++rt) {
            int arow = rt * 16 + lr;
            int sw = (arow & 7) << 4;
            short8 a0 = *(const short8*)(ob + ((arow * 128 + lg * 16) ^ sw));
            short8 a1 = *(const short8*)(ob + ((arow * 128 + 64 + lg * 16) ^ sw));
            f32x4 acc = {0.f, 0.f, 0.f, 0.f};
            acc = __builtin_amdgcn_mfma_f32_16x16x32_bf16(a0, b0, acc, 0, 0, 0);
            acc = __builtin_amdgcn_mfma_f32_16x16x32_bf16(a1, b1, acc, 0, 0, 0);
            int rb = rt * 16 + lg * 4;
            #pragma unroll
            for (int r = 0; r < 4; ++r) {
                int row = rb + r;
                if (row < 33) {
                    float zev = bf2f(*(const unsigned short*)(zg + row * 64 + col));
                    ps += msk[row] * (zev + fmaxf(acc[r] + bias, 0.f));
                }
            }
        }
        ps += __shfl_xor(ps, 16); ps += __shfl_xor(ps, 32);
        if (lg == 0) pooled_ws[(size_t)s * 64 + col] = ps * (1.0f / 33.0f);
    }
}

// ---------------------------------------------------------------------------
// k_zinx: fused zin + x-projection. 256 blocks x 256 thr, 64 samples/block.
// GEMM1: zin = relu(zin_x + Wp2 @ pooled + pool_b) -> LDS bf16 tile
// GEMM2: xp = zin @ W_ih^T + (b_ih + b_hh), gates packed [j][4].
// ---------------------------------------------------------------------------
__global__ __launch_bounds__(256, 2) void k_zinx(
    const float* __restrict__ pooled_ws, const float* __restrict__ zin_x,
    const short* __restrict__ wp2, const float* __restrict__ pool_b,
    const short* __restrict__ wihb, const float* __restrict__ b_ih,
    const float* __restrict__ b_hh, short* __restrict__ xp)
{
    extern __shared__ char smem[];
    char* A1 = smem;           // bf16 [64][64] swz8 (8192 B)
    char* zt = smem + 8192;    // bf16 [64][128] swz8 (16384 B)
    const int tid = threadIdx.x;
    const size_t r0 = (size_t)blockIdx.x * 64;

    for (int i = tid; i < 2048; i += 256) {
        int sl = i >> 5, dp = i & 31;
        float2 v = ((const float2*)(pooled_ws + (r0 + sl) * 64))[dp];
        *(uint32*)(A1 + ((sl * 128 + dp * 4) ^ ((sl & 7) << 4))) = pkbf(v.x, v.y);
    }
    __syncthreads();

    const int wv = __builtin_amdgcn_readfirstlane(tid >> 6);
    const int l = tid & 63;
    const int lr = l & 15;
    const int lg = l >> 4;

    // ---- GEMM1: [64 x 64] @ Wp2^T [128 x 64] ----
    #pragma unroll
    for (int c = 0; c < 2; ++c) {
        int col = (wv * 2 + c) * 16 + lr;
        short8 bf0 = *(const short8*)(wp2 + col * 64 + lg * 8);
        short8 bf1 = *(const short8*)(wp2 + col * 64 + 32 + lg * 8);
        float bias = pool_b[col];
        #pragma unroll
        for (int rt = 0; rt < 4; ++rt) {
            int row16 = rt * 16 + lr;
            short8 a0 = *(const short8*)(A1 + ((row16 * 128 + lg * 16) ^ ((row16 & 7) << 4)));
            short8 a1 = *(const short8*)(A1 + ((row16 * 128 + 64 + lg * 16) ^ ((row16 & 7) << 4)));
            f32x4 acc = {0.f, 0.f, 0.f, 0.f};
            acc = __builtin_amdgcn_mfma_f32_16x16x32_bf16(a0, bf0, acc, 0, 0, 0);
            acc = __builtin_amdgcn_mfma_f32_16x16x32_bf16(a1, bf1, acc, 0, 0, 0);
            #pragma unroll
            for (int r = 0; r < 4; ++r) {
                int row = rt * 16 + lg * 4 + r;
                float v = fmaxf(acc[r] + bias + zin_x[(r0 + row) * 128 + col], 0.f);
                *(short*)(zt + ((row * 256 + col * 2) ^ ((row & 7) << 4))) = f2bs(v);
            }
        }
    }
    __syncthreads();

    // ---- GEMM2: xp = zin @ W_ih^T ----
    short8 af[4][4];
    #pragma unroll
    for (int rt = 0; rt < 4; ++rt)
        #pragma unroll
        for (int kc = 0; kc < 4; ++kc) {
            int row = rt * 16 + lr;
            af[rt][kc] = *(const short8*)(zt + ((row * 256 + kc * 64 + lg * 16) ^ ((row & 7) << 4)));
        }

    for (int ct8 = 0; ct8 < 8; ++ct8) {
        int ct = wv * 8 + ct8;
        int col = ct * 16 + lr;
        short8 bf[4];
        #pragma unroll
        for (int kc = 0; kc < 4; ++kc)
            bf[kc] = *(const short8*)(wihb + (size_t)col * 128 + kc * 32 + lg * 8);
        float bias = b_ih[col] + b_hh[col];
        int g = col >> 7, j = col & 127;
        #pragma unroll
        for (int rt = 0; rt < 4; ++rt) {
            f32x4 acc = {0.f, 0.f, 0.f, 0.f};
            #pragma unroll
            for (int kc = 0; kc < 4; ++kc)
                acc = __builtin_amdgcn_mfma_f32_16x16x32_bf16(af[rt][kc], bf[kc], acc, 0, 0, 0);
            #pragma unroll
            for (int r = 0; r < 4; ++r)
                xp[(r0 + rt * 16 + lg * 4 + r) * 512 + j * 4 + g] = f2bs(acc[r] + bias);
        }
    }
}

// ---------------------------------------------------------------------------
// k_lstm2: MFMA recurrent scan (unchanged from round 11).
// ---------------------------------------------------------------------------
__global__ __launch_bounds__(512, 1) void k_lstm2(
    const short* __restrict__ xp, const short* __restrict__ whhb,
    const int* __restrict__ done, float* __restrict__ h_all)
{
    __shared__ short hl[16 * 128];
    __shared__ float keepl[64 * 16];
    const int tid = threadIdx.x;
    const int s0 = blockIdx.x * 16;
    const int wv = __builtin_amdgcn_readfirstlane(tid >> 6);
    const int l = tid & 63;
    const int lr = l & 15;
    const int lg = l >> 4;

    for (int i = tid; i < 1024; i += 512) {
        int t = i >> 4, ls = i & 15;
        keepl[i] = done[t * 32 + ((s0 + ls) >> 3)] ? 0.f : 1.f;
    }
    for (int i = tid; i < 1024; i += 512) ((uint32*)hl)[i] = 0;

    short8 bf[4][4];
    #pragma unroll
    for (int gi = 0; gi < 4; ++gi) {
        int col = (gi * 8 + wv) * 16 + lr;
        #pragma unroll
        for (int kc = 0; kc < 4; ++kc)
            bf[gi][kc] = *(const short8*)(whhb + (size_t)col * 128 + kc * 32 + lg * 8);
    }
    float c0 = 0.f, c1 = 0.f, c2 = 0.f, c3 = 0.f;
    const int jcol = wv * 16 + lr;

    short4 xn[4];
    #pragma unroll
    for (int r = 0; r < 4; ++r)
        xn[r] = *(const short4*)(xp + ((size_t)(s0 + lg * 4 + r)) * 512 + jcol * 4);
    __syncthreads();

    for (int t = 0; t < T_DIM; ++t) {
        short4 xc[4];
        #pragma unroll
        for (int r = 0; r < 4; ++r) xc[r] = xn[r];
        if (t < 63) {
            #pragma unroll
            for (int r = 0; r < 4; ++r)
                xn[r] = *(const short4*)(xp + ((size_t)(t + 1) * 256 + s0 + lg * 4 + r) * 512 + jcol * 4);
        }
        short8 af[4];
        #pragma unroll
        for (int kc = 0; kc < 4; ++kc)
            af[kc] = *(const short8*)((char*)hl + ((lr * 256 + kc * 64 + lg * 16) ^ ((lr & 7) << 4)));
        f32x4 z = {0.f, 0.f, 0.f, 0.f};
        f32x4 Ci = z, Cf = z, Cg = z, Co = z;
        #pragma unroll
        for (int kc = 0; kc < 4; ++kc) {
            Ci = __builtin_amdgcn_mfma_f32_16x16x32_bf16(af[kc], bf[0][kc], Ci, 0, 0, 0);
            Cf = __builtin_amdgcn_mfma_f32_16x16x32_bf16(af[kc], bf[1][kc], Cf, 0, 0, 0);
            Cg = __builtin_amdgcn_mfma_f32_16x16x32_bf16(af[kc], bf[2][kc], Cg, 0, 0, 0);
            Co = __builtin_amdgcn_mfma_f32_16x16x32_bf16(af[kc], bf[3][kc], Co, 0, 0, 0);
        }
        __syncthreads();

        #pragma unroll
        for (int r = 0; r < 4; ++r) {
            int sl = lg * 4 + r;
            float kt = keepl[t * 16 + sl];
            float gi = bf2f((unsigned short)xc[r].x) + Ci[r];
            float gf = bf2f((unsigned short)xc[r].y) + Cf[r];
            float gg = bf2f((unsigned short)xc[r].z) + Cg[r];
            float go = bf2f((unsigned short)xc[r].w) + Co[r];
            float cc = (r == 0 ? c0 : r == 1 ? c1 : r == 2 ? c2 : c3) * kt;
            cc = sigf(gf) * cc + sigf(gi) * tanhf(gg);
            float hn = sigf(go) * tanhf(cc);
            if (r == 0) c0 = cc; else if (r == 1) c1 = cc; else if (r == 2) c2 = cc; else c3 = cc;
            float kn = (t < 63) ? keepl[(t + 1) * 16 + sl] : 1.f;
            *(short*)((char*)hl + ((sl * 256 + jcol * 2) ^ ((sl & 7) << 4))) = f2bs(hn * kn);
            h_all[((size_t)t * 256 + s0 + sl) * 128 + jcol] = hn;
        }
        __syncthreads();
    }
}

// ---------------------------------------------------------------------------
// Kernel: categorical heads (unchanged)
// ---------------------------------------------------------------------------
__global__ __launch_bounds__(256) void k_heads(
    const float* __restrict__ h_all, const int* __restrict__ actions,
    const float* __restrict__ h0w, const float* __restrict__ h0b,
    const float* __restrict__ h1w, const float* __restrict__ h1b,
    float* __restrict__ out)
{
    __shared__ float w0[640], w1[640], b0[8], b1[8];
    const int tid = threadIdx.x;
    for (int i = tid; i < 640; i += 256) { w0[i] = h0w[i]; w1[i] = h1w[i]; }
    if (tid < 5) { b0[tid] = h0b[tid]; b1[tid] = h1b[tid]; }
    __syncthreads();
    const int g = blockIdx.x * 256 + tid;
    const float* h = h_all + (size_t)g * 128;
    float l0[5], l1[5];
    #pragma unroll
    for (int cc = 0; cc < 5; ++cc) { l0[cc] = b0[cc]; l1[cc] = b1[cc]; }
    for (int j = 0; j < 128; ++j) {
        float hv = h[j];
        #pragma unroll
        for (int cc = 0; cc < 5; ++cc) {
            l0[cc] = fmaf(w0[cc * 128 + j], hv, l0[cc]);
            l1[cc] = fmaf(w1[cc * 128 + j], hv, l1[cc]);
        }
    }
    int a0 = actions[(size_t)g * 2], a1 = actions[(size_t)g * 2 + 1];
    float m0 = l0[0], m1 = l1[0];
    #pragma unroll
    for (int cc = 1; cc < 5; ++cc) { m0 = fmaxf(m0, l0[cc]); m1 = fmaxf(m1, l1[cc]); }
    float s0 = 0.f, s1 = 0.f;
    #pragma unroll
    for (int cc = 0; cc < 5; ++cc) { s0 += expf(l0[cc] - m0); s1 += expf(l1[cc] - m1); }
    float lse0 = m0 + logf(s0), lse1 = m1 + logf(s1);
    float ent0 = 0.f, ent1 = 0.f, lp0 = 0.f, lp1 = 0.f;
    #pragma unroll
    for (int cc = 0; cc < 5; ++cc) {
        float p0 = l0[cc] - lse0, p1 = l1[cc] - lse1;
        ent0 -= expf(p0) * p0;
        ent1 -= expf(p1) * p1;
        if (cc == a0) lp0 = p0;
        if (cc == a1) lp1 = p1;
    }
    out[ACT_OFF + (size_t)g * 2]     = (float)a0;
    out[ACT_OFF + (size_t)g * 2 + 1] = (float)a1;
    out[LP_OFF + g]                  = lp0 * lp1;
    out[ENT_OFF + (size_t)g * 2]     = ent0;
    out[ENT_OFF + (size_t)g * 2 + 1] = ent1;
}

extern "C" void kernel_launch(void* const* d_in, const int* in_sizes, int n_in,
                              void* d_out, int out_size, void* d_ws, size_t ws_size,
                              hipStream_t stream)
{
    const float* x_agent = (const float*)d_in[0];
    const float* x_lidar = (const float*)d_in[1];
    const float* x_safe  = (const float*)d_in[2];
    const float* x_ent0  = (const float*)d_in[3];
    const float* x_ent1  = (const float*)d_in[4];
    const int*   mask0   = (const int*)d_in[5];
    const int*   mask1   = (const int*)d_in[6];
    const int*   done    = (const int*)d_in[7];
    const int*   actions = (const int*)d_in[8];
    const float* conv_w  = (const float*)d_in[9];
    const float* conv_b  = (const float*)d_in[10];
    const float* self_w  = (const float*)d_in[11];
    const float* self_b  = (const float*)d_in[12];
    const float* ent0_w  = (const float*)d_in[13];
    const float* ent0_b  = (const float*)d_in[14];
    const float* ent1_w  = (const float*)d_in[15];
    const float* ent1_b  = (const float*)d_in[16];
    const float* inp_w   = (const float*)d_in[17];
    const float* inp_b   = (const float*)d_in[18];
    const float* outp_w  = (const float*)d_in[19];
    const float* outp_b  = (const float*)d_in[20];
    const float* sa_w    = (const float*)d_in[21];
    const float* sa_b    = (const float*)d_in[22];
    const float* pool_w  = (const float*)d_in[23];
    const float* pool_b  = (const float*)d_in[24];
    const float* w_ih    = (const float*)d_in[25];
    const float* w_hh    = (const float*)d_in[26];
    const float* b_ih    = (const float*)d_in[27];
    const float* b_hh    = (const float*)d_in[28];
    const float* h0w     = (const float*)d_in[29];
    const float* h0b     = (const float*)d_in[30];
    const float* h1w     = (const float*)d_in[31];
    const float* h1b     = (const float*)d_in[32];

    // ws layout
    __hip_bfloat16* z_ent = (__hip_bfloat16*)d_ws;                       // 69.2 MB
    float* zin_x  = (float*)((char*)d_ws + (size_t)S_TOT * 2112 * 2);    // 8.4 MB
    float* pooled = zin_x + (size_t)S_TOT * 128;                         // 4.2 MB
    float* h_all  = pooled + (size_t)S_TOT * 64;                         // 8.4 MB
    short* xp     = (short*)(h_all + (size_t)S_TOT * 128);               // 16.8 MB
    short* wqkvb  = xp + (size_t)S_TOT * 512;
    short* Wf     = wqkvb + 12288;
    short* We0    = Wf + 102400;
    short* We1    = We0 + 1024;
    short* wos    = We1 + 1024;
    float* bos    = (float*)(wos + 4096);
    short* wihb   = (short*)(bos + 64);
    short* whhb   = wihb + 65536;
    short* wp2    = whhb + 65536;

    k_cvt2<<<400, 256, 0, stream>>>(inp_w, outp_w, outp_b, sa_w, sa_b, self_w, pool_w,
                                    ent0_w, ent1_w, w_ih, w_hh,
                                    wqkvb, Wf, We0, We1, wos, bos, wihb, whhb, wp2);

    k_frontN<<<S_TOT / FN_SB, 256, FN_TOTAL, stream>>>(
        x_agent, x_lidar, x_safe, x_ent0, x_ent1,
        conv_w, conv_b, self_b, ent0_b, ent1_b,
        Wf, We0, We1, z_ent, zin_x);

    k_attnG<<<S_TOT, 256, AG_TOTAL, stream>>>(
        z_ent, mask0, mask1, wqkvb, inp_b, wos, bos, pooled);

    k_zinx<<<256, 256, 24576, stream>>>(pooled, zin_x, wp2, pool_b, wihb, b_ih, b_hh, xp);

    k_lstm2<<<16, 512, 0, stream>>>(xp, whhb, done, h_all);

    k_heads<<<S_TOT / 256, 256, 0, stream>>>(h_all, actions, h0w, h0b, h1w, h1b, (float*)d_out);
}

// Round 13
// 318.138 us; speedup vs baseline: 19.1454x; 1.0746x over previous
//
#include <hip/hip_runtime.h>
#include <hip/hip_bf16.h>
#include <math.h>

#define T_DIM 64
#define B_DIM 32
#define S_TOT 16384
#define BA 256
#define FN_SB 16

#define ACT_OFF 0
#define LP_OFF 32768
#define ENT_OFF 49152

typedef __attribute__((ext_vector_type(8))) short short8;
typedef __attribute__((ext_vector_type(4))) float f32x4;
typedef unsigned int uint32;

__device__ __forceinline__ float sigf(float x) { return 1.0f / (1.0f + expf(-x)); }
__device__ __forceinline__ float bf2f(unsigned short u) {
    union { unsigned int i; float f; } a; a.i = ((unsigned int)u) << 16; return a.f;
}
__device__ __forceinline__ uint32 pkbf(float a, float b) {
    __hip_bfloat16 ha = __float2bfloat16(a), hb = __float2bfloat16(b);
    return (uint32)(*(unsigned short*)&ha) | ((uint32)(*(unsigned short*)&hb) << 16);
}
__device__ __forceinline__ short f2bs(float v) {
    __hip_bfloat16 h = __float2bfloat16(v); return *(short*)&h;
}
__device__ __forceinline__ int pswz(int row) { return (((row & 3) ^ ((row >> 2) & 3)) << 4); }

// ---------------------------------------------------------------------------
// k_cvt2: pack all MFMA weights to bf16 (unchanged from round 12).
// ---------------------------------------------------------------------------
__global__ __launch_bounds__(256) void k_cvt2(
    const float* __restrict__ inp_w, const float* __restrict__ outp_w,
    const float* __restrict__ outp_b, const float* __restrict__ sa_w,
    const float* __restrict__ sa_b, const float* __restrict__ self_w,
    const float* __restrict__ pool_w, const float* __restrict__ ent0_w,
    const float* __restrict__ ent1_w, const float* __restrict__ w_ih,
    const float* __restrict__ w_hh,
    short* __restrict__ wq, short* __restrict__ Wf,
    short* __restrict__ We0, short* __restrict__ We1,
    short* __restrict__ wos, float* __restrict__ bos,
    short* __restrict__ wihb, short* __restrict__ whhb,
    short* __restrict__ wp2)
{
    int i = blockIdx.x * 256 + threadIdx.x;
    if (i < 12288) wq[i] = f2bs(inp_w[i]);
    if (i < 65536) { wihb[i] = f2bs(w_ih[i]); whhb[i] = f2bs(w_hh[i]); }
    if (i < 8192) { int c = i >> 6, k = i & 63; wp2[i] = f2bs(pool_w[(size_t)c * 354 + 290 + k]); }
    if (i < 4096) {
        int c = i >> 6, k = i & 63;
        float s = 0.f;
        for (int j = 0; j < 64; ++j) s = fmaf(sa_w[c * 64 + j], outp_w[j * 64 + k], s);
        wos[i] = f2bs(s);
    }
    if (i < 64) {
        float s = sa_b[i];
        for (int j = 0; j < 64; ++j) s = fmaf(sa_w[i * 64 + j], outp_b[j], s);
        bos[i] = s;
    }
    if (i < 1024) {
        int cp = i >> 4, k = i & 15;
        int ct = cp >> 4, lr2 = cp & 15;
        int e = 32 * (ct >> 1) + 2 * lr2 + (ct & 1);   // even/odd remap
        We0[i] = f2bs(k < 12 ? ent0_w[e * 302 + k] : 0.f);
        We1[i] = f2bs(k < 8 ? ent1_w[e * 298 + k] : 0.f);
    }
    if (i < 102400) {
        int c = i / 320, k = i - c * 320;
        float v = 0.f;
        if (k < 290) {
            if (c < 64) v = self_w[c * 580 + k] + self_w[c * 580 + 290 + k];
            else if (c < 192) v = pool_w[(size_t)(c - 64) * 354 + k];
            else if (c < 256) v = ent0_w[(c - 192) * 302 + 12 + k];
            else v = ent1_w[(c - 256) * 298 + 8 + k];
        }
        Wf[i] = f2bs(v);
    }
}

// ---------------------------------------------------------------------------
// k_frontN: MFMA front end. Conv loop de-divided (c outer, scalar weights);
// ent0/ent1 staging: 1 thread = 1 (sample,n) row, float4 loads + packed
// LDS stores (no integer division).
// ---------------------------------------------------------------------------
#define FN_XSB 0
#define FN_XP0 16384
#define FN_XP1 20736
#define FN_TOTAL 25088

__global__ __launch_bounds__(256, 4) void k_frontN(
    const float* __restrict__ xag, const float* __restrict__ xlid,
    const float* __restrict__ xsz, const float* __restrict__ xe0,
    const float* __restrict__ xe1,
    const float* __restrict__ conv_w, const float* __restrict__ conv_b,
    const float* __restrict__ self_b, const float* __restrict__ ent0_b,
    const float* __restrict__ ent1_b,
    const short* __restrict__ Wf, const short* __restrict__ We0,
    const short* __restrict__ We1,
    __hip_bfloat16* __restrict__ z_ent, float* __restrict__ zin_x)
{
    extern __shared__ char smem[];
    char* xsb = smem + FN_XSB;
    float* xp0f = (float*)(smem + FN_XP0);
    float* xp1f = (float*)(smem + FN_XP1);
    char* ae = smem + FN_XSB;
    float* lidf = (float*)(smem + FN_XP0);

    const int tid = threadIdx.x;
    const int s0 = blockIdx.x * FN_SB;
    const int wv = __builtin_amdgcn_readfirstlane(tid >> 6);
    const int l = tid & 63;
    const int lr = l & 15;
    const int lg = l >> 4;

    for (int i = tid; i < FN_SB * 32; i += 256) {
        int d = i & 31, sl = i >> 5;
        lidf[d * 18 + sl] = xlid[(size_t)s0 * 32 + i];
    }
    for (int i = tid; i < FN_SB * 16; i += 256) {
        int sl = i >> 4, d = i & 15;
        *(short*)(xsb + ((sl * 640 + d * 2) ^ ((sl & 7) << 4))) = f2bs(xag[(size_t)s0 * 16 + i]);
    }
    for (int i = tid; i < FN_SB * 4; i += 256) {
        int sl = i >> 2, d = i & 3;
        *(short*)(xsb + ((sl * 640 + (286 + d) * 2) ^ ((sl & 7) << 4))) = f2bs(xsz[(size_t)s0 * 4 + i]);
    }
    for (int i = tid; i < FN_SB * 30; i += 256) {
        int sl = i / 30, d = 290 + (i - (i / 30) * 30);
        *(short*)(xsb + ((sl * 640 + d * 2) ^ ((sl & 7) << 4))) = 0;
    }
    __syncthreads();
    // ---- conv: c outer (scalar weights), no division ----
    #pragma unroll
    for (int c = 0; c < 9; ++c) {
        float w0 = conv_w[c * 3], w1 = conv_w[c * 3 + 1], w2 = conv_w[c * 3 + 2];
        float bb = conv_b[c];
        for (int i = tid; i < 30 * FN_SB; i += 256) {
            int p = i >> 4, sl = i & 15;
            float v = bb + w0 * lidf[p * 18 + sl] + w1 * lidf[(p + 1) * 18 + sl]
                    + w2 * lidf[(p + 2) * 18 + sl];
            *(short*)(xsb + ((sl * 640 + (16 + c * 30 + p) * 2) ^ ((sl & 7) << 4))) = f2bs(fmaxf(v, 0.f));
        }
    }
    __syncthreads();

    f32x4 acc[5];
    #pragma unroll
    for (int c = 0; c < 5; ++c) acc[c] = (f32x4){0.f, 0.f, 0.f, 0.f};

    for (int kk = 0; kk < 10; ++kk) {
        short8 af = *(const short8*)(xsb + ((lr * 640 + kk * 64 + lg * 16) ^ ((lr & 7) << 4)));
        short8 bf[5];
        #pragma unroll
        for (int c = 0; c < 5; ++c) {
            int col = (wv * 5 + c) * 16 + lr;
            bf[c] = *(const short8*)(Wf + (size_t)col * 320 + kk * 32 + lg * 8);
        }
        #pragma unroll
        for (int c = 0; c < 5; ++c)
            acc[c] = __builtin_amdgcn_mfma_f32_16x16x32_bf16(af, bf[c], acc[c], 0, 0, 0);
    }

    #pragma unroll
    for (int c = 0; c < 5; ++c) {
        int ct = wv * 5 + c;
        int gc = ct * 16 + lr;
        int rowb = lg * 4;
        f32x4 a = acc[c];
        if (ct * 16 < 64) {
            float bias = self_b[gc];
            #pragma unroll
            for (int r = 0; r < 4; ++r)
                z_ent[(size_t)(s0 + rowb + r) * 2112 + gc] = __float2bfloat16(fmaxf(a[r] + bias, 0.f));
        } else if (ct * 16 < 192) {
            int r2 = gc - 64;
            #pragma unroll
            for (int r = 0; r < 4; ++r)
                zin_x[(size_t)(s0 + rowb + r) * 128 + r2] = a[r];
        } else if (ct * 16 < 256) {
            float bias = ent0_b[gc - 192];
            #pragma unroll
            for (int r = 0; r < 4; ++r)
                xp0f[(rowb + r) * 68 + (gc - 192)] = a[r] + bias;
        } else {
            float bias = ent1_b[gc - 256];
            #pragma unroll
            for (int r = 0; r < 4; ++r)
                xp1f[(rowb + r) * 68 + (gc - 256)] = a[r] + bias;
        }
    }
    __syncthreads();   // xsb reads done -> ae may alias it

    // ---- ent0 MLP ----
    {
        short8 bz = {0, 0, 0, 0, 0, 0, 0, 0};
        short8 be[4];
        #pragma unroll
        for (int ct = 0; ct < 4; ++ct) {
            int col = ct * 16 + lr;
            short8 bv = *(const short8*)(We0 + col * 16 + (lg & 1) * 8);
            be[ct] = (lg < 2) ? bv : bz;
        }
        for (int i = tid; i < 4096; i += 256) ((uint32*)ae)[i] = 0;
        __syncthreads();
        {   // one thread = one (sample,n) row: float4 loads, packed LDS stores
            int sl = tid >> 4, n = tid & 15;
            int row = sl * 16 + n;
            int sw = (row & 3) << 4;
            const float4* src = (const float4*)(xe0 + (size_t)(s0 + sl) * 192 + n * 12);
            float4 v0 = src[0], v1 = src[1], v2 = src[2];
            *(uint32*)(ae + ((row * 64 + 0) ^ sw))  = pkbf(v0.x, v0.y);
            *(uint32*)(ae + ((row * 64 + 4) ^ sw))  = pkbf(v0.z, v0.w);
            *(uint32*)(ae + ((row * 64 + 8) ^ sw))  = pkbf(v1.x, v1.y);
            *(uint32*)(ae + ((row * 64 + 12) ^ sw)) = pkbf(v1.z, v1.w);
            *(uint32*)(ae + ((row * 64 + 16) ^ sw)) = pkbf(v2.x, v2.y);
            *(uint32*)(ae + ((row * 64 + 20) ^ sw)) = pkbf(v2.z, v2.w);
        }
        __syncthreads();
        #pragma unroll
        for (int j = 0; j < 4; ++j) {
            int gs = wv * 4 + j;
            int row = gs * 16 + lr;
            short8 af = *(const short8*)(ae + ((row * 64 + lg * 16) ^ ((row & 3) << 4)));
            f32x4 a2[4];
            #pragma unroll
            for (int ct = 0; ct < 4; ++ct) {
                f32x4 z = {0.f, 0.f, 0.f, 0.f};
                a2[ct] = __builtin_amdgcn_mfma_f32_16x16x32_bf16(af, be[ct], z, 0, 0, 0);
            }
            #pragma unroll
            for (int t = 0; t < 2; ++t) {
                int e0 = 32 * t + 2 * lr;
                float xv0 = xp0f[gs * 68 + e0];
                float xv1 = xp0f[gs * 68 + e0 + 1];
                #pragma unroll
                for (int r = 0; r < 4; ++r) {
                    int n = lg * 4 + r;
                    float v0 = fmaxf(a2[2 * t][r] + xv0, 0.f);
                    float v1 = fmaxf(a2[2 * t + 1][r] + xv1, 0.f);
                    *(uint32*)((char*)z_ent + ((size_t)(s0 + gs) * 2112 + (1 + n) * 64 + e0) * 2) = pkbf(v0, v1);
                }
            }
        }
        __syncthreads();
    }

    // ---- ent1 MLP ----
    {
        short8 bz = {0, 0, 0, 0, 0, 0, 0, 0};
        short8 be[4];
        #pragma unroll
        for (int ct = 0; ct < 4; ++ct) {
            int col = ct * 16 + lr;
            short8 bv = *(const short8*)(We1 + col * 16 + (lg & 1) * 8);
            be[ct] = (lg < 2) ? bv : bz;
        }
        for (int i = tid; i < 4096; i += 256) ((uint32*)ae)[i] = 0;
        __syncthreads();
        {
            int sl = tid >> 4, n = tid & 15;
            int row = sl * 16 + n;
            int sw = (row & 3) << 4;
            const float4* src = (const float4*)(xe1 + (size_t)(s0 + sl) * 128 + n * 8);
            float4 v0 = src[0], v1 = src[1];
            *(uint32*)(ae + ((row * 64 + 0) ^ sw))  = pkbf(v0.x, v0.y);
            *(uint32*)(ae + ((row * 64 + 4) ^ sw))  = pkbf(v0.z, v0.w);
            *(uint32*)(ae + ((row * 64 + 8) ^ sw))  = pkbf(v1.x, v1.y);
            *(uint32*)(ae + ((row * 64 + 12) ^ sw)) = pkbf(v1.z, v1.w);
        }
        __syncthreads();
        #pragma unroll
        for (int j = 0; j < 4; ++j) {
            int gs = wv * 4 + j;
            int row = gs * 16 + lr;
            short8 af = *(const short8*)(ae + ((row * 64 + lg * 16) ^ ((row & 3) << 4)));
            f32x4 a2[4];
            #pragma unroll
            for (int ct = 0; ct < 4; ++ct) {
                f32x4 z = {0.f, 0.f, 0.f, 0.f};
                a2[ct] = __builtin_amdgcn_mfma_f32_16x16x32_bf16(af, be[ct], z, 0, 0, 0);
            }
            #pragma unroll
            for (int t = 0; t < 2; ++t) {
                int e0 = 32 * t + 2 * lr;
                float xv0 = xp1f[gs * 68 + e0];
                float xv1 = xp1f[gs * 68 + e0 + 1];
                #pragma unroll
                for (int r = 0; r < 4; ++r) {
                    int n = lg * 4 + r;
                    float v0 = fmaxf(a2[2 * t][r] + xv0, 0.f);
                    float v1 = fmaxf(a2[2 * t + 1][r] + xv1, 0.f);
                    *(uint32*)((char*)z_ent + ((size_t)(s0 + gs) * 2112 + (17 + n) * 64 + e0) * 2) = pkbf(v0, v1);
                }
            }
        }
    }
}

// ---------------------------------------------------------------------------
// k_attnG: full-MFMA attention. Softmax: mask folded into exp argument via
// per-thread (scale,bias); no max-subtraction (scores O(1) by construction).
// ---------------------------------------------------------------------------
#define AG_QB   0
#define AG_KB   4224
#define AG_VT   8448
#define AG_PW   12544
#define AG_P32  16640
#define AG_V32  17408
#define AG_MSK  17664
#define AG_TOTAL 17824

__global__ __launch_bounds__(256, 8) void k_attnG(
    const __hip_bfloat16* __restrict__ z_ent,
    const int* __restrict__ mask0, const int* __restrict__ mask1,
    const short* __restrict__ wqkvb, const float* __restrict__ inp_b,
    const short* __restrict__ wos_g, const float* __restrict__ bos_g,
    float* __restrict__ pooled_ws)
{
    extern __shared__ char smem[];
    char*  Qb  = smem + AG_QB;
    char*  Kb  = smem + AG_KB;
    char*  Vt  = smem + AG_VT;
    char*  Pw  = smem + AG_PW;
    float* P32 = (float*)(smem + AG_P32);
    float* V32 = (float*)(smem + AG_V32);
    float* msk = (float*)(smem + AG_MSK);
    char*  ob  = Qb;

    const int tid = threadIdx.x;
    const int s = blockIdx.x;
    const short* zg = (const short*)(z_ent + (size_t)s * 2112);

    if (tid < 16) msk[1 + tid] = (float)mask0[(size_t)s * 16 + tid];
    else if (tid < 32) msk[17 + (tid - 16)] = (float)mask1[(size_t)s * 16 + (tid - 16)];
    else if (tid == 32) msk[0] = 1.0f;

    const int wv = __builtin_amdgcn_readfirstlane(tid >> 6);
    const int l  = tid & 63;
    const int lr = l & 15;
    const int lg = l >> 4;

    // ---- P1: in_proj GEMM (A from global, rows clamped to 32) ----
    {
        short8 bw[3][2]; float bias[3];
        #pragma unroll
        for (int c = 0; c < 3; ++c) {
            int col = (wv * 3 + c) * 16 + lr;
            bw[c][0] = *(const short8*)(wqkvb + col * 64 + lg * 8);
            bw[c][1] = *(const short8*)(wqkvb + col * 64 + 32 + lg * 8);
            bias[c] = inp_b[col];
        }
        for (int rt = 0; rt < 3; ++rt) {
            int arow = rt * 16 + lr;
            if (arow > 32) arow = 32;
            short8 a0 = *(const short8*)(zg + arow * 64 + lg * 8);
            short8 a1 = *(const short8*)(zg + arow * 64 + 32 + lg * 8);
            #pragma unroll
            for (int c = 0; c < 3; ++c) {
                f32x4 acc = {0.f, 0.f, 0.f, 0.f};
                acc = __builtin_amdgcn_mfma_f32_16x16x32_bf16(a0, bw[c][0], acc, 0, 0, 0);
                acc = __builtin_amdgcn_mfma_f32_16x16x32_bf16(a1, bw[c][1], acc, 0, 0, 0);
                int col = (wv * 3 + c) * 16 + lr;
                int rb = rt * 16 + lg * 4;
                #pragma unroll
                for (int r = 0; r < 4; ++r) {
                    int q = rb + r;
                    if (q < 33) {
                        float val = acc[r] + bias[c];
                        if (col < 64) {
                            int h = col >> 4, d = col & 15;
                            *(short*)(Qb + ((h * 33 + q) * 32) + d * 2) = f2bs(val);
                        } else if (col < 128) {
                            int kc = col - 64; int h = kc >> 4, d = kc & 15;
                            *(short*)(Kb + ((h * 33 + q) * 32) + d * 2) = f2bs(val);
                        } else {
                            int vc = col - 128; int h = vc >> 4, d = vc & 15;
                            if (q < 32)
                                *(short*)(Vt + (h * 16 + d) * 64 + ((q * 2) ^ pswz(d))) = f2bs(val);
                            else
                                V32[h * 16 + d] = val;
                        }
                    }
                }
            }
        }
    }
    __syncthreads();

    // ---- P2a: QK MFMA + mask-folded softmax (no max-sub); P packed in regs ----
    uint32 pk[3][4];
    {
        const short8 zero8 = {0, 0, 0, 0, 0, 0, 0, 0};
        short8 kf[3];
        #pragma unroll
        for (int t = 0; t < 3; ++t)
            kf[t] = (lg < 2) ? *(const short8*)(Kb + ((wv * 33 + t * 16 + lr) * 32) + lg * 16) : zero8;
        // per-thread fused mask: e = exp(S*sc + bo); masked -> exp(-40) ~= 0
        float mk0 = msk[lr];
        float mk1 = msk[16 + lr];
        float mk2 = (lr == 0) ? msk[32] : 0.f;
        float sc0 = mk0 * 0.25f, bo0 = (mk0 - 1.f) * 40.f;
        float sc1 = mk1 * 0.25f, bo1 = (mk1 - 1.f) * 40.f;
        float sc2 = mk2 * 0.25f, bo2 = (mk2 - 1.f) * 40.f;
        #pragma unroll
        for (int qt = 0; qt < 3; ++qt) {
            short8 qf = (lg < 2) ? *(const short8*)(Qb + ((wv * 33 + qt * 16 + lr) * 32) + lg * 16) : zero8;
            f32x4 z = {0.f, 0.f, 0.f, 0.f};
            f32x4 S0 = __builtin_amdgcn_mfma_f32_16x16x32_bf16(qf, kf[0], z, 0, 0, 0);
            f32x4 S1 = __builtin_amdgcn_mfma_f32_16x16x32_bf16(qf, kf[1], z, 0, 0, 0);
            f32x4 S2 = __builtin_amdgcn_mfma_f32_16x16x32_bf16(qf, kf[2], z, 0, 0, 0);
            #pragma unroll
            for (int r = 0; r < 4; ++r) {
                float e0 = __expf(fmaf(S0[r], sc0, bo0));
                float e1 = __expf(fmaf(S1[r], sc1, bo1));
                float e2 = __expf(fmaf(S2[r], sc2, bo2));
                float sm = e0 + e1 + e2;
                sm += __shfl_xor(sm, 1);
                sm += __shfl_xor(sm, 2);
                sm += __shfl_xor(sm, 4);
                sm += __shfl_xor(sm, 8);
                float inv = 1.0f / sm;
                pk[qt][r] = pkbf(e0 * inv, e1 * inv);
                if (lr == 0) P32[wv * 48 + qt * 16 + lg * 4 + r] = e2 * inv;
            }
        }
    }
    __syncthreads();

    // ---- P2b: PV MFMA via per-wave Pw tile; write ob (aliases Qb) ----
    {
        short8 vf = *(const short8*)(Vt + (wv * 16 + lr) * 64 + ((lg * 16) ^ pswz(lr)));
        float v32reg = V32[wv * 16 + lr];
        f32x4 C[3];
        #pragma unroll
        for (int qt = 0; qt < 3; ++qt) {
            #pragma unroll
            for (int r = 0; r < 4; ++r) {
                int ql = lg * 4 + r;
                uint32 p = pk[qt][r];
                char* prow = Pw + wv * 1024 + ql * 64;
                int sz = pswz(ql);
                *(short*)(prow + ((lr * 2) ^ sz)) = (short)(p & 0xffffu);
                *(short*)(prow + (((16 + lr) * 2) ^ sz)) = (short)(p >> 16);
            }
            short8 pf = *(const short8*)(Pw + wv * 1024 + lr * 64 + ((lg * 16) ^ pswz(lr)));
            f32x4 z = {0.f, 0.f, 0.f, 0.f};
            C[qt] = __builtin_amdgcn_mfma_f32_16x16x32_bf16(pf, vf, z, 0, 0, 0);
        }
        #pragma unroll
        for (int qt = 0; qt < 3; ++qt) {
            #pragma unroll
            for (int r = 0; r < 4; ++r) {
                int q = qt * 16 + lg * 4 + r;
                if (q <= 32) {
                    float cv = C[qt][r] + P32[wv * 48 + q] * v32reg;
                    *(short*)(ob + ((q * 128 + (wv * 16 + lr) * 2) ^ ((q & 7) << 4))) = f2bs(cv);
                }
            }
        }
    }
    __syncthreads();

    // ---- P4: fused (sa@out_proj) GEMM + residual + mask; pooled -> ws ----
    {
        int col = wv * 16 + lr;
        short8 b0 = *(const short8*)(wos_g + col * 64 + lg * 8);
        short8 b1 = *(const short8*)(wos_g + col * 64 + 32 + lg * 8);
        float bias = bos_g[col];
        float ps = 0.f;
        for (int rt = 0; rt < 3; ++rt) {
            int arow = rt * 16 + lr;
            int sw = (arow & 7) << 4;
            short8 a0 = *(const short8*)(ob + ((arow * 128 + lg * 16) ^ sw));
            short8 a1 = *(const short8*)(ob + ((arow * 128 + 64 + lg * 16) ^ sw));
            f32x4 acc = {0.f, 0.f, 0.f, 0.f};
            acc = __builtin_amdgcn_mfma_f32_16x16x32_bf16(a0, b0, acc, 0, 0, 0);
            acc = __builtin_amdgcn_mfma_f32_16x16x32_bf16(a1, b1, acc, 0, 0, 0);
            int rb = rt * 16 + lg * 4;
            #pragma unroll
            for (int r = 0; r < 4; ++r) {
                int row = rb + r;
                if (row < 33) {
                    float zev = bf2f(*(const unsigned short*)(zg + row * 64 + col));
                    ps += msk[row] * (zev + fmaxf(acc[r] + bias, 0.f));
                }
            }
        }
        ps += __shfl_xor(ps, 16); ps += __shfl_xor(ps, 32);
        if (lg == 0) pooled_ws[(size_t)s * 64 + col] = ps * (1.0f / 33.0f);
    }
}

// ---------------------------------------------------------------------------
// k_zinx: fused zin + x-projection (unchanged from round 12).
// ---------------------------------------------------------------------------
__global__ __launch_bounds__(256, 2) void k_zinx(
    const float* __restrict__ pooled_ws, const float* __restrict__ zin_x,
    const short* __restrict__ wp2, const float* __restrict__ pool_b,
    const short* __restrict__ wihb, const float* __restrict__ b_ih,
    const float* __restrict__ b_hh, short* __restrict__ xp)
{
    extern __shared__ char smem[];
    char* A1 = smem;
    char* zt = smem + 8192;
    const int tid = threadIdx.x;
    const size_t r0 = (size_t)blockIdx.x * 64;

    for (int i = tid; i < 2048; i += 256) {
        int sl = i >> 5, dp = i & 31;
        float2 v = ((const float2*)(pooled_ws + (r0 + sl) * 64))[dp];
        *(uint32*)(A1 + ((sl * 128 + dp * 4) ^ ((sl & 7) << 4))) = pkbf(v.x, v.y);
    }
    __syncthreads();

    const int wv = __builtin_amdgcn_readfirstlane(tid >> 6);
    const int l = tid & 63;
    const int lr = l & 15;
    const int lg = l >> 4;

    #pragma unroll
    for (int c = 0; c < 2; ++c) {
        int col = (wv * 2 + c) * 16 + lr;
        short8 bf0 = *(const short8*)(wp2 + col * 64 + lg * 8);
        short8 bf1 = *(const short8*)(wp2 + col * 64 + 32 + lg * 8);
        float bias = pool_b[col];
        #pragma unroll
        for (int rt = 0; rt < 4; ++rt) {
            int row16 = rt * 16 + lr;
            short8 a0 = *(const short8*)(A1 + ((row16 * 128 + lg * 16) ^ ((row16 & 7) << 4)));
            short8 a1 = *(const short8*)(A1 + ((row16 * 128 + 64 + lg * 16) ^ ((row16 & 7) << 4)));
            f32x4 acc = {0.f, 0.f, 0.f, 0.f};
            acc = __builtin_amdgcn_mfma_f32_16x16x32_bf16(a0, bf0, acc, 0, 0, 0);
            acc = __builtin_amdgcn_mfma_f32_16x16x32_bf16(a1, bf1, acc, 0, 0, 0);
            #pragma unroll
            for (int r = 0; r < 4; ++r) {
                int row = rt * 16 + lg * 4 + r;
                float v = fmaxf(acc[r] + bias + zin_x[(r0 + row) * 128 + col], 0.f);
                *(short*)(zt + ((row * 256 + col * 2) ^ ((row & 7) << 4))) = f2bs(v);
            }
        }
    }
    __syncthreads();

    short8 af[4][4];
    #pragma unroll
    for (int rt = 0; rt < 4; ++rt)
        #pragma unroll
        for (int kc = 0; kc < 4; ++kc) {
            int row = rt * 16 + lr;
            af[rt][kc] = *(const short8*)(zt + ((row * 256 + kc * 64 + lg * 16) ^ ((row & 7) << 4)));
        }

    for (int ct8 = 0; ct8 < 8; ++ct8) {
        int ct = wv * 8 + ct8;
        int col = ct * 16 + lr;
        short8 bf[4];
        #pragma unroll
        for (int kc = 0; kc < 4; ++kc)
            bf[kc] = *(const short8*)(wihb + (size_t)col * 128 + kc * 32 + lg * 8);
        float bias = b_ih[col] + b_hh[col];
        int g = col >> 7, j = col & 127;
        #pragma unroll
        for (int rt = 0; rt < 4; ++rt) {
            f32x4 acc = {0.f, 0.f, 0.f, 0.f};
            #pragma unroll
            for (int kc = 0; kc < 4; ++kc)
                acc = __builtin_amdgcn_mfma_f32_16x16x32_bf16(af[rt][kc], bf[kc], acc, 0, 0, 0);
            #pragma unroll
            for (int r = 0; r < 4; ++r)
                xp[(r0 + rt * 16 + lg * 4 + r) * 512 + j * 4 + g] = f2bs(acc[r] + bias);
        }
    }
}

// ---------------------------------------------------------------------------
// k_lstm2: MFMA recurrent scan (unchanged).
// ---------------------------------------------------------------------------
__global__ __launch_bounds__(512, 1) void k_lstm2(
    const short* __restrict__ xp, const short* __restrict__ whhb,
    const int* __restrict__ done, float* __restrict__ h_all)
{
    __shared__ short hl[16 * 128];
    __shared__ float keepl[64 * 16];
    const int tid = threadIdx.x;
    const int s0 = blockIdx.x * 16;
    const int wv = __builtin_amdgcn_readfirstlane(tid >> 6);
    const int l = tid & 63;
    const int lr = l & 15;
    const int lg = l >> 4;

    for (int i = tid; i < 1024; i += 512) {
        int t = i >> 4, ls = i & 15;
        keepl[i] = done[t * 32 + ((s0 + ls) >> 3)] ? 0.f : 1.f;
    }
    for (int i = tid; i < 1024; i += 512) ((uint32*)hl)[i] = 0;

    short8 bf[4][4];
    #pragma unroll
    for (int gi = 0; gi < 4; ++gi) {
        int col = (gi * 8 + wv) * 16 + lr;
        #pragma unroll
        for (int kc = 0; kc < 4; ++kc)
            bf[gi][kc] = *(const short8*)(whhb + (size_t)col * 128 + kc * 32 + lg * 8);
    }
    float c0 = 0.f, c1 = 0.f, c2 = 0.f, c3 = 0.f;
    const int jcol = wv * 16 + lr;

    short4 xn[4];
    #pragma unroll
    for (int r = 0; r < 4; ++r)
        xn[r] = *(const short4*)(xp + ((size_t)(s0 + lg * 4 + r)) * 512 + jcol * 4);
    __syncthreads();

    for (int t = 0; t < T_DIM; ++t) {
        short4 xc[4];
        #pragma unroll
        for (int r = 0; r < 4; ++r) xc[r] = xn[r];
        if (t < 63) {
            #pragma unroll
            for (int r = 0; r < 4; ++r)
                xn[r] = *(const short4*)(xp + ((size_t)(t + 1) * 256 + s0 + lg * 4 + r) * 512 + jcol * 4);
        }
        short8 af[4];
        #pragma unroll
        for (int kc = 0; kc < 4; ++kc)
            af[kc] = *(const short8*)((char*)hl + ((lr * 256 + kc * 64 + lg * 16) ^ ((lr & 7) << 4)));
        f32x4 z = {0.f, 0.f, 0.f, 0.f};
        f32x4 Ci = z, Cf = z, Cg = z, Co = z;
        #pragma unroll
        for (int kc = 0; kc < 4; ++kc) {
            Ci = __builtin_amdgcn_mfma_f32_16x16x32_bf16(af[kc], bf[0][kc], Ci, 0, 0, 0);
            Cf = __builtin_amdgcn_mfma_f32_16x16x32_bf16(af[kc], bf[1][kc], Cf, 0, 0, 0);
            Cg = __builtin_amdgcn_mfma_f32_16x16x32_bf16(af[kc], bf[2][kc], Cg, 0, 0, 0);
            Co = __builtin_amdgcn_mfma_f32_16x16x32_bf16(af[kc], bf[3][kc], Co, 0, 0, 0);
        }
        __syncthreads();

        #pragma unroll
        for (int r = 0; r < 4; ++r) {
            int sl = lg * 4 + r;
            float kt = keepl[t * 16 + sl];
            float gi = bf2f((unsigned short)xc[r].x) + Ci[r];
            float gf = bf2f((unsigned short)xc[r].y) + Cf[r];
            float gg = bf2f((unsigned short)xc[r].z) + Cg[r];
            float go = bf2f((unsigned short)xc[r].w) + Co[r];
            float cc = (r == 0 ? c0 : r == 1 ? c1 : r == 2 ? c2 : c3) * kt;
            cc = sigf(gf) * cc + sigf(gi) * tanhf(gg);
            float hn = sigf(go) * tanhf(cc);
            if (r == 0) c0 = cc; else if (r == 1) c1 = cc; else if (r == 2) c2 = cc; else c3 = cc;
            float kn = (t < 63) ? keepl[(t + 1) * 16 + sl] : 1.f;
            *(short*)((char*)hl + ((sl * 256 + jcol * 2) ^ ((sl & 7) << 4))) = f2bs(hn * kn);
            h_all[((size_t)t * 256 + s0 + sl) * 128 + jcol] = hn;
        }
        __syncthreads();
    }
}

// ---------------------------------------------------------------------------
// Kernel: categorical heads (unchanged)
// ---------------------------------------------------------------------------
__global__ __launch_bounds__(256) void k_heads(
    const float* __restrict__ h_all, const int* __restrict__ actions,
    const float* __restrict__ h0w, const float* __restrict__ h0b,
    const float* __restrict__ h1w, const float* __restrict__ h1b,
    float* __restrict__ out)
{
    __shared__ float w0[640], w1[640], b0[8], b1[8];
    const int tid = threadIdx.x;
    for (int i = tid; i < 640; i += 256) { w0[i] = h0w[i]; w1[i] = h1w[i]; }
    if (tid < 5) { b0[tid] = h0b[tid]; b1[tid] = h1b[tid]; }
    __syncthreads();
    const int g = blockIdx.x * 256 + tid;
    const float* h = h_all + (size_t)g * 128;
    float l0[5], l1[5];
    #pragma unroll
    for (int cc = 0; cc < 5; ++cc) { l0[cc] = b0[cc]; l1[cc] = b1[cc]; }
    for (int j = 0; j < 128; ++j) {
        float hv = h[j];
        #pragma unroll
        for (int cc = 0; cc < 5; ++cc) {
            l0[cc] = fmaf(w0[cc * 128 + j], hv, l0[cc]);
            l1[cc] = fmaf(w1[cc * 128 + j], hv, l1[cc]);
        }
    }
    int a0 = actions[(size_t)g * 2], a1 = actions[(size_t)g * 2 + 1];
    float m0 = l0[0], m1 = l1[0];
    #pragma unroll
    for (int cc = 1; cc < 5; ++cc) { m0 = fmaxf(m0, l0[cc]); m1 = fmaxf(m1, l1[cc]); }
    float s0 = 0.f, s1 = 0.f;
    #pragma unroll
    for (int cc = 0; cc < 5; ++cc) { s0 += expf(l0[cc] - m0); s1 += expf(l1[cc] - m1); }
    float lse0 = m0 + logf(s0), lse1 = m1 + logf(s1);
    float ent0 = 0.f, ent1 = 0.f, lp0 = 0.f, lp1 = 0.f;
    #pragma unroll
    for (int cc = 0; cc < 5; ++cc) {
        float p0 = l0[cc] - lse0, p1 = l1[cc] - lse1;
        ent0 -= expf(p0) * p0;
        ent1 -= expf(p1) * p1;
        if (cc == a0) lp0 = p0;
        if (cc == a1) lp1 = p1;
    }
    out[ACT_OFF + (size_t)g * 2]     = (float)a0;
    out[ACT_OFF + (size_t)g * 2 + 1] = (float)a1;
    out[LP_OFF + g]                  = lp0 * lp1;
    out[ENT_OFF + (size_t)g * 2]     = ent0;
    out[ENT_OFF + (size_t)g * 2 + 1] = ent1;
}

extern "C" void kernel_launch(void* const* d_in, const int* in_sizes, int n_in,
                              void* d_out, int out_size, void* d_ws, size_t ws_size,
                              hipStream_t stream)
{
    const float* x_agent = (const float*)d_in[0];
    const float* x_lidar = (const float*)d_in[1];
    const float* x_safe  = (const float*)d_in[2];
    const float* x_ent0  = (const float*)d_in[3];
    const float* x_ent1  = (const float*)d_in[4];
    const int*   mask0   = (const int*)d_in[5];
    const int*   mask1   = (const int*)d_in[6];
    const int*   done    = (const int*)d_in[7];
    const int*   actions = (const int*)d_in[8];
    const float* conv_w  = (const float*)d_in[9];
    const float* conv_b  = (const float*)d_in[10];
    const float* self_w  = (const float*)d_in[11];
    const float* self_b  = (const float*)d_in[12];
    const float* ent0_w  = (const float*)d_in[13];
    const float* ent0_b  = (const float*)d_in[14];
    const float* ent1_w  = (const float*)d_in[15];
    const float* ent1_b  = (const float*)d_in[16];
    const float* inp_w   = (const float*)d_in[17];
    const float* inp_b   = (const float*)d_in[18];
    const float* outp_w  = (const float*)d_in[19];
    const float* outp_b  = (const float*)d_in[20];
    const float* sa_w    = (const float*)d_in[21];
    const float* sa_b    = (const float*)d_in[22];
    const float* pool_w  = (const float*)d_in[23];
    const float* pool_b  = (const float*)d_in[24];
    const float* w_ih    = (const float*)d_in[25];
    const float* w_hh    = (const float*)d_in[26];
    const float* b_ih    = (const float*)d_in[27];
    const float* b_hh    = (const float*)d_in[28];
    const float* h0w     = (const float*)d_in[29];
    const float* h0b     = (const float*)d_in[30];
    const float* h1w     = (const float*)d_in[31];
    const float* h1b     = (const float*)d_in[32];

    // ws layout
    __hip_bfloat16* z_ent = (__hip_bfloat16*)d_ws;
    float* zin_x  = (float*)((char*)d_ws + (size_t)S_TOT * 2112 * 2);
    float* pooled = zin_x + (size_t)S_TOT * 128;
    float* h_all  = pooled + (size_t)S_TOT * 64;
    short* xp     = (short*)(h_all + (size_t)S_TOT * 128);
    short* wqkvb  = xp + (size_t)S_TOT * 512;
    short* Wf     = wqkvb + 12288;
    short* We0    = Wf + 102400;
    short* We1    = We0 + 1024;
    short* wos    = We1 + 1024;
    float* bos    = (float*)(wos + 4096);
    short* wihb   = (short*)(bos + 64);
    short* whhb   = wihb + 65536;
    short* wp2    = whhb + 65536;

    k_cvt2<<<400, 256, 0, stream>>>(inp_w, outp_w, outp_b, sa_w, sa_b, self_w, pool_w,
                                    ent0_w, ent1_w, w_ih, w_hh,
                                    wqkvb, Wf, We0, We1, wos, bos, wihb, whhb, wp2);

    k_frontN<<<S_TOT / FN_SB, 256, FN_TOTAL, stream>>>(
        x_agent, x_lidar, x_safe, x_ent0, x_ent1,
        conv_w, conv_b, self_b, ent0_b, ent1_b,
        Wf, We0, We1, z_ent, zin_x);

    k_attnG<<<S_TOT, 256, AG_TOTAL, stream>>>(
        z_ent, mask0, mask1, wqkvb, inp_b, wos, bos, pooled);

    k_zinx<<<256, 256, 24576, stream>>>(pooled, zin_x, wp2, pool_b, wihb, b_ih, b_hh, xp);

    k_lstm2<<<16, 512, 0, stream>>>(xp, whhb, done, h_all);

    k_heads<<<S_TOT / 256, 256, 0, stream>>>(h_all, actions, h0w, h0b, h1w, h1b, (float*)d_out);
}